// Round 1
// baseline (14309.109 us; speedup 1.0000x reference)
//
#include <hip/hip_runtime.h>

// ---------------- problem constants ----------------
constexpr int NB  = 4;
constexpr int IH  = 270;
constexpr int IW  = 512;
constexpr int NPIX = IH * IW;      // 138240
constexpr int PH  = 271;           // pooled height
constexpr int PW  = 513;           // pooled width
constexpr float TWO_PI_F = 6.28318530717958647692f;

// ============================================================
// Stage 1: x -> pooled (8 ch, PH x PW). Fuses gradient, orientation
// binning (ang) and the 4x4 depthwise pool (pad 2, zero).
// grid (33, 17, NB), block 256 (16x16 tile of pooled outputs)
// ============================================================
__global__ __launch_bounds__(256) void pooled_kernel(
    const float* __restrict__ x, float* __restrict__ pooled) {
  const int b = blockIdx.z;
  const int px0 = blockIdx.x * 16, py0 = blockIdx.y * 16;
  __shared__ float wo0s[19][19];
  __shared__ float wo1s[19][19];
  __shared__ int   bo0s[19][19];
  const float* xb = x + (size_t)b * NPIX;

  for (int t = threadIdx.x; t < 19 * 19; t += 256) {
    int r = t / 19, c = t % 19;
    int gy = py0 - 2 + r, gx = px0 - 2 + c;   // ang-pixel coords
    float w0 = 0.f, w1v = 0.f; int b0 = 0;
    if (gy >= 0 && gy < IH && gx >= 0 && gx < IW) {
      int xm = gx > 0 ? gx - 1 : 0, xp = gx < IW - 1 ? gx + 1 : IW - 1;
      int ym = gy > 0 ? gy - 1 : 0, yp = gy < IH - 1 ? gy + 1 : IH - 1;
      float gxv = (xb[gy * IW + xp] - xb[gy * IW + xm]) * 0.5f;
      float gyv = (xb[yp * IW + gx] - xb[ym * IW + gx]) * 0.5f;
      float mag = sqrtf(gxv * gxv + gyv * gyv + 1e-10f);
      float ori = atan2f(gyv, gxv + 1e-10f) + TWO_PI_F;
      float obig = ori * (8.0f / TWO_PI_F);
      float bf = floorf(obig);
      float w1_ = obig - bf;
      w0  = (1.0f - w1_) * mag;
      w1v = w1_ * mag;
      b0  = ((int)bf) & 7;
    }
    wo0s[r][c] = w0; wo1s[r][c] = w1v; bo0s[r][c] = b0;
  }
  __syncthreads();

  const int t = threadIdx.x;
  const int lx = t % 16, ly = t / 16;
  const int py = py0 + ly, px = px0 + lx;
  if (py >= PH || px >= PW) return;

  const float pwt[4] = {0.25f, 0.75f, 0.75f, 0.25f};  // xc2/2 -> product = pool1
  float acc[8] = {0, 0, 0, 0, 0, 0, 0, 0};
  for (int i = 0; i < 4; i++) {
    for (int j = 0; j < 4; j++) {
      int r = ly + i, c = lx + j;              // ang pixel (py+i-2, px+j-2)
      float w0 = wo0s[r][c], w1v = wo1s[r][c];
      int b0 = bo0s[r][c];
      int b1i = (b0 + 1) & 7;
      float pw = pwt[i] * pwt[j];
      #pragma unroll
      for (int a = 0; a < 8; a++) {
        float add = (a == b0 ? w0 : 0.f) + (a == b1i ? w1v : 0.f);
        acc[a] = fmaf(pw, add, acc[a]);
      }
    }
  }
  float* pb = pooled + (size_t)b * 8 * PH * PW;
  #pragma unroll
  for (int a = 0; a < 8; a++) pb[((size_t)a * PH + py) * PW + px] = acc[a];
}

// ============================================================
// Stage 2: per-pixel SIFT normalization scalars s1, g
//   d[c=a*16+i*4+j](y,x) = pooled[a][y+i-1][x+j-1]  (zero OOB)
//   s1 = 1/max(||d||2, 1e-12); t = min(d*s1, 0.2)
//   s2 = 1/max(||t||2, 1e-12); l1 = max(s2*sum(t), 1e-12); g = s2/l1
// grid (32, 17, NB), block 256 (16x16 pixels)
// ============================================================
__global__ __launch_bounds__(256) void sift_scalars_kernel(
    const float* __restrict__ pooled, float* __restrict__ s1g) {
  const int b = blockIdx.z;
  const int x0 = blockIdx.x * 16, y0 = blockIdx.y * 16;
  __shared__ float pt[8][19][19];
  const float* pb = pooled + (size_t)b * 8 * PH * PW;
  for (int t = threadIdx.x; t < 8 * 19 * 19; t += 256) {
    int a = t / 361, rc = t % 361, r = rc / 19, c = rc % 19;
    int gy = y0 - 1 + r, gx = x0 - 1 + c;
    float v = 0.f;
    if (gy >= 0 && gy < PH && gx >= 0 && gx < PW) v = pb[((size_t)a * PH + gy) * PW + gx];
    pt[a][r][c] = v;
  }
  __syncthreads();
  const int t = threadIdx.x;
  const int lx = t % 16, ly = t / 16;
  const int y = y0 + ly, x = x0 + lx;
  if (y >= IH) return;

  float sum2 = 0.f;
  for (int c = 0; c < 128; c++) {
    int a = c >> 4, i = (c >> 2) & 3, j = c & 3;
    float p = pt[a][ly + i][lx + j];
    sum2 = fmaf(p, p, sum2);
  }
  float s1 = 1.0f / fmaxf(sqrtf(sum2), 1e-12f);
  float st2 = 0.f, st = 0.f;
  for (int c = 0; c < 128; c++) {
    int a = c >> 4, i = (c >> 2) & 3, j = c & 3;
    float p = pt[a][ly + i][lx + j];
    float tv = fminf(p * s1, 0.2f);
    st2 = fmaf(tv, tv, st2);
    st += tv;
  }
  float s2 = 1.0f / fmaxf(sqrtf(st2), 1e-12f);
  float l1 = fmaxf(s2 * st, 1e-12f);
  float g = s2 / l1;
  float* o = s1g + (size_t)b * 2 * NPIX;
  o[y * IW + x] = s1;
  o[NPIX + y * IW + x] = g;
}

// ============================================================
// Weight repack: w[CO][CI][K*K] -> wT[K*K][CI][CO]
// ============================================================
__global__ void repack_kernel(const float* __restrict__ w, float* __restrict__ wT,
                              int CO, int CI, int KK) {
  int i = blockIdx.x * 256 + threadIdx.x;
  int total = CO * CI * KK;
  if (i >= total) return;
  int o = i / (CI * KK);
  int r = i % (CI * KK);
  int ci = r / KK, kk = r % KK;
  wT[(kk * CI + ci) * CO + o] = w[i];
}

// ============================================================
// Conv1 fused: descriptors reconstructed from (pooled, s1g) in LDS,
// then 5x5 conv 128->64, + bias. 8x8 output tile, 32-ch desc chunks.
// grid (64, 34, NB), block 256 (64 px x 4 ch-groups of 16)
// ============================================================
__global__ __launch_bounds__(256) void conv1_kernel(
    const float* __restrict__ pooled, const float* __restrict__ s1g,
    const float* __restrict__ w1T, const float* __restrict__ bias,
    float* __restrict__ out) {
  const int b = blockIdx.z;
  const int x0 = blockIdx.x * 8, y0 = blockIdx.y * 8;
  __shared__ float pt[8][15][15];     // pooled rows [y0-3, y0+12)
  __shared__ float sc[2][12][12];     // s1, g for pixels [y0-2, y0+10)
  __shared__ float desc[32][12][12];  // one 32-channel descriptor chunk

  const float* pb = pooled + (size_t)b * 8 * PH * PW;
  for (int t = threadIdx.x; t < 8 * 15 * 15; t += 256) {
    int a = t / 225, rc = t % 225, r = rc / 15, c = rc % 15;
    int gy = y0 - 3 + r, gx = x0 - 3 + c;
    float v = 0.f;
    if (gy >= 0 && gy < PH && gx >= 0 && gx < PW) v = pb[((size_t)a * PH + gy) * PW + gx];
    pt[a][r][c] = v;
  }
  const float* sb = s1g + (size_t)b * 2 * NPIX;
  for (int t = threadIdx.x; t < 144; t += 256) {
    int r = t / 12, c = t % 12;
    int gy = y0 - 2 + r, gx = x0 - 2 + c;
    float a0 = 0.f, a1 = 0.f;
    if (gy >= 0 && gy < IH && gx >= 0 && gx < IW) {
      a0 = sb[gy * IW + gx];
      a1 = sb[NPIX + gy * IW + gx];
    }
    sc[0][r][c] = a0; sc[1][r][c] = a1;
  }
  __syncthreads();

  const int t = threadIdx.x;
  const int px = t % 64;
  const int pyy = px / 8, pxx = px % 8;
  const int oc0 = (t / 64) * 16;
  float acc[16];
  #pragma unroll
  for (int o = 0; o < 16; o++) acc[o] = 0.f;

  for (int cc = 0; cc < 4; cc++) {
    if (cc) __syncthreads();  // previous chunk fully consumed
    for (int u = threadIdx.x; u < 32 * 144; u += 256) {
      int lc = u / 144, rc = u % 144, r = rc / 12, c = rc % 12;
      int ch = cc * 32 + lc;
      int a = ch >> 4, i = (ch >> 2) & 3, j = ch & 3;
      int gy = y0 - 2 + r, gx = x0 - 2 + c;
      float v = 0.f;
      if (gy >= 0 && gy < IH && gx >= 0 && gx < IW) {
        float p = pt[a][r + i][c + j];
        v = sqrtf(fminf(p * sc[0][r][c], 0.2f) * sc[1][r][c] + 1e-10f);
      }
      desc[lc][r][c] = v;
    }
    __syncthreads();

    for (int ky = 0; ky < 5; ky++) {
      for (int kx = 0; kx < 5; kx++) {
        const float* wrow = w1T + (size_t)((ky * 5 + kx) * 128 + cc * 32) * 64 + oc0;
        for (int lc = 0; lc < 32; lc++) {
          float v = desc[lc][pyy + ky][pxx + kx];
          const float* wp = wrow + lc * 64;
          #pragma unroll
          for (int o = 0; o < 16; o++) acc[o] = fmaf(v, wp[o], acc[o]);
        }
      }
    }
  }

  const int y = y0 + pyy, x = x0 + pxx;
  if (y < IH) {
    float* ob = out + (size_t)b * 64 * NPIX;
    #pragma unroll
    for (int o = 0; o < 16; o++)
      ob[(size_t)(oc0 + o) * NPIX + y * IW + x] = acc[o] + bias[oc0 + o];
  }
}

// ============================================================
// GroupNorm: per-(b,c)-plane sums (fp64, deterministic), then coefs,
// then fused scale+shift+ReLU applied in place.
// ============================================================
__global__ __launch_bounds__(256) void gn_stats_kernel(
    const float* __restrict__ xin, double* __restrict__ stats_pc) {
  const int bc = blockIdx.x;
  const float* p = xin + (size_t)bc * NPIX;
  double s = 0.0, s2 = 0.0;
  for (int i = threadIdx.x; i < NPIX; i += 256) {
    float v = p[i];
    s += v;
    s2 += (double)v * v;
  }
  __shared__ double sh0[256];
  __shared__ double sh1[256];
  sh0[threadIdx.x] = s; sh1[threadIdx.x] = s2;
  __syncthreads();
  for (int off = 128; off > 0; off >>= 1) {
    if (threadIdx.x < off) {
      sh0[threadIdx.x] += sh0[threadIdx.x + off];
      sh1[threadIdx.x] += sh1[threadIdx.x + off];
    }
    __syncthreads();
  }
  if (threadIdx.x == 0) {
    stats_pc[bc * 2] = sh0[0];
    stats_pc[bc * 2 + 1] = sh1[0];
  }
}

__global__ void gn_coef_kernel(const double* __restrict__ stats_pc,
                               const float* __restrict__ gamma,
                               const float* __restrict__ beta,
                               float* __restrict__ cA, float* __restrict__ cB,
                               int C, int chper) {
  int i = blockIdx.x * 64 + threadIdx.x;
  if (i >= NB * C) return;
  int b = i / C, c = i % C;
  int g0 = (c / chper) * chper;
  double S = 0.0, S2 = 0.0;
  for (int k = 0; k < chper; k++) {
    S  += stats_pc[(b * C + g0 + k) * 2];
    S2 += stats_pc[(b * C + g0 + k) * 2 + 1];
  }
  double Nd = (double)chper * NPIX;
  double mu = S / Nd;
  double var = S2 / Nd - mu * mu;
  double rstd = 1.0 / sqrt(var + 1e-5);
  float A = (float)rstd * gamma[c];
  cA[i] = A;
  cB[i] = beta[c] - (float)mu * A;
}

__global__ __launch_bounds__(256) void gn_apply_kernel(
    float* __restrict__ xio, const float* __restrict__ cA,
    const float* __restrict__ cB, int C) {
  size_t total = (size_t)NB * C * NPIX;
  for (size_t i = (size_t)blockIdx.x * 256 + threadIdx.x; i < total;
       i += (size_t)gridDim.x * 256) {
    size_t bc = i / NPIX;
    float v = fmaf(xio[i], cA[bc], cB[bc]);
    xio[i] = v > 0.f ? v : 0.f;
  }
}

// ============================================================
// Generic direct conv KxK (pad K/2) + bias. 8x8 tile.
// thread = (pixel, out-channel group of OPT)
// ============================================================
template <int CI, int CO, int K, int OPT, int THREADS>
__global__ __launch_bounds__(THREADS) void conv_kernel(
    const float* __restrict__ xin, const float* __restrict__ wT,
    const float* __restrict__ bias, float* __restrict__ out) {
  constexpr int PAD = K / 2;
  constexpr int T2 = 8 + K - 1;
  const int b = blockIdx.z;
  const int x0 = blockIdx.x * 8, y0 = blockIdx.y * 8;
  __shared__ float tile[CI][T2][T2];
  const float* xb = xin + (size_t)b * CI * NPIX;
  for (int t = threadIdx.x; t < CI * T2 * T2; t += THREADS) {
    int ci = t / (T2 * T2), rc = t % (T2 * T2), r = rc / T2, c = rc % T2;
    int gy = y0 - PAD + r, gx = x0 - PAD + c;
    float v = 0.f;
    if (gy >= 0 && gy < IH && gx >= 0 && gx < IW) v = xb[(size_t)ci * NPIX + gy * IW + gx];
    tile[ci][r][c] = v;
  }
  __syncthreads();
  const int t = threadIdx.x;
  const int px = t % 64, og = t / 64;
  const int pyy = px / 8, pxx = px % 8;
  const int oc0 = og * OPT;
  float acc[OPT] = {};
  for (int ky = 0; ky < K; ky++) {
    for (int kx = 0; kx < K; kx++) {
      const float* wrow = wT + (size_t)((ky * K + kx) * CI) * CO + oc0;
      for (int ci = 0; ci < CI; ci++) {
        float v = tile[ci][pyy + ky][pxx + kx];
        #pragma unroll
        for (int o = 0; o < OPT; o++) acc[o] = fmaf(v, wrow[ci * CO + o], acc[o]);
      }
    }
  }
  const int y = y0 + pyy, x = x0 + pxx;
  if (y < IH) {
    float* ob = out + (size_t)b * CO * NPIX;
    #pragma unroll
    for (int o = 0; o < OPT; o++)
      ob[(size_t)(oc0 + o) * NPIX + y * IW + x] = acc[o] + bias[oc0 + o];
  }
}

// ============================================================
// Guide: gt (B,3,H,W) -> (u,v) (B,2,H,W)
// ============================================================
__global__ __launch_bounds__(256) void guide_kernel(
    const float* __restrict__ gt, float* __restrict__ guide) {
  int i = blockIdx.x * 256 + threadIdx.x;
  if (i >= NB * NPIX) return;
  int b = i / NPIX, p = i % NPIX;
  const float* g0 = gt + (size_t)b * 3 * NPIX;
  float r = g0[p], g = g0[NPIX + p], bl = g0[2 * NPIX + p];
  float* ob = guide + (size_t)b * 2 * NPIX;
  ob[p]        = -0.147f * r - 0.289f * g + 0.436f * bl;
  ob[NPIX + p] =  0.615f * r - 0.515f * g - 0.100f * bl;
}

// ============================================================
// Joint bilateral 5x5, reflect padding. 16x16 tile.
// ============================================================
__global__ __launch_bounds__(256) void bilateral_kernel(
    const float* __restrict__ f, const float* __restrict__ guide,
    float* __restrict__ out) {
  const int b = blockIdx.z;
  const int x0 = blockIdx.x * 16, y0 = blockIdx.y * 16;
  __shared__ float gu[20][20], gv[20][20], f0s[20][20], f1s[20][20];
  const float* gb = guide + (size_t)b * 2 * NPIX;
  const float* fb = f + (size_t)b * 2 * NPIX;
  for (int t = threadIdx.x; t < 400; t += 256) {
    int r = t / 20, c = t % 20;
    int gy = y0 - 2 + r, gx = x0 - 2 + c;
    if (gy < 0) gy = -gy;
    if (gy > IH - 1) gy = 2 * (IH - 1) - gy;
    if (gx < 0) gx = -gx;
    if (gx > IW - 1) gx = 2 * (IW - 1) - gx;
    gu[r][c]  = gb[gy * IW + gx];
    gv[r][c]  = gb[NPIX + gy * IW + gx];
    f0s[r][c] = fb[gy * IW + gx];
    f1s[r][c] = fb[NPIX + gy * IW + gx];
  }
  __syncthreads();
  const int t = threadIdx.x;
  const int lx = t % 16, ly = t / 16;
  const int y = y0 + ly, x = x0 + lx;
  if (y >= IH) return;

  float g1v[5];
  {
    float s = 0.f;
    #pragma unroll
    for (int k = 0; k < 5; k++) {
      float a = (float)(k - 2);
      g1v[k] = expf(-a * a / 4.5f);
      s += g1v[k];
    }
    #pragma unroll
    for (int k = 0; k < 5; k++) g1v[k] /= s;
  }
  float cu = gu[ly + 2][lx + 2], cv = gv[ly + 2][lx + 2];
  float num0 = 0.f, num1 = 0.f, den = 0.f;
  #pragma unroll
  for (int dy = 0; dy < 5; dy++) {
    #pragma unroll
    for (int dx = 0; dx < 5; dx++) {
      float du = fabsf(gu[ly + dy][lx + dx] - cu) + fabsf(gv[ly + dy][lx + dx] - cv);
      float wgt = g1v[dy] * g1v[dx] * expf(-50.0f * du * du);
      num0 = fmaf(wgt, f0s[ly + dy][lx + dx], num0);
      num1 = fmaf(wgt, f1s[ly + dy][lx + dx], num1);
      den += wgt;
    }
  }
  float* ob = out + (size_t)b * 2 * NPIX;
  ob[y * IW + x] = num0 / den;
  ob[NPIX + y * IW + x] = num1 / den;
}

// ============================================================
// Global min/max over both channels (deterministic 2-stage)
// ============================================================
__global__ __launch_bounds__(256) void minmax_partial_kernel(
    const float* __restrict__ bil, float* __restrict__ part) {
  float mn0 = 1e30f, mx0 = -1e30f, mn1 = 1e30f, mx1 = -1e30f;
  for (size_t i = (size_t)blockIdx.x * 256 + threadIdx.x; i < (size_t)NB * NPIX;
       i += 256 * 256) {
    int b = (int)(i / NPIX), p = (int)(i % NPIX);
    float v0 = bil[(size_t)b * 2 * NPIX + p];
    float v1 = bil[(size_t)b * 2 * NPIX + NPIX + p];
    mn0 = fminf(mn0, v0); mx0 = fmaxf(mx0, v0);
    mn1 = fminf(mn1, v1); mx1 = fmaxf(mx1, v1);
  }
  __shared__ float sh[4][256];
  sh[0][threadIdx.x] = mn0; sh[1][threadIdx.x] = mx0;
  sh[2][threadIdx.x] = mn1; sh[3][threadIdx.x] = mx1;
  __syncthreads();
  for (int off = 128; off > 0; off >>= 1) {
    if (threadIdx.x < off) {
      sh[0][threadIdx.x] = fminf(sh[0][threadIdx.x], sh[0][threadIdx.x + off]);
      sh[1][threadIdx.x] = fmaxf(sh[1][threadIdx.x], sh[1][threadIdx.x + off]);
      sh[2][threadIdx.x] = fminf(sh[2][threadIdx.x], sh[2][threadIdx.x + off]);
      sh[3][threadIdx.x] = fmaxf(sh[3][threadIdx.x], sh[3][threadIdx.x + off]);
    }
    __syncthreads();
  }
  if (threadIdx.x == 0) {
    part[blockIdx.x * 4 + 0] = sh[0][0];
    part[blockIdx.x * 4 + 1] = sh[1][0];
    part[blockIdx.x * 4 + 2] = sh[2][0];
    part[blockIdx.x * 4 + 3] = sh[3][0];
  }
}

__global__ __launch_bounds__(256) void minmax_final_kernel(
    const float* __restrict__ part, float* __restrict__ mm) {
  __shared__ float sh[4][256];
  int t = threadIdx.x;
  sh[0][t] = part[t * 4 + 0];
  sh[1][t] = part[t * 4 + 1];
  sh[2][t] = part[t * 4 + 2];
  sh[3][t] = part[t * 4 + 3];
  __syncthreads();
  for (int off = 128; off > 0; off >>= 1) {
    if (t < off) {
      sh[0][t] = fminf(sh[0][t], sh[0][t + off]);
      sh[1][t] = fmaxf(sh[1][t], sh[1][t + off]);
      sh[2][t] = fminf(sh[2][t], sh[2][t + off]);
      sh[3][t] = fmaxf(sh[3][t], sh[3][t + off]);
    }
    __syncthreads();
  }
  if (t == 0) {
    mm[0] = sh[0][0]; mm[1] = sh[1][0]; mm[2] = sh[2][0]; mm[3] = sh[3][0];
  }
}

// ============================================================
// Final: rescale U/V, YUV->RGB composite
// ============================================================
__global__ __launch_bounds__(256) void final_kernel(
    const float* __restrict__ bil, const float* __restrict__ x,
    const float* __restrict__ mm, float* __restrict__ out) {
  int i = blockIdx.x * 256 + threadIdx.x;
  if (i >= NB * NPIX) return;
  int b = i / NPIX, p = i % NPIX;
  float f0 = bil[(size_t)b * 2 * NPIX + p];
  float f1 = bil[(size_t)b * 2 * NPIX + NPIX + p];
  float U = (f0 - mm[0]) / (mm[1] - mm[0] + 1e-6f);
  U = fminf(fmaxf(U, 0.f), 1.f) * 0.872f - 0.436f;
  float V = (f1 - mm[2]) / (mm[3] - mm[2] + 1e-6f);
  V = fminf(fmaxf(V, 0.f), 1.f) * 1.23f - 0.615f;
  float Y = x[(size_t)b * NPIX + p];
  float* ob = out + (size_t)b * 3 * NPIX;
  ob[p]            = Y + 1.14f * V;
  ob[NPIX + p]     = Y - 0.396f * U - 0.581f * V;
  ob[2 * NPIX + p] = Y + 2.029f * U;
}

// ============================================================
// launch
// ============================================================
extern "C" void kernel_launch(void* const* d_in, const int* in_sizes, int n_in,
                              void* d_out, int out_size, void* d_ws, size_t ws_size,
                              hipStream_t stream) {
  const float* x   = (const float*)d_in[0];
  const float* gt  = (const float*)d_in[1];
  const float* w1  = (const float*)d_in[2];
  const float* b1  = (const float*)d_in[3];
  const float* g1w = (const float*)d_in[4];
  const float* g1b = (const float*)d_in[5];
  const float* w2  = (const float*)d_in[6];
  const float* b2  = (const float*)d_in[7];
  const float* g2w = (const float*)d_in[8];
  const float* g2b = (const float*)d_in[9];
  const float* w3  = (const float*)d_in[10];
  const float* b3  = (const float*)d_in[11];
  const float* g3w = (const float*)d_in[12];
  const float* g3b = (const float*)d_in[13];
  const float* w4  = (const float*)d_in[14];
  const float* b4  = (const float*)d_in[15];
  const float* g4w = (const float*)d_in[16];
  const float* g4b = (const float*)d_in[17];
  const float* w5  = (const float*)d_in[18];
  const float* b5  = (const float*)d_in[19];
  float* out = (float*)d_out;

  // ---- workspace layout (bump allocation with aliasing) ----
  char* ws = (char*)d_ws;
  double* stats = (double*)ws;               // 64 doubles max per stage (reused)
  float* coefA  = (float*)(ws + 2048);       // 256 floats
  float* coefB  = (float*)(ws + 3072);       // 256 floats
  float* mmpart = (float*)(ws + 4096);       // 1024 floats
  float* mm     = (float*)(ws + 8192);       // 4 floats
  float* fbase  = (float*)(ws + 16384);
  size_t off = 0;
  float* pooled = fbase + off; off += 4452864;   // NB*8*PH*PW = 4,448,736
  float* s1g    = fbase + off; off += 1105920;   // NB*2*NPIX
  float* w1T    = fbase + off; off += 204800;
  float* w2T    = fbase + off; off += 18432;
  float* w3T    = fbase + off; off += 4608;
  float* w4T    = fbase + off; off += 1152;
  float* w5T    = fbase + off; off += 256;
  float* bufA   = fbase + off; off += 35389440;  // 64ch fp32 (also c3)
  float* bufB   = fbase + off; off += 17694720;  // 32ch fp32 (also c4)
  float* c5     = pooled;                        // alias: pooled dead by conv5
  float* bilat  = pooled + 1105920;              // alias: still inside pooled region
  float* guide  = s1g;                           // alias: s1g dead after conv1

  // ---- weight repacks ----
  {
    int tot;
    tot = 64 * 128 * 25;
    repack_kernel<<<(tot + 255) / 256, 256, 0, stream>>>(w1, w1T, 64, 128, 25);
    tot = 32 * 64 * 9;
    repack_kernel<<<(tot + 255) / 256, 256, 0, stream>>>(w2, w2T, 32, 64, 9);
    tot = 16 * 32 * 9;
    repack_kernel<<<(tot + 255) / 256, 256, 0, stream>>>(w3, w3T, 16, 32, 9);
    tot = 8 * 16 * 9;
    repack_kernel<<<(tot + 255) / 256, 256, 0, stream>>>(w4, w4T, 8, 16, 9);
    tot = 2 * 8 * 9;
    repack_kernel<<<(tot + 255) / 256, 256, 0, stream>>>(w5, w5T, 2, 8, 9);
  }

  // ---- SIFT front-end ----
  pooled_kernel<<<dim3(33, 17, NB), 256, 0, stream>>>(x, pooled);
  sift_scalars_kernel<<<dim3(32, 17, NB), 256, 0, stream>>>(pooled, s1g);
  conv1_kernel<<<dim3(64, 34, NB), 256, 0, stream>>>(pooled, s1g, w1T, b1, bufA);

  // ---- GN1 + ReLU (C=64, 8 groups) ----
  gn_stats_kernel<<<NB * 64, 256, 0, stream>>>(bufA, stats);
  gn_coef_kernel<<<(NB * 64 + 63) / 64, 64, 0, stream>>>(stats, g1w, g1b, coefA, coefB, 64, 8);
  gn_apply_kernel<<<4096, 256, 0, stream>>>(bufA, coefA, coefB, 64);

  // ---- conv2 (64->32) + GN2 (8 groups) ----
  conv_kernel<64, 32, 3, 8, 256><<<dim3(64, 34, NB), 256, 0, stream>>>(bufA, w2T, b2, bufB);
  gn_stats_kernel<<<NB * 32, 256, 0, stream>>>(bufB, stats);
  gn_coef_kernel<<<(NB * 32 + 63) / 64, 64, 0, stream>>>(stats, g2w, g2b, coefA, coefB, 32, 4);
  gn_apply_kernel<<<2048, 256, 0, stream>>>(bufB, coefA, coefB, 32);

  // ---- conv3 (32->16) + GN3 (4 groups) ---- (c3 aliases bufA)
  conv_kernel<32, 16, 3, 4, 256><<<dim3(64, 34, NB), 256, 0, stream>>>(bufB, w3T, b3, bufA);
  gn_stats_kernel<<<NB * 16, 256, 0, stream>>>(bufA, stats);
  gn_coef_kernel<<<(NB * 16 + 63) / 64, 64, 0, stream>>>(stats, g3w, g3b, coefA, coefB, 16, 4);
  gn_apply_kernel<<<1024, 256, 0, stream>>>(bufA, coefA, coefB, 16);

  // ---- conv4 (16->8) + GN4 (4 groups) ---- (c4 aliases bufB)
  conv_kernel<16, 8, 3, 2, 256><<<dim3(64, 34, NB), 256, 0, stream>>>(bufA, w4T, b4, bufB);
  gn_stats_kernel<<<NB * 8, 256, 0, stream>>>(bufB, stats);
  gn_coef_kernel<<<(NB * 8 + 63) / 64, 64, 0, stream>>>(stats, g4w, g4b, coefA, coefB, 8, 2);
  gn_apply_kernel<<<512, 256, 0, stream>>>(bufB, coefA, coefB, 8);

  // ---- conv5 (8->2), no GN ----
  conv_kernel<8, 2, 3, 1, 128><<<dim3(64, 34, NB), 128, 0, stream>>>(bufB, w5T, b5, c5);

  // ---- bilateral + rescale + composite ----
  guide_kernel<<<(NB * NPIX + 255) / 256, 256, 0, stream>>>(gt, guide);
  bilateral_kernel<<<dim3(32, 17, NB), 256, 0, stream>>>(c5, guide, bilat);
  minmax_partial_kernel<<<256, 256, 0, stream>>>(bilat, mmpart);
  minmax_final_kernel<<<1, 256, 0, stream>>>(mmpart, mm);
  final_kernel<<<(NB * NPIX + 255) / 256, 256, 0, stream>>>(bilat, x, mm, out);

  (void)in_sizes; (void)n_in; (void)out_size; (void)ws_size;
}

// Round 2
// 1623.413 us; speedup vs baseline: 8.8142x; 8.8142x over previous
//
#include <hip/hip_runtime.h>

// ---------------- problem constants ----------------
constexpr int NB  = 4;
constexpr int IH  = 270;
constexpr int IW  = 512;
constexpr int NPIX = IH * IW;      // 138240
constexpr int PH  = 271;           // pooled height
constexpr int PW  = 513;           // pooled width
constexpr float TWO_PI_F = 6.28318530717958647692f;

typedef short  bf16x8 __attribute__((ext_vector_type(8)));
typedef float floatx4 __attribute__((ext_vector_type(4)));

__device__ inline short f2bf(float x) {
  union { float f; unsigned u; } un; un.f = x;
  unsigned r = un.u + 0x7fff + ((un.u >> 16) & 1);   // RNE
  return (short)(r >> 16);
}

// ============================================================
// Stage 1: x -> pooled (8 ch, PH x PW).
// ============================================================
__global__ __launch_bounds__(256) void pooled_kernel(
    const float* __restrict__ x, float* __restrict__ pooled) {
  const int b = blockIdx.z;
  const int px0 = blockIdx.x * 16, py0 = blockIdx.y * 16;
  __shared__ float wo0s[19][19];
  __shared__ float wo1s[19][19];
  __shared__ int   bo0s[19][19];
  const float* xb = x + (size_t)b * NPIX;

  for (int t = threadIdx.x; t < 19 * 19; t += 256) {
    int r = t / 19, c = t % 19;
    int gy = py0 - 2 + r, gx = px0 - 2 + c;
    float w0 = 0.f, w1v = 0.f; int b0 = 0;
    if (gy >= 0 && gy < IH && gx >= 0 && gx < IW) {
      int xm = gx > 0 ? gx - 1 : 0, xp = gx < IW - 1 ? gx + 1 : IW - 1;
      int ym = gy > 0 ? gy - 1 : 0, yp = gy < IH - 1 ? gy + 1 : IH - 1;
      float gxv = (xb[gy * IW + xp] - xb[gy * IW + xm]) * 0.5f;
      float gyv = (xb[yp * IW + gx] - xb[ym * IW + gx]) * 0.5f;
      float mag = sqrtf(gxv * gxv + gyv * gyv + 1e-10f);
      float ori = atan2f(gyv, gxv + 1e-10f) + TWO_PI_F;
      float obig = ori * (8.0f / TWO_PI_F);
      float bf = floorf(obig);
      float w1_ = obig - bf;
      w0  = (1.0f - w1_) * mag;
      w1v = w1_ * mag;
      b0  = ((int)bf) & 7;
    }
    wo0s[r][c] = w0; wo1s[r][c] = w1v; bo0s[r][c] = b0;
  }
  __syncthreads();

  const int t = threadIdx.x;
  const int lx = t % 16, ly = t / 16;
  const int py = py0 + ly, px = px0 + lx;
  if (py >= PH || px >= PW) return;

  const float pwt[4] = {0.25f, 0.75f, 0.75f, 0.25f};
  float acc[8] = {0, 0, 0, 0, 0, 0, 0, 0};
  for (int i = 0; i < 4; i++) {
    for (int j = 0; j < 4; j++) {
      int r = ly + i, c = lx + j;
      float w0 = wo0s[r][c], w1v = wo1s[r][c];
      int b0 = bo0s[r][c];
      int b1i = (b0 + 1) & 7;
      float pw = pwt[i] * pwt[j];
      #pragma unroll
      for (int a = 0; a < 8; a++) {
        float add = (a == b0 ? w0 : 0.f) + (a == b1i ? w1v : 0.f);
        acc[a] = fmaf(pw, add, acc[a]);
      }
    }
  }
  float* pb = pooled + (size_t)b * 8 * PH * PW;
  #pragma unroll
  for (int a = 0; a < 8; a++) pb[((size_t)a * PH + py) * PW + px] = acc[a];
}

// ============================================================
// Stage 2: per-pixel SIFT normalization scalars s1, g
// ============================================================
__global__ __launch_bounds__(256) void sift_scalars_kernel(
    const float* __restrict__ pooled, float* __restrict__ s1g) {
  const int b = blockIdx.z;
  const int x0 = blockIdx.x * 16, y0 = blockIdx.y * 16;
  __shared__ float pt[8][19][19];
  const float* pb = pooled + (size_t)b * 8 * PH * PW;
  for (int t = threadIdx.x; t < 8 * 19 * 19; t += 256) {
    int a = t / 361, rc = t % 361, r = rc / 19, c = rc % 19;
    int gy = y0 - 1 + r, gx = x0 - 1 + c;
    float v = 0.f;
    if (gy >= 0 && gy < PH && gx >= 0 && gx < PW) v = pb[((size_t)a * PH + gy) * PW + gx];
    pt[a][r][c] = v;
  }
  __syncthreads();
  const int t = threadIdx.x;
  const int lx = t % 16, ly = t / 16;
  const int y = y0 + ly, x = x0 + lx;
  if (y >= IH) return;

  float sum2 = 0.f;
  for (int c = 0; c < 128; c++) {
    int a = c >> 4, i = (c >> 2) & 3, j = c & 3;
    float p = pt[a][ly + i][lx + j];
    sum2 = fmaf(p, p, sum2);
  }
  float s1 = 1.0f / fmaxf(sqrtf(sum2), 1e-12f);
  float st2 = 0.f, st = 0.f;
  for (int c = 0; c < 128; c++) {
    int a = c >> 4, i = (c >> 2) & 3, j = c & 3;
    float p = pt[a][ly + i][lx + j];
    float tv = fminf(p * s1, 0.2f);
    st2 = fmaf(tv, tv, st2);
    st += tv;
  }
  float s2 = 1.0f / fmaxf(sqrtf(st2), 1e-12f);
  float l1 = fmaxf(s2 * st, 1e-12f);
  float g = s2 / l1;
  float* o = s1g + (size_t)b * 2 * NPIX;
  o[y * IW + x] = s1;
  o[NPIX + y * IW + x] = g;
}

// ============================================================
// Weight repack (fp32 path, conv4/conv5): w[CO][CI][K*K] -> wT[K*K][CI][CO]
// ============================================================
__global__ void repack_kernel(const float* __restrict__ w, float* __restrict__ wT,
                              int CO, int CI, int KK) {
  int i = blockIdx.x * 256 + threadIdx.x;
  int total = CO * CI * KK;
  if (i >= total) return;
  int o = i / (CI * KK);
  int r = i % (CI * KK);
  int ci = r / KK, kk = r % KK;
  wT[(kk * CI + ci) * CO + o] = w[i];
}

// ============================================================
// MFMA B-operand pack: w[CO][CI][KK] fp32 -> fragment-ordered bf16
// frag f = (g*CHUNKS + cc)*KK + t ; lane l holds B[k=quad*8+j][n=l&15]
//   ci = cc*32 + (l>>4)*8 + j, co = g*16 + (l&15)
// ============================================================
__global__ void mfma_pack_kernel(const float* __restrict__ w, short* __restrict__ wB,
                                 int CO, int CI, int KK) {
  int CHUNKS = (CI + 31) / 32;
  int GG = (CO + 15) / 16;
  int total = GG * CHUNKS * KK * 512;
  for (int i = blockIdx.x * 256 + threadIdx.x; i < total; i += gridDim.x * 256) {
    int j = i & 7, l = (i >> 3) & 63, f = i >> 9;
    int t = f % KK; int fc = f / KK; int cc = fc % CHUNKS; int g = fc / CHUNKS;
    int ci = cc * 32 + ((l >> 4) << 3) + j;
    int co = g * 16 + (l & 15);
    float v = (ci < CI && co < CO) ? w[((size_t)co * CI + ci) * KK + t] : 0.f;
    wB[i] = f2bf(v);
  }
}

// ============================================================
// Conv1 via MFMA: desc (128ch SIFT) regenerated per 32-ch chunk into LDS
// as bf16 A-operands; 5x5 conv 128->64 as implicit GEMM (K=3200).
// Block: 8x8 pixels, 4 waves (wave = 16-co group). grid (64,34,NB)
// ============================================================
__global__ __launch_bounds__(256) void conv1_mfma_kernel(
    const float* __restrict__ pooled, const float* __restrict__ s1g,
    const short* __restrict__ w1B, const float* __restrict__ bias,
    float* __restrict__ out) {
  const int b = blockIdx.z;
  const int x0 = blockIdx.x * 8, y0 = blockIdx.y * 8;
  __shared__ __align__(16) float smem[4968];
  float* pt = smem;                         // [8][15][15] pooled tile
  float* sc = smem + 1800;                  // [2][144]
  short* desc = (short*)(smem + 2088);      // [144 pos][stride 40] bf16
  const int tid = threadIdx.x;
  const int wave = tid >> 6, lane = tid & 63;
  const int quad = lane >> 4, lm = lane & 15;

  const float* pb = pooled + (size_t)b * 8 * PH * PW;
  for (int t = tid; t < 1800; t += 256) {
    int a = t / 225, rc = t % 225, r = rc / 15, c = rc % 15;
    int gy = y0 - 3 + r, gx = x0 - 3 + c;
    float v = 0.f;
    if (gy >= 0 && gy < PH && gx >= 0 && gx < PW) v = pb[((size_t)a * PH + gy) * PW + gx];
    pt[t] = v;
  }
  const float* sb = s1g + (size_t)b * 2 * NPIX;
  for (int t = tid; t < 144; t += 256) {
    int r = t / 12, c = t % 12;
    int gy = y0 - 2 + r, gx = x0 - 2 + c;
    float a0 = 0.f, a1 = 0.f;
    if (gy >= 0 && gy < IH && gx >= 0 && gx < IW) {
      a0 = sb[gy * IW + gx];
      a1 = sb[NPIX + gy * IW + gx];
    }
    sc[t] = a0; sc[144 + t] = a1;
  }

  // per-M-tile A base addresses (short index); tap offset added as immediate
  int abase[4];
  #pragma unroll
  for (int mt = 0; mt < 4; mt++) {
    int pixel = mt * 16 + lm;
    abase[mt] = ((pixel >> 3) * 12 + (pixel & 7)) * 40 + quad * 8;
  }

  floatx4 acc[4];
  #pragma unroll
  for (int mt = 0; mt < 4; mt++) acc[mt] = (floatx4){0.f, 0.f, 0.f, 0.f};

  for (int cc = 0; cc < 4; cc++) {
    __syncthreads();   // previous chunk fully consumed (and initial loads done)
    for (int v = tid; v < 1152; v += 256) {
      int pos = v % 144, cg = v / 144;      // cg: group of 4 ci
      int r = pos / 12, c = pos % 12;
      int gy = y0 - 2 + r, gx = x0 - 2 + c;
      bool ok = (gy >= 0 && gy < IH && gx >= 0 && gx < IW);
      int ci0 = cc * 32 + cg * 4;
      int a = ci0 >> 4, i = (ci0 >> 2) & 3; // j = 0..3 contiguous
      float s1v = sc[pos], gv = sc[144 + pos];
      const float* prow = pt + a * 225 + (r + i) * 15 + c;
      unsigned short o4[4];
      #pragma unroll
      for (int q = 0; q < 4; q++) {
        float p = prow[q];
        float val = ok ? sqrtf(fminf(p * s1v, 0.2f) * gv + 1e-10f) : 0.f;
        o4[q] = (unsigned short)f2bf(val);
      }
      uint2 pk;
      pk.x = (unsigned)o4[0] | ((unsigned)o4[1] << 16);
      pk.y = (unsigned)o4[2] | ((unsigned)o4[3] << 16);
      *(uint2*)(desc + pos * 40 + cg * 4) = pk;
    }
    __syncthreads();

    #pragma unroll
    for (int ky = 0; ky < 5; ky++) {
      bf16x8 bfr[5];
      #pragma unroll
      for (int kx = 0; kx < 5; kx++) {
        int f = (wave * 4 + cc) * 25 + ky * 5 + kx;
        bfr[kx] = *(const bf16x8*)(w1B + ((size_t)f << 9) + (lane << 3));
      }
      #pragma unroll
      for (int kx = 0; kx < 5; kx++) {
        #pragma unroll
        for (int mt = 0; mt < 4; mt++) {
          bf16x8 av = *(const bf16x8*)(desc + abase[mt] + (ky * 12 + kx) * 40);
          acc[mt] = __builtin_amdgcn_mfma_f32_16x16x32_bf16(av, bfr[kx], acc[mt], 0, 0, 0);
        }
      }
    }
  }
  __syncthreads();
  // C/D: col=lane&15 (co), row=quad*4+reg (pixel-in-tile). Transpose via LDS.
  float* cout = smem;  // [64 co][65]
  #pragma unroll
  for (int mt = 0; mt < 4; mt++) {
    #pragma unroll
    for (int r = 0; r < 4; r++) {
      int pixel = mt * 16 + quad * 4 + r;
      cout[(wave * 16 + lm) * 65 + pixel] = acc[mt][r];
    }
  }
  __syncthreads();
  float* ob = out + (size_t)b * 64 * NPIX;
  for (int v = tid; v < 4096; v += 256) {
    int co = v >> 6, pix = v & 63;
    int y = y0 + (pix >> 3), x = x0 + (pix & 7);
    if (y < IH) ob[(size_t)co * NPIX + y * IW + x] = cout[co * 65 + pix] + bias[co];
  }
}

// ============================================================
// Generic 3x3 conv via MFMA (CI,CO multiples of 32/16). 8x8 tile.
// ============================================================
template <int CI, int CO>
__global__ __launch_bounds__(256) void convk3_mfma_kernel(
    const float* __restrict__ xin, const short* __restrict__ wB,
    const float* __restrict__ bias, float* __restrict__ out) {
  constexpr int CHUNKS = CI / 32;
  constexpr int G = CO / 16;           // co-groups
  constexpr int WPG = 4 / G;           // waves per co-group
  constexpr int TPW = G;               // M-tiles per wave
  constexpr int CIS = CHUNKS * 32 + 8; // LDS stride (shorts) per position
  const int b = blockIdx.z;
  const int x0 = blockIdx.x * 8, y0 = blockIdx.y * 8;
  __shared__ __align__(16) short tile[100 * CIS];
  __shared__ float cout[CO * 65];
  const int tid = threadIdx.x;
  const int wave = tid >> 6, lane = tid & 63;
  const int quad = lane >> 4, lm = lane & 15;
  const int g = wave / WPG, mh = wave % WPG;

  const float* xb = xin + (size_t)b * CI * NPIX;
  for (int v = tid; v < (CI / 2) * 100; v += 256) {
    int cp = v / 100, pos = v % 100;
    int r = pos / 10, c = pos % 10;
    int gy = y0 - 1 + r, gx = x0 - 1 + c;
    float v0 = 0.f, v1 = 0.f;
    if (gy >= 0 && gy < IH && gx >= 0 && gx < IW) {
      v0 = xb[(size_t)(2 * cp) * NPIX + gy * IW + gx];
      v1 = xb[(size_t)(2 * cp + 1) * NPIX + gy * IW + gx];
    }
    unsigned pk = (unsigned)(unsigned short)f2bf(v0) |
                  ((unsigned)(unsigned short)f2bf(v1) << 16);
    *(unsigned*)(tile + pos * CIS + 2 * cp) = pk;
  }
  __syncthreads();

  int abase[TPW];
  #pragma unroll
  for (int i = 0; i < TPW; i++) {
    int pixel = (mh * TPW + i) * 16 + lm;
    abase[i] = ((pixel >> 3) * 10 + (pixel & 7)) * CIS + quad * 8;
  }

  floatx4 acc[TPW];
  #pragma unroll
  for (int i = 0; i < TPW; i++) acc[i] = (floatx4){0.f, 0.f, 0.f, 0.f};

  #pragma unroll
  for (int cc = 0; cc < CHUNKS; cc++) {
    #pragma unroll
    for (int ky = 0; ky < 3; ky++) {
      bf16x8 bfr[3];
      #pragma unroll
      for (int kx = 0; kx < 3; kx++) {
        int f = (g * CHUNKS + cc) * 9 + ky * 3 + kx;
        bfr[kx] = *(const bf16x8*)(wB + ((size_t)f << 9) + (lane << 3));
      }
      #pragma unroll
      for (int kx = 0; kx < 3; kx++) {
        #pragma unroll
        for (int i = 0; i < TPW; i++) {
          bf16x8 av = *(const bf16x8*)(tile + abase[i] + cc * 32 + (ky * 10 + kx) * CIS);
          acc[i] = __builtin_amdgcn_mfma_f32_16x16x32_bf16(av, bfr[kx], acc[i], 0, 0, 0);
        }
      }
    }
  }
  #pragma unroll
  for (int i = 0; i < TPW; i++) {
    #pragma unroll
    for (int r = 0; r < 4; r++) {
      int pixel = (mh * TPW + i) * 16 + quad * 4 + r;
      cout[(g * 16 + lm) * 65 + pixel] = acc[i][r];
    }
  }
  __syncthreads();
  float* ob = out + (size_t)b * CO * NPIX;
  for (int v = tid; v < CO * 64; v += 256) {
    int co = v >> 6, pix = v & 63;
    int y = y0 + (pix >> 3), x = x0 + (pix & 7);
    if (y < IH) ob[(size_t)co * NPIX + y * IW + x] = cout[co * 65 + pix] + bias[co];
  }
}

// ============================================================
// GroupNorm: per-(b,c)-plane sums (fp64), coefs, fused apply+ReLU.
// ============================================================
__global__ __launch_bounds__(256) void gn_stats_kernel(
    const float* __restrict__ xin, double* __restrict__ stats_pc) {
  const int bc = blockIdx.x;
  const float* p = xin + (size_t)bc * NPIX;
  double s = 0.0, s2 = 0.0;
  for (int i = threadIdx.x; i < NPIX; i += 256) {
    float v = p[i];
    s += v;
    s2 += (double)v * v;
  }
  __shared__ double sh0[256];
  __shared__ double sh1[256];
  sh0[threadIdx.x] = s; sh1[threadIdx.x] = s2;
  __syncthreads();
  for (int off = 128; off > 0; off >>= 1) {
    if (threadIdx.x < off) {
      sh0[threadIdx.x] += sh0[threadIdx.x + off];
      sh1[threadIdx.x] += sh1[threadIdx.x + off];
    }
    __syncthreads();
  }
  if (threadIdx.x == 0) {
    stats_pc[bc * 2] = sh0[0];
    stats_pc[bc * 2 + 1] = sh1[0];
  }
}

__global__ void gn_coef_kernel(const double* __restrict__ stats_pc,
                               const float* __restrict__ gamma,
                               const float* __restrict__ beta,
                               float* __restrict__ cA, float* __restrict__ cB,
                               int C, int chper) {
  int i = blockIdx.x * 64 + threadIdx.x;
  if (i >= NB * C) return;
  int b = i / C, c = i % C;
  int g0 = (c / chper) * chper;
  double S = 0.0, S2 = 0.0;
  for (int k = 0; k < chper; k++) {
    S  += stats_pc[(b * C + g0 + k) * 2];
    S2 += stats_pc[(b * C + g0 + k) * 2 + 1];
  }
  double Nd = (double)chper * NPIX;
  double mu = S / Nd;
  double var = S2 / Nd - mu * mu;
  double rstd = 1.0 / sqrt(var + 1e-5);
  float A = (float)rstd * gamma[c];
  cA[i] = A;
  cB[i] = beta[c] - (float)mu * A;
}

__global__ __launch_bounds__(256) void gn_apply_kernel(
    float* __restrict__ xio, const float* __restrict__ cA,
    const float* __restrict__ cB, int C) {
  size_t total = (size_t)NB * C * NPIX;
  for (size_t i = (size_t)blockIdx.x * 256 + threadIdx.x; i < total;
       i += (size_t)gridDim.x * 256) {
    size_t bc = i / NPIX;
    float v = fmaf(xio[i], cA[bc], cB[bc]);
    xio[i] = v > 0.f ? v : 0.f;
  }
}

// ============================================================
// Direct fp32 conv KxK + bias (small tail convs). 8x8 tile.
// ============================================================
template <int CI, int CO, int K, int OPT, int THREADS>
__global__ __launch_bounds__(THREADS) void conv_kernel(
    const float* __restrict__ xin, const float* __restrict__ wT,
    const float* __restrict__ bias, float* __restrict__ out) {
  constexpr int PAD = K / 2;
  constexpr int T2 = 8 + K - 1;
  const int b = blockIdx.z;
  const int x0 = blockIdx.x * 8, y0 = blockIdx.y * 8;
  __shared__ float tile[CI][T2][T2];
  const float* xb = xin + (size_t)b * CI * NPIX;
  for (int t = threadIdx.x; t < CI * T2 * T2; t += THREADS) {
    int ci = t / (T2 * T2), rc = t % (T2 * T2), r = rc / T2, c = rc % T2;
    int gy = y0 - PAD + r, gx = x0 - PAD + c;
    float v = 0.f;
    if (gy >= 0 && gy < IH && gx >= 0 && gx < IW) v = xb[(size_t)ci * NPIX + gy * IW + gx];
    tile[ci][r][c] = v;
  }
  __syncthreads();
  const int t = threadIdx.x;
  const int px = t % 64, og = t / 64;
  const int pyy = px / 8, pxx = px % 8;
  const int oc0 = og * OPT;
  float acc[OPT] = {};
  for (int ky = 0; ky < K; ky++) {
    for (int kx = 0; kx < K; kx++) {
      const float* wrow = wT + (size_t)((ky * K + kx) * CI) * CO + oc0;
      for (int ci = 0; ci < CI; ci++) {
        float v = tile[ci][pyy + ky][pxx + kx];
        #pragma unroll
        for (int o = 0; o < OPT; o++) acc[o] = fmaf(v, wrow[ci * CO + o], acc[o]);
      }
    }
  }
  const int y = y0 + pyy, x = x0 + pxx;
  if (y < IH) {
    float* ob = out + (size_t)b * CO * NPIX;
    #pragma unroll
    for (int o = 0; o < OPT; o++)
      ob[(size_t)(oc0 + o) * NPIX + y * IW + x] = acc[o] + bias[oc0 + o];
  }
}

// ============================================================
// Guide: gt (B,3,H,W) -> (u,v)
// ============================================================
__global__ __launch_bounds__(256) void guide_kernel(
    const float* __restrict__ gt, float* __restrict__ guide) {
  int i = blockIdx.x * 256 + threadIdx.x;
  if (i >= NB * NPIX) return;
  int b = i / NPIX, p = i % NPIX;
  const float* g0 = gt + (size_t)b * 3 * NPIX;
  float r = g0[p], g = g0[NPIX + p], bl = g0[2 * NPIX + p];
  float* ob = guide + (size_t)b * 2 * NPIX;
  ob[p]        = -0.147f * r - 0.289f * g + 0.436f * bl;
  ob[NPIX + p] =  0.615f * r - 0.515f * g - 0.100f * bl;
}

// ============================================================
// Joint bilateral 5x5 (reflect). 16x16 tile.
// ============================================================
__global__ __launch_bounds__(256) void bilateral_kernel(
    const float* __restrict__ f, const float* __restrict__ guide,
    float* __restrict__ out) {
  const int b = blockIdx.z;
  const int x0 = blockIdx.x * 16, y0 = blockIdx.y * 16;
  __shared__ float gu[20][20], gv[20][20], f0s[20][20], f1s[20][20];
  const float* gb = guide + (size_t)b * 2 * NPIX;
  const float* fb = f + (size_t)b * 2 * NPIX;
  for (int t = threadIdx.x; t < 400; t += 256) {
    int r = t / 20, c = t % 20;
    int gy = y0 - 2 + r, gx = x0 - 2 + c;
    if (gy < 0) gy = -gy;
    if (gy > IH - 1) gy = 2 * (IH - 1) - gy;
    if (gx < 0) gx = -gx;
    if (gx > IW - 1) gx = 2 * (IW - 1) - gx;
    gu[r][c]  = gb[gy * IW + gx];
    gv[r][c]  = gb[NPIX + gy * IW + gx];
    f0s[r][c] = fb[gy * IW + gx];
    f1s[r][c] = fb[NPIX + gy * IW + gx];
  }
  __syncthreads();
  const int t = threadIdx.x;
  const int lx = t % 16, ly = t / 16;
  const int y = y0 + ly, x = x0 + lx;
  if (y >= IH) return;

  float g1v[5];
  {
    float s = 0.f;
    #pragma unroll
    for (int k = 0; k < 5; k++) {
      float a = (float)(k - 2);
      g1v[k] = expf(-a * a / 4.5f);
      s += g1v[k];
    }
    #pragma unroll
    for (int k = 0; k < 5; k++) g1v[k] /= s;
  }
  float cu = gu[ly + 2][lx + 2], cv = gv[ly + 2][lx + 2];
  float num0 = 0.f, num1 = 0.f, den = 0.f;
  #pragma unroll
  for (int dy = 0; dy < 5; dy++) {
    #pragma unroll
    for (int dx = 0; dx < 5; dx++) {
      float du = fabsf(gu[ly + dy][lx + dx] - cu) + fabsf(gv[ly + dy][lx + dx] - cv);
      float wgt = g1v[dy] * g1v[dx] * expf(-50.0f * du * du);
      num0 = fmaf(wgt, f0s[ly + dy][lx + dx], num0);
      num1 = fmaf(wgt, f1s[ly + dy][lx + dx], num1);
      den += wgt;
    }
  }
  float* ob = out + (size_t)b * 2 * NPIX;
  ob[y * IW + x] = num0 / den;
  ob[NPIX + y * IW + x] = num1 / den;
}

// ============================================================
// Global min/max (deterministic 2-stage)
// ============================================================
__global__ __launch_bounds__(256) void minmax_partial_kernel(
    const float* __restrict__ bil, float* __restrict__ part) {
  float mn0 = 1e30f, mx0 = -1e30f, mn1 = 1e30f, mx1 = -1e30f;
  for (size_t i = (size_t)blockIdx.x * 256 + threadIdx.x; i < (size_t)NB * NPIX;
       i += 256 * 256) {
    int b = (int)(i / NPIX), p = (int)(i % NPIX);
    float v0 = bil[(size_t)b * 2 * NPIX + p];
    float v1 = bil[(size_t)b * 2 * NPIX + NPIX + p];
    mn0 = fminf(mn0, v0); mx0 = fmaxf(mx0, v0);
    mn1 = fminf(mn1, v1); mx1 = fmaxf(mx1, v1);
  }
  __shared__ float sh[4][256];
  sh[0][threadIdx.x] = mn0; sh[1][threadIdx.x] = mx0;
  sh[2][threadIdx.x] = mn1; sh[3][threadIdx.x] = mx1;
  __syncthreads();
  for (int off = 128; off > 0; off >>= 1) {
    if (threadIdx.x < off) {
      sh[0][threadIdx.x] = fminf(sh[0][threadIdx.x], sh[0][threadIdx.x + off]);
      sh[1][threadIdx.x] = fmaxf(sh[1][threadIdx.x], sh[1][threadIdx.x + off]);
      sh[2][threadIdx.x] = fminf(sh[2][threadIdx.x], sh[2][threadIdx.x + off]);
      sh[3][threadIdx.x] = fmaxf(sh[3][threadIdx.x], sh[3][threadIdx.x + off]);
    }
    __syncthreads();
  }
  if (threadIdx.x == 0) {
    part[blockIdx.x * 4 + 0] = sh[0][0];
    part[blockIdx.x * 4 + 1] = sh[1][0];
    part[blockIdx.x * 4 + 2] = sh[2][0];
    part[blockIdx.x * 4 + 3] = sh[3][0];
  }
}

__global__ __launch_bounds__(256) void minmax_final_kernel(
    const float* __restrict__ part, float* __restrict__ mm) {
  __shared__ float sh[4][256];
  int t = threadIdx.x;
  sh[0][t] = part[t * 4 + 0];
  sh[1][t] = part[t * 4 + 1];
  sh[2][t] = part[t * 4 + 2];
  sh[3][t] = part[t * 4 + 3];
  __syncthreads();
  for (int off = 128; off > 0; off >>= 1) {
    if (t < off) {
      sh[0][t] = fminf(sh[0][t], sh[0][t + off]);
      sh[1][t] = fmaxf(sh[1][t], sh[1][t + off]);
      sh[2][t] = fminf(sh[2][t], sh[2][t + off]);
      sh[3][t] = fmaxf(sh[3][t], sh[3][t + off]);
    }
    __syncthreads();
  }
  if (t == 0) {
    mm[0] = sh[0][0]; mm[1] = sh[1][0]; mm[2] = sh[2][0]; mm[3] = sh[3][0];
  }
}

// ============================================================
// Final: rescale U/V, YUV->RGB
// ============================================================
__global__ __launch_bounds__(256) void final_kernel(
    const float* __restrict__ bil, const float* __restrict__ x,
    const float* __restrict__ mm, float* __restrict__ out) {
  int i = blockIdx.x * 256 + threadIdx.x;
  if (i >= NB * NPIX) return;
  int b = i / NPIX, p = i % NPIX;
  float f0 = bil[(size_t)b * 2 * NPIX + p];
  float f1 = bil[(size_t)b * 2 * NPIX + NPIX + p];
  float U = (f0 - mm[0]) / (mm[1] - mm[0] + 1e-6f);
  U = fminf(fmaxf(U, 0.f), 1.f) * 0.872f - 0.436f;
  float V = (f1 - mm[2]) / (mm[3] - mm[2] + 1e-6f);
  V = fminf(fmaxf(V, 0.f), 1.f) * 1.23f - 0.615f;
  float Y = x[(size_t)b * NPIX + p];
  float* ob = out + (size_t)b * 3 * NPIX;
  ob[p]            = Y + 1.14f * V;
  ob[NPIX + p]     = Y - 0.396f * U - 0.581f * V;
  ob[2 * NPIX + p] = Y + 2.029f * U;
}

// ============================================================
// launch
// ============================================================
extern "C" void kernel_launch(void* const* d_in, const int* in_sizes, int n_in,
                              void* d_out, int out_size, void* d_ws, size_t ws_size,
                              hipStream_t stream) {
  const float* x   = (const float*)d_in[0];
  const float* gt  = (const float*)d_in[1];
  const float* w1  = (const float*)d_in[2];
  const float* b1  = (const float*)d_in[3];
  const float* g1w = (const float*)d_in[4];
  const float* g1b = (const float*)d_in[5];
  const float* w2  = (const float*)d_in[6];
  const float* b2  = (const float*)d_in[7];
  const float* g2w = (const float*)d_in[8];
  const float* g2b = (const float*)d_in[9];
  const float* w3  = (const float*)d_in[10];
  const float* b3  = (const float*)d_in[11];
  const float* g3w = (const float*)d_in[12];
  const float* g3b = (const float*)d_in[13];
  const float* w4  = (const float*)d_in[14];
  const float* b4  = (const float*)d_in[15];
  const float* g4w = (const float*)d_in[16];
  const float* g4b = (const float*)d_in[17];
  const float* w5  = (const float*)d_in[18];
  const float* b5  = (const float*)d_in[19];
  float* out = (float*)d_out;

  // ---- workspace layout ----
  char* ws = (char*)d_ws;
  double* stats = (double*)ws;
  float* coefA  = (float*)(ws + 2048);
  float* coefB  = (float*)(ws + 3072);
  float* mmpart = (float*)(ws + 4096);
  float* mm     = (float*)(ws + 8192);
  float* fbase  = (float*)(ws + 16384);
  size_t off = 0;
  float* pooled = fbase + off; off += 4452864;   // NB*8*PH*PW
  float* s1g    = fbase + off; off += 1105920;   // NB*2*NPIX
  short* w1B    = (short*)(fbase + off); off += 102400;  // 204800 bf16
  short* w2B    = (short*)(fbase + off); off += 9216;    // 18432 bf16
  short* w3B    = (short*)(fbase + off); off += 2304;    // 4608 bf16
  float* w4T    = fbase + off; off += 1152;
  float* w5T    = fbase + off; off += 256;
  float* bufA   = fbase + off; off += 35389440;  // 64ch fp32 (also c3)
  float* bufB   = fbase + off; off += 17694720;  // 32ch fp32 (also c4)
  float* c5     = pooled;                        // alias
  float* bilat  = pooled + 1105920;              // alias
  float* guide  = s1g;                           // alias

  // ---- weight packs ----
  mfma_pack_kernel<<<800, 256, 0, stream>>>(w1, w1B, 64, 128, 25);
  mfma_pack_kernel<<<72, 256, 0, stream>>>(w2, w2B, 32, 64, 9);
  mfma_pack_kernel<<<18, 256, 0, stream>>>(w3, w3B, 16, 32, 9);
  repack_kernel<<<(8 * 16 * 9 + 255) / 256, 256, 0, stream>>>(w4, w4T, 8, 16, 9);
  repack_kernel<<<(2 * 8 * 9 + 255) / 256, 256, 0, stream>>>(w5, w5T, 2, 8, 9);

  // ---- SIFT front-end ----
  pooled_kernel<<<dim3(33, 17, NB), 256, 0, stream>>>(x, pooled);
  sift_scalars_kernel<<<dim3(32, 17, NB), 256, 0, stream>>>(pooled, s1g);
  conv1_mfma_kernel<<<dim3(64, 34, NB), 256, 0, stream>>>(pooled, s1g, w1B, b1, bufA);

  // ---- GN1 + ReLU (C=64, 8 groups) ----
  gn_stats_kernel<<<NB * 64, 256, 0, stream>>>(bufA, stats);
  gn_coef_kernel<<<(NB * 64 + 63) / 64, 64, 0, stream>>>(stats, g1w, g1b, coefA, coefB, 64, 8);
  gn_apply_kernel<<<4096, 256, 0, stream>>>(bufA, coefA, coefB, 64);

  // ---- conv2 (64->32) MFMA + GN2 ----
  convk3_mfma_kernel<64, 32><<<dim3(64, 34, NB), 256, 0, stream>>>(bufA, w2B, b2, bufB);
  gn_stats_kernel<<<NB * 32, 256, 0, stream>>>(bufB, stats);
  gn_coef_kernel<<<(NB * 32 + 63) / 64, 64, 0, stream>>>(stats, g2w, g2b, coefA, coefB, 32, 4);
  gn_apply_kernel<<<2048, 256, 0, stream>>>(bufB, coefA, coefB, 32);

  // ---- conv3 (32->16) MFMA + GN3 ----
  convk3_mfma_kernel<32, 16><<<dim3(64, 34, NB), 256, 0, stream>>>(bufB, w3B, b3, bufA);
  gn_stats_kernel<<<NB * 16, 256, 0, stream>>>(bufA, stats);
  gn_coef_kernel<<<(NB * 16 + 63) / 64, 64, 0, stream>>>(stats, g3w, g3b, coefA, coefB, 16, 4);
  gn_apply_kernel<<<1024, 256, 0, stream>>>(bufA, coefA, coefB, 16);

  // ---- conv4 (16->8) + GN4 ----
  conv_kernel<16, 8, 3, 2, 256><<<dim3(64, 34, NB), 256, 0, stream>>>(bufA, w4T, b4, bufB);
  gn_stats_kernel<<<NB * 8, 256, 0, stream>>>(bufB, stats);
  gn_coef_kernel<<<(NB * 8 + 63) / 64, 64, 0, stream>>>(stats, g4w, g4b, coefA, coefB, 8, 2);
  gn_apply_kernel<<<512, 256, 0, stream>>>(bufB, coefA, coefB, 8);

  // ---- conv5 (8->2) ----
  conv_kernel<8, 2, 3, 1, 128><<<dim3(64, 34, NB), 128, 0, stream>>>(bufB, w5T, b5, c5);

  // ---- bilateral + rescale + composite ----
  guide_kernel<<<(NB * NPIX + 255) / 256, 256, 0, stream>>>(gt, guide);
  bilateral_kernel<<<dim3(32, 17, NB), 256, 0, stream>>>(c5, guide, bilat);
  minmax_partial_kernel<<<256, 256, 0, stream>>>(bilat, mmpart);
  minmax_final_kernel<<<1, 256, 0, stream>>>(mmpart, mm);
  final_kernel<<<(NB * NPIX + 255) / 256, 256, 0, stream>>>(bilat, x, mm, out);

  (void)in_sizes; (void)n_in; (void)out_size; (void)ws_size;
}

// Round 3
// 1554.753 us; speedup vs baseline: 9.2035x; 1.0442x over previous
//
#include <hip/hip_runtime.h>

// ---------------- problem constants ----------------
constexpr int NB  = 4;
constexpr int IH  = 270;
constexpr int IW  = 512;
constexpr int NPIX = IH * IW;      // 138240
constexpr int PH  = 271;           // pooled height
constexpr int PW  = 513;           // pooled width
constexpr float TWO_PI_F = 6.28318530717958647692f;

typedef short  bf16x8 __attribute__((ext_vector_type(8)));
typedef float floatx4 __attribute__((ext_vector_type(4)));

__device__ inline short f2bf(float x) {
  union { float f; unsigned u; } un; un.f = x;
  unsigned r = un.u + 0x7fff + ((un.u >> 16) & 1);   // RNE
  return (short)(r >> 16);
}

// ============================================================
// Stage 1: x -> pooled (8 ch, PH x PW).
// ============================================================
__global__ __launch_bounds__(256) void pooled_kernel(
    const float* __restrict__ x, float* __restrict__ pooled) {
  const int b = blockIdx.z;
  const int px0 = blockIdx.x * 16, py0 = blockIdx.y * 16;
  __shared__ float wo0s[19][19];
  __shared__ float wo1s[19][19];
  __shared__ int   bo0s[19][19];
  const float* xb = x + (size_t)b * NPIX;

  for (int t = threadIdx.x; t < 19 * 19; t += 256) {
    int r = t / 19, c = t % 19;
    int gy = py0 - 2 + r, gx = px0 - 2 + c;
    float w0 = 0.f, w1v = 0.f; int b0 = 0;
    if (gy >= 0 && gy < IH && gx >= 0 && gx < IW) {
      int xm = gx > 0 ? gx - 1 : 0, xp = gx < IW - 1 ? gx + 1 : IW - 1;
      int ym = gy > 0 ? gy - 1 : 0, yp = gy < IH - 1 ? gy + 1 : IH - 1;
      float gxv = (xb[gy * IW + xp] - xb[gy * IW + xm]) * 0.5f;
      float gyv = (xb[yp * IW + gx] - xb[ym * IW + gx]) * 0.5f;
      float mag = sqrtf(gxv * gxv + gyv * gyv + 1e-10f);
      float ori = atan2f(gyv, gxv + 1e-10f) + TWO_PI_F;
      float obig = ori * (8.0f / TWO_PI_F);
      float bf = floorf(obig);
      float w1_ = obig - bf;
      w0  = (1.0f - w1_) * mag;
      w1v = w1_ * mag;
      b0  = ((int)bf) & 7;
    }
    wo0s[r][c] = w0; wo1s[r][c] = w1v; bo0s[r][c] = b0;
  }
  __syncthreads();

  const int t = threadIdx.x;
  const int lx = t % 16, ly = t / 16;
  const int py = py0 + ly, px = px0 + lx;
  if (py >= PH || px >= PW) return;

  const float pwt[4] = {0.25f, 0.75f, 0.75f, 0.25f};
  float acc[8] = {0, 0, 0, 0, 0, 0, 0, 0};
  for (int i = 0; i < 4; i++) {
    for (int j = 0; j < 4; j++) {
      int r = ly + i, c = lx + j;
      float w0 = wo0s[r][c], w1v = wo1s[r][c];
      int b0 = bo0s[r][c];
      int b1i = (b0 + 1) & 7;
      float pw = pwt[i] * pwt[j];
      #pragma unroll
      for (int a = 0; a < 8; a++) {
        float add = (a == b0 ? w0 : 0.f) + (a == b1i ? w1v : 0.f);
        acc[a] = fmaf(pw, add, acc[a]);
      }
    }
  }
  float* pb = pooled + (size_t)b * 8 * PH * PW;
  #pragma unroll
  for (int a = 0; a < 8; a++) pb[((size_t)a * PH + py) * PW + px] = acc[a];
}

// ============================================================
// Stage 2: per-pixel SIFT normalization scalars s1, g
// ============================================================
__global__ __launch_bounds__(256) void sift_scalars_kernel(
    const float* __restrict__ pooled, float* __restrict__ s1g) {
  const int b = blockIdx.z;
  const int x0 = blockIdx.x * 16, y0 = blockIdx.y * 16;
  __shared__ float pt[8][19][19];
  const float* pb = pooled + (size_t)b * 8 * PH * PW;
  for (int t = threadIdx.x; t < 8 * 19 * 19; t += 256) {
    int a = t / 361, rc = t % 361, r = rc / 19, c = rc % 19;
    int gy = y0 - 1 + r, gx = x0 - 1 + c;
    float v = 0.f;
    if (gy >= 0 && gy < PH && gx >= 0 && gx < PW) v = pb[((size_t)a * PH + gy) * PW + gx];
    pt[a][r][c] = v;
  }
  __syncthreads();
  const int t = threadIdx.x;
  const int lx = t % 16, ly = t / 16;
  const int y = y0 + ly, x = x0 + lx;
  if (y >= IH) return;

  float sum2 = 0.f;
  for (int c = 0; c < 128; c++) {
    int a = c >> 4, i = (c >> 2) & 3, j = c & 3;
    float p = pt[a][ly + i][lx + j];
    sum2 = fmaf(p, p, sum2);
  }
  float s1 = 1.0f / fmaxf(sqrtf(sum2), 1e-12f);
  float st2 = 0.f, st = 0.f;
  for (int c = 0; c < 128; c++) {
    int a = c >> 4, i = (c >> 2) & 3, j = c & 3;
    float p = pt[a][ly + i][lx + j];
    float tv = fminf(p * s1, 0.2f);
    st2 = fmaf(tv, tv, st2);
    st += tv;
  }
  float s2 = 1.0f / fmaxf(sqrtf(st2), 1e-12f);
  float l1 = fmaxf(s2 * st, 1e-12f);
  float g = s2 / l1;
  float* o = s1g + (size_t)b * 2 * NPIX;
  o[y * IW + x] = s1;
  o[NPIX + y * IW + x] = g;
}

// ============================================================
// Weight repack (fp32 path): w[CO][CI][K*K] -> wT[K*K][CI][CO]
// ============================================================
__global__ void repack_kernel(const float* __restrict__ w, float* __restrict__ wT,
                              int CO, int CI, int KK) {
  int i = blockIdx.x * 256 + threadIdx.x;
  int total = CO * CI * KK;
  if (i >= total) return;
  int o = i / (CI * KK);
  int r = i % (CI * KK);
  int ci = r / KK, kk = r % KK;
  wT[(kk * CI + ci) * CO + o] = w[i];
}

// ============================================================
// MFMA B-operand pack: w[CO][CI][KK] fp32 -> fragment-ordered bf16
// ============================================================
__global__ void mfma_pack_kernel(const float* __restrict__ w, short* __restrict__ wB,
                                 int CO, int CI, int KK) {
  int CHUNKS = (CI + 31) / 32;
  int GG = (CO + 15) / 16;
  int total = GG * CHUNKS * KK * 512;
  for (int i = blockIdx.x * 256 + threadIdx.x; i < total; i += gridDim.x * 256) {
    int j = i & 7, l = (i >> 3) & 63, f = i >> 9;
    int t = f % KK; int fc = f / KK; int cc = fc % CHUNKS; int g = fc / CHUNKS;
    int ci = cc * 32 + ((l >> 4) << 3) + j;
    int co = g * 16 + (l & 15);
    float v = (ci < CI && co < CO) ? w[((size_t)co * CI + ci) * KK + t] : 0.f;
    wB[i] = f2bf(v);
  }
}

// ============================================================
// Conv1 via MFMA, 16x16 pixel tile. Wave w: co-pair p=w>>1 (2x16 co),
// M-half mh=w&1 (8 x 16-px tiles). Each A ds_read feeds 2 MFMAs.
// Epilogue: two 32-co halves transposed via LDS + fused GN1 stats.
// grid (32,17,NB), block 256.
// ============================================================
__global__ __launch_bounds__(256) void conv1_mfma_kernel(
    const float* __restrict__ pooled, const float* __restrict__ s1g,
    const short* __restrict__ w1B, const float* __restrict__ bias,
    float* __restrict__ out, float* __restrict__ stats) {
  const int b = blockIdx.z;
  const int x0 = blockIdx.x * 16, y0 = blockIdx.y * 16;
  __shared__ __align__(16) char smem_raw[52128];
  short* desc = (short*)smem_raw;                    // [400 pos][40] bf16
  float* pt   = (float*)(smem_raw + 32000);          // [8][23][23]
  float* sc   = (float*)(smem_raw + 48928);          // [2][400]
  float* cout = (float*)smem_raw;                    // [32][261] (epilogue)

  const int tid = threadIdx.x;
  const int wave = tid >> 6, lane = tid & 63;
  const int quad = lane >> 4, lm = lane & 15;
  const int mh = wave & 1, pp = wave >> 1;

  const float* pb = pooled + (size_t)b * 8 * PH * PW;
  for (int t = tid; t < 8 * 23 * 23; t += 256) {
    int a = t / 529, rc = t % 529, r = rc / 23, c = rc % 23;
    int gy = y0 - 3 + r, gx = x0 - 3 + c;
    float v = 0.f;
    if (gy >= 0 && gy < PH && gx >= 0 && gx < PW) v = pb[((size_t)a * PH + gy) * PW + gx];
    pt[t] = v;
  }
  const float* sb = s1g + (size_t)b * 2 * NPIX;
  for (int t = tid; t < 400; t += 256) {
    int r = t / 20, c = t % 20;
    int gy = y0 - 2 + r, gx = x0 - 2 + c;
    float a0 = 0.f, a1 = 0.f;
    if (gy >= 0 && gy < IH && gx >= 0 && gx < IW) {
      a0 = sb[gy * IW + gx];
      a1 = sb[NPIX + gy * IW + gx];
    }
    sc[t] = a0; sc[400 + t] = a1;
  }

  const int laneoff = lm * 40 + quad * 8;
  floatx4 acc[2][8];
  #pragma unroll
  for (int n = 0; n < 2; n++)
    #pragma unroll
    for (int m = 0; m < 8; m++) acc[n][m] = (floatx4){0.f, 0.f, 0.f, 0.f};

  for (int cc = 0; cc < 4; cc++) {
    __syncthreads();   // staging / previous chunk consumed
    for (int v = tid; v < 3200; v += 256) {
      int pos = v % 400, cg = v / 400;
      int r = pos / 20, c = pos % 20;
      int gy = y0 - 2 + r, gx = x0 - 2 + c;
      bool ok = (gy >= 0 && gy < IH && gx >= 0 && gx < IW);
      int ci0 = cc * 32 + cg * 4;
      int a = ci0 >> 4, i = (ci0 >> 2) & 3;
      float s1v = sc[pos], gv = sc[400 + pos];
      const float* prow = pt + a * 529 + (r + i) * 23 + c;
      unsigned short o4[4];
      #pragma unroll
      for (int q = 0; q < 4; q++) {
        float p = prow[q];
        float val = ok ? sqrtf(fminf(p * s1v, 0.2f) * gv + 1e-10f) : 0.f;
        o4[q] = (unsigned short)f2bf(val);
      }
      uint2 pk;
      pk.x = (unsigned)o4[0] | ((unsigned)o4[1] << 16);
      pk.y = (unsigned)o4[2] | ((unsigned)o4[3] << 16);
      *(uint2*)(desc + pos * 40 + cg * 4) = pk;
    }
    __syncthreads();

    #pragma unroll
    for (int ky = 0; ky < 5; ky++) {
      #pragma unroll
      for (int kx = 0; kx < 5; kx++) {
        bf16x8 bfr[2];
        #pragma unroll
        for (int ng = 0; ng < 2; ng++) {
          int f = ((pp * 2 + ng) * 4 + cc) * 25 + ky * 5 + kx;
          bfr[ng] = *(const bf16x8*)(w1B + ((size_t)f << 9) + (lane << 3));
        }
        bf16x8 av[8];
        #pragma unroll
        for (int m = 0; m < 8; m++) {
          int mt = mh * 8 + m;
          av[m] = *(const bf16x8*)(desc + (mt + ky) * 800 + kx * 40 + laneoff);
        }
        #pragma unroll
        for (int ng = 0; ng < 2; ng++)
          #pragma unroll
          for (int m = 0; m < 8; m++)
            acc[ng][m] = __builtin_amdgcn_mfma_f32_16x16x32_bf16(av[m], bfr[ng], acc[ng][m], 0, 0, 0);
      }
    }
  }

  // epilogue in two 32-co halves: transpose via LDS, store, fused GN stats
  float* ob = out + (size_t)b * 64 * NPIX;
  for (int h = 0; h < 2; h++) {
    __syncthreads();
    if (pp == h) {
      #pragma unroll
      for (int ng = 0; ng < 2; ng++)
        #pragma unroll
        for (int m = 0; m < 8; m++)
          #pragma unroll
          for (int r = 0; r < 4; r++)
            cout[(ng * 16 + lm) * 261 + (mh * 8 + m) * 16 + quad * 4 + r] = acc[ng][m][r];
    }
    __syncthreads();
    for (int v = tid; v < 8192; v += 256) {
      int col = v >> 8, px = v & 255;
      int y = y0 + (px >> 4), x = x0 + (px & 15);
      if (y < IH)
        ob[(size_t)(h * 32 + col) * NPIX + y * IW + x] = cout[col * 261 + px] + bias[h * 32 + col];
    }
    // stats: 32 co x 8 segs (2 rows each)
    int col = tid >> 3, seg = tid & 7;
    int co = h * 32 + col;
    float bv = bias[co];
    float sum = 0.f, sq = 0.f;
    #pragma unroll
    for (int rr = 0; rr < 2; rr++) {
      int row = seg * 2 + rr;
      if (y0 + row < IH) {
        #pragma unroll
        for (int k = 0; k < 16; k++) {
          float vv = cout[col * 261 + row * 16 + k] + bv;
          sum += vv; sq += vv * vv;
        }
      }
    }
    sum += __shfl_down(sum, 4); sq += __shfl_down(sq, 4);
    sum += __shfl_down(sum, 2); sq += __shfl_down(sq, 2);
    sum += __shfl_down(sum, 1); sq += __shfl_down(sq, 1);
    if ((tid & 7) == 0) {
      atomicAdd(&stats[(b * 64 + co) * 2], sum);
      atomicAdd(&stats[(b * 64 + co) * 2 + 1], sq);
    }
  }
}

// ============================================================
// 3x3 conv via MFMA with fused input GN+ReLU and fused output stats.
// 8x8 tile. CI mult of 32, CO mult of 16.
// ============================================================
template <int CI, int CO, bool STATS>
__global__ __launch_bounds__(256) void convk3_mfma_kernel(
    const float* __restrict__ xin, const short* __restrict__ wB,
    const float* __restrict__ bias, const float* __restrict__ cA,
    const float* __restrict__ cB, float* __restrict__ stats,
    float* __restrict__ out) {
  constexpr int CHUNKS = CI / 32;
  constexpr int G = CO / 16;
  constexpr int WPG = 4 / G;
  constexpr int TPW = G;
  constexpr int CIS = CHUNKS * 32 + 8;
  const int b = blockIdx.z;
  const int x0 = blockIdx.x * 8, y0 = blockIdx.y * 8;
  __shared__ __align__(16) short tile[100 * CIS];
  __shared__ float cout[CO * 65];
  const int tid = threadIdx.x;
  const int wave = tid >> 6, lane = tid & 63;
  const int quad = lane >> 4, lm = lane & 15;
  const int g = wave / WPG, mh = wave % WPG;

  const float* xb = xin + (size_t)b * CI * NPIX;
  const float* cAb = cA + b * CI;
  const float* cBb = cB + b * CI;
  for (int v = tid; v < (CI / 2) * 100; v += 256) {
    int cp = v / 100, pos = v % 100;
    int r = pos / 10, c = pos % 10;
    int gy = y0 - 1 + r, gx = x0 - 1 + c;
    float v0 = 0.f, v1 = 0.f;
    if (gy >= 0 && gy < IH && gx >= 0 && gx < IW) {
      v0 = fmaxf(fmaf(xb[(size_t)(2 * cp) * NPIX + gy * IW + gx], cAb[2 * cp], cBb[2 * cp]), 0.f);
      v1 = fmaxf(fmaf(xb[(size_t)(2 * cp + 1) * NPIX + gy * IW + gx], cAb[2 * cp + 1], cBb[2 * cp + 1]), 0.f);
    }
    unsigned pk = (unsigned)(unsigned short)f2bf(v0) |
                  ((unsigned)(unsigned short)f2bf(v1) << 16);
    *(unsigned*)(tile + pos * CIS + 2 * cp) = pk;
  }
  __syncthreads();

  int abase[TPW];
  #pragma unroll
  for (int i = 0; i < TPW; i++) {
    int pixel = (mh * TPW + i) * 16 + lm;
    abase[i] = ((pixel >> 3) * 10 + (pixel & 7)) * CIS + quad * 8;
  }

  floatx4 acc[TPW];
  #pragma unroll
  for (int i = 0; i < TPW; i++) acc[i] = (floatx4){0.f, 0.f, 0.f, 0.f};

  #pragma unroll
  for (int cc = 0; cc < CHUNKS; cc++) {
    #pragma unroll
    for (int ky = 0; ky < 3; ky++) {
      bf16x8 bfr[3];
      #pragma unroll
      for (int kx = 0; kx < 3; kx++) {
        int f = (g * CHUNKS + cc) * 9 + ky * 3 + kx;
        bfr[kx] = *(const bf16x8*)(wB + ((size_t)f << 9) + (lane << 3));
      }
      #pragma unroll
      for (int kx = 0; kx < 3; kx++) {
        #pragma unroll
        for (int i = 0; i < TPW; i++) {
          bf16x8 av = *(const bf16x8*)(tile + abase[i] + cc * 32 + (ky * 10 + kx) * CIS);
          acc[i] = __builtin_amdgcn_mfma_f32_16x16x32_bf16(av, bfr[kx], acc[i], 0, 0, 0);
        }
      }
    }
  }
  #pragma unroll
  for (int i = 0; i < TPW; i++) {
    #pragma unroll
    for (int r = 0; r < 4; r++) {
      int pixel = (mh * TPW + i) * 16 + quad * 4 + r;
      cout[(g * 16 + lm) * 65 + pixel] = acc[i][r];
    }
  }
  __syncthreads();
  float* ob = out + (size_t)b * CO * NPIX;
  for (int v = tid; v < CO * 64; v += 256) {
    int co = v >> 6, pix = v & 63;
    int y = y0 + (pix >> 3), x = x0 + (pix & 7);
    if (y < IH) ob[(size_t)co * NPIX + y * IW + x] = cout[co * 65 + pix] + bias[co];
  }
  if (STATS) {
    constexpr int TPC = 256 / CO;     // threads per channel
    constexpr int PXT = 64 / TPC;     // pixels per thread
    int col = tid / TPC, seg = tid % TPC;
    float bv = bias[col];
    float sum = 0.f, sq = 0.f;
    for (int k = 0; k < PXT; k++) {
      int p = seg * PXT + k;
      if (y0 + (p >> 3) < IH) {
        float vv = cout[col * 65 + p] + bv;
        sum += vv; sq += vv * vv;
      }
    }
    #pragma unroll
    for (int off = TPC / 2; off > 0; off >>= 1) {
      sum += __shfl_down(sum, off);
      sq  += __shfl_down(sq, off);
    }
    if (seg == 0) {
      atomicAdd(&stats[(b * CO + col) * 2], sum);
      atomicAdd(&stats[(b * CO + col) * 2 + 1], sq);
    }
  }
}

// ============================================================
// Small direct fp32 3x3 conv with fused input GN+ReLU, optional stats.
// ============================================================
template <int CI, int CO, int OPT, bool STATS>
__global__ __launch_bounds__(256) void convs_kernel(
    const float* __restrict__ xin, const float* __restrict__ wT,
    const float* __restrict__ bias, const float* __restrict__ cA,
    const float* __restrict__ cB, float* __restrict__ stats,
    float* __restrict__ out) {
  const int b = blockIdx.z;
  const int x0 = blockIdx.x * 8, y0 = blockIdx.y * 8;
  __shared__ float tile[CI][10][10];
  __shared__ float ssum[CO], ssq[CO];
  if (STATS && threadIdx.x < CO) { ssum[threadIdx.x] = 0.f; ssq[threadIdx.x] = 0.f; }
  const float* xb = xin + (size_t)b * CI * NPIX;
  const float* cAb = cA + b * CI;
  const float* cBb = cB + b * CI;
  for (int t = threadIdx.x; t < CI * 100; t += 256) {
    int ci = t / 100, rc = t % 100, r = rc / 10, c = rc % 10;
    int gy = y0 - 1 + r, gx = x0 - 1 + c;
    float v = 0.f;
    if (gy >= 0 && gy < IH && gx >= 0 && gx < IW)
      v = fmaxf(fmaf(xb[(size_t)ci * NPIX + gy * IW + gx], cAb[ci], cBb[ci]), 0.f);
    tile[ci][r][c] = v;
  }
  __syncthreads();
  const int t = threadIdx.x;
  const int px = t % 64, og = t / 64;
  const int pyy = px / 8, pxx = px % 8;
  const int oc0 = og * OPT;
  const int y = y0 + pyy, x = x0 + pxx;
  if (og < CO / OPT) {
    float acc[OPT] = {};
    for (int ky = 0; ky < 3; ky++) {
      for (int kx = 0; kx < 3; kx++) {
        const float* wrow = wT + (size_t)((ky * 3 + kx) * CI) * CO + oc0;
        for (int ci = 0; ci < CI; ci++) {
          float v = tile[ci][pyy + ky][pxx + kx];
          #pragma unroll
          for (int o = 0; o < OPT; o++) acc[o] = fmaf(v, wrow[ci * CO + o], acc[o]);
        }
      }
    }
    if (y < IH) {
      float* ob = out + (size_t)b * CO * NPIX;
      #pragma unroll
      for (int o = 0; o < OPT; o++) {
        float vv = acc[o] + bias[oc0 + o];
        ob[(size_t)(oc0 + o) * NPIX + y * IW + x] = vv;
        if (STATS) {
          atomicAdd(&ssum[oc0 + o], vv);
          atomicAdd(&ssq[oc0 + o], vv * vv);
        }
      }
    }
  }
  if (STATS) {
    __syncthreads();
    if (threadIdx.x < CO) {
      atomicAdd(&stats[(b * CO + threadIdx.x) * 2], ssum[threadIdx.x]);
      atomicAdd(&stats[(b * CO + threadIdx.x) * 2 + 1], ssq[threadIdx.x]);
    }
  }
}

// ============================================================
// GN coefficients from fp32 accumulated stats
// ============================================================
__global__ void gn_coef_kernel(const float* __restrict__ stats,
                               const float* __restrict__ gamma,
                               const float* __restrict__ beta,
                               float* __restrict__ cA, float* __restrict__ cB,
                               int C, int chper) {
  int i = blockIdx.x * 64 + threadIdx.x;
  if (i >= NB * C) return;
  int b = i / C, c = i % C;
  int g0 = (c / chper) * chper;
  double S = 0.0, S2 = 0.0;
  for (int k = 0; k < chper; k++) {
    S  += (double)stats[(b * C + g0 + k) * 2];
    S2 += (double)stats[(b * C + g0 + k) * 2 + 1];
  }
  double Nd = (double)chper * NPIX;
  double mu = S / Nd;
  double var = S2 / Nd - mu * mu;
  double rstd = 1.0 / sqrt(var + 1e-5);
  float A = (float)rstd * gamma[c];
  cA[i] = A;
  cB[i] = beta[c] - (float)mu * A;
}

// ============================================================
// Joint bilateral 5x5 (reflect) with fused guide computation.
// ============================================================
__global__ __launch_bounds__(256) void bilateral_kernel(
    const float* __restrict__ f, const float* __restrict__ gt,
    float* __restrict__ out) {
  const int b = blockIdx.z;
  const int x0 = blockIdx.x * 16, y0 = blockIdx.y * 16;
  __shared__ float gu[20][20], gv[20][20], f0s[20][20], f1s[20][20];
  const float* gtb = gt + (size_t)b * 3 * NPIX;
  const float* fb = f + (size_t)b * 2 * NPIX;
  for (int t = threadIdx.x; t < 400; t += 256) {
    int r = t / 20, c = t % 20;
    int gy = y0 - 2 + r, gx = x0 - 2 + c;
    if (gy < 0) gy = -gy;
    if (gy > IH - 1) gy = 2 * (IH - 1) - gy;
    if (gx < 0) gx = -gx;
    if (gx > IW - 1) gx = 2 * (IW - 1) - gx;
    int p = gy * IW + gx;
    float rr = gtb[p], gg = gtb[NPIX + p], bb = gtb[2 * NPIX + p];
    gu[r][c]  = -0.147f * rr - 0.289f * gg + 0.436f * bb;
    gv[r][c]  =  0.615f * rr - 0.515f * gg - 0.100f * bb;
    f0s[r][c] = fb[p];
    f1s[r][c] = fb[NPIX + p];
  }
  __syncthreads();
  const int t = threadIdx.x;
  const int lx = t % 16, ly = t / 16;
  const int y = y0 + ly, x = x0 + lx;
  if (y >= IH) return;

  float g1v[5];
  {
    float s = 0.f;
    #pragma unroll
    for (int k = 0; k < 5; k++) {
      float a = (float)(k - 2);
      g1v[k] = expf(-a * a / 4.5f);
      s += g1v[k];
    }
    #pragma unroll
    for (int k = 0; k < 5; k++) g1v[k] /= s;
  }
  float cu = gu[ly + 2][lx + 2], cv = gv[ly + 2][lx + 2];
  float num0 = 0.f, num1 = 0.f, den = 0.f;
  #pragma unroll
  for (int dy = 0; dy < 5; dy++) {
    #pragma unroll
    for (int dx = 0; dx < 5; dx++) {
      float du = fabsf(gu[ly + dy][lx + dx] - cu) + fabsf(gv[ly + dy][lx + dx] - cv);
      float wgt = g1v[dy] * g1v[dx] * expf(-50.0f * du * du);
      num0 = fmaf(wgt, f0s[ly + dy][lx + dx], num0);
      num1 = fmaf(wgt, f1s[ly + dy][lx + dx], num1);
      den += wgt;
    }
  }
  float* ob = out + (size_t)b * 2 * NPIX;
  ob[y * IW + x] = num0 / den;
  ob[NPIX + y * IW + x] = num1 / den;
}

// ============================================================
// Global min/max (deterministic 2-stage)
// ============================================================
__global__ __launch_bounds__(256) void minmax_partial_kernel(
    const float* __restrict__ bil, float* __restrict__ part) {
  float mn0 = 1e30f, mx0 = -1e30f, mn1 = 1e30f, mx1 = -1e30f;
  for (size_t i = (size_t)blockIdx.x * 256 + threadIdx.x; i < (size_t)NB * NPIX;
       i += 256 * 256) {
    int b = (int)(i / NPIX), p = (int)(i % NPIX);
    float v0 = bil[(size_t)b * 2 * NPIX + p];
    float v1 = bil[(size_t)b * 2 * NPIX + NPIX + p];
    mn0 = fminf(mn0, v0); mx0 = fmaxf(mx0, v0);
    mn1 = fminf(mn1, v1); mx1 = fmaxf(mx1, v1);
  }
  __shared__ float sh[4][256];
  sh[0][threadIdx.x] = mn0; sh[1][threadIdx.x] = mx0;
  sh[2][threadIdx.x] = mn1; sh[3][threadIdx.x] = mx1;
  __syncthreads();
  for (int off = 128; off > 0; off >>= 1) {
    if (threadIdx.x < off) {
      sh[0][threadIdx.x] = fminf(sh[0][threadIdx.x], sh[0][threadIdx.x + off]);
      sh[1][threadIdx.x] = fmaxf(sh[1][threadIdx.x], sh[1][threadIdx.x + off]);
      sh[2][threadIdx.x] = fminf(sh[2][threadIdx.x], sh[2][threadIdx.x + off]);
      sh[3][threadIdx.x] = fmaxf(sh[3][threadIdx.x], sh[3][threadIdx.x + off]);
    }
    __syncthreads();
  }
  if (threadIdx.x == 0) {
    part[blockIdx.x * 4 + 0] = sh[0][0];
    part[blockIdx.x * 4 + 1] = sh[1][0];
    part[blockIdx.x * 4 + 2] = sh[2][0];
    part[blockIdx.x * 4 + 3] = sh[3][0];
  }
}

__global__ __launch_bounds__(256) void minmax_final_kernel(
    const float* __restrict__ part, float* __restrict__ mm) {
  __shared__ float sh[4][256];
  int t = threadIdx.x;
  sh[0][t] = part[t * 4 + 0];
  sh[1][t] = part[t * 4 + 1];
  sh[2][t] = part[t * 4 + 2];
  sh[3][t] = part[t * 4 + 3];
  __syncthreads();
  for (int off = 128; off > 0; off >>= 1) {
    if (t < off) {
      sh[0][t] = fminf(sh[0][t], sh[0][t + off]);
      sh[1][t] = fmaxf(sh[1][t], sh[1][t + off]);
      sh[2][t] = fminf(sh[2][t], sh[2][t + off]);
      sh[3][t] = fmaxf(sh[3][t], sh[3][t + off]);
    }
    __syncthreads();
  }
  if (t == 0) {
    mm[0] = sh[0][0]; mm[1] = sh[1][0]; mm[2] = sh[2][0]; mm[3] = sh[3][0];
  }
}

// ============================================================
// Final: rescale U/V, YUV->RGB
// ============================================================
__global__ __launch_bounds__(256) void final_kernel(
    const float* __restrict__ bil, const float* __restrict__ x,
    const float* __restrict__ mm, float* __restrict__ out) {
  int i = blockIdx.x * 256 + threadIdx.x;
  if (i >= NB * NPIX) return;
  int b = i / NPIX, p = i % NPIX;
  float f0 = bil[(size_t)b * 2 * NPIX + p];
  float f1 = bil[(size_t)b * 2 * NPIX + NPIX + p];
  float U = (f0 - mm[0]) / (mm[1] - mm[0] + 1e-6f);
  U = fminf(fmaxf(U, 0.f), 1.f) * 0.872f - 0.436f;
  float V = (f1 - mm[2]) / (mm[3] - mm[2] + 1e-6f);
  V = fminf(fmaxf(V, 0.f), 1.f) * 1.23f - 0.615f;
  float Y = x[(size_t)b * NPIX + p];
  float* ob = out + (size_t)b * 3 * NPIX;
  ob[p]            = Y + 1.14f * V;
  ob[NPIX + p]     = Y - 0.396f * U - 0.581f * V;
  ob[2 * NPIX + p] = Y + 2.029f * U;
}

// ============================================================
// launch
// ============================================================
extern "C" void kernel_launch(void* const* d_in, const int* in_sizes, int n_in,
                              void* d_out, int out_size, void* d_ws, size_t ws_size,
                              hipStream_t stream) {
  const float* x   = (const float*)d_in[0];
  const float* gt  = (const float*)d_in[1];
  const float* w1  = (const float*)d_in[2];
  const float* b1  = (const float*)d_in[3];
  const float* g1w = (const float*)d_in[4];
  const float* g1b = (const float*)d_in[5];
  const float* w2  = (const float*)d_in[6];
  const float* b2  = (const float*)d_in[7];
  const float* g2w = (const float*)d_in[8];
  const float* g2b = (const float*)d_in[9];
  const float* w3  = (const float*)d_in[10];
  const float* b3  = (const float*)d_in[11];
  const float* g3w = (const float*)d_in[12];
  const float* g3b = (const float*)d_in[13];
  const float* w4  = (const float*)d_in[14];
  const float* b4  = (const float*)d_in[15];
  const float* g4w = (const float*)d_in[16];
  const float* g4b = (const float*)d_in[17];
  const float* w5  = (const float*)d_in[18];
  const float* b5  = (const float*)d_in[19];
  float* out = (float*)d_out;

  // ---- workspace layout ----
  char* ws = (char*)d_ws;
  float* statsF = (float*)ws;                 // s1:512  s2:256  s3:128  s4:64 floats
  float* stats1 = statsF;
  float* stats2 = statsF + 512;
  float* stats3 = statsF + 768;
  float* stats4 = statsF + 896;               // ends at 960 floats
  float* c1A = (float*)(ws + 4096);           // 256
  float* c1B = c1A + 256;
  float* c2A = c1B + 256;                     // 128
  float* c2B = c2A + 128;
  float* c3A = c2B + 128;                     // 64
  float* c3B = c3A + 64;
  float* c4A = c3B + 64;                      // 32
  float* c4B = c4A + 32;
  float* mmpart = (float*)(ws + 8192);        // 1024
  float* mm     = (float*)(ws + 12288);       // 4
  float* fbase  = (float*)(ws + 16384);
  size_t off = 0;
  float* pooled = fbase + off; off += 4452864;   // NB*8*PH*PW
  float* s1g    = fbase + off; off += 1105920;   // NB*2*NPIX
  short* w1B    = (short*)(fbase + off); off += 102400;  // 204800 bf16
  short* w2B    = (short*)(fbase + off); off += 9216;
  short* w3B    = (short*)(fbase + off); off += 2304;
  float* w4T    = fbase + off; off += 1152;
  float* w5T    = fbase + off; off += 256;
  float* bufA   = fbase + off; off += 35389440;  // 64ch fp32 (also c3 out)
  float* bufB   = fbase + off; off += 17694720;  // 32ch fp32 (also c4 out)
  float* c5     = pooled;                        // alias: pooled dead by conv5
  float* bilat  = pooled + 1105920;              // alias

  hipMemsetAsync(statsF, 0, 960 * sizeof(float), stream);

  // ---- weight packs ----
  mfma_pack_kernel<<<800, 256, 0, stream>>>(w1, w1B, 64, 128, 25);
  mfma_pack_kernel<<<72, 256, 0, stream>>>(w2, w2B, 32, 64, 9);
  mfma_pack_kernel<<<18, 256, 0, stream>>>(w3, w3B, 16, 32, 9);
  repack_kernel<<<(8 * 16 * 9 + 255) / 256, 256, 0, stream>>>(w4, w4T, 8, 16, 9);
  repack_kernel<<<(2 * 8 * 9 + 255) / 256, 256, 0, stream>>>(w5, w5T, 2, 8, 9);

  // ---- SIFT front-end ----
  pooled_kernel<<<dim3(33, 17, NB), 256, 0, stream>>>(x, pooled);
  sift_scalars_kernel<<<dim3(32, 17, NB), 256, 0, stream>>>(pooled, s1g);
  conv1_mfma_kernel<<<dim3(32, 17, NB), 256, 0, stream>>>(pooled, s1g, w1B, b1, bufA, stats1);
  gn_coef_kernel<<<(NB * 64 + 63) / 64, 64, 0, stream>>>(stats1, g1w, g1b, c1A, c1B, 64, 8);

  // ---- conv2 (64->32, GN1 applied on input, stats2 fused) ----
  convk3_mfma_kernel<64, 32, true><<<dim3(64, 34, NB), 256, 0, stream>>>(
      bufA, w2B, b2, c1A, c1B, stats2, bufB);
  gn_coef_kernel<<<(NB * 32 + 63) / 64, 64, 0, stream>>>(stats2, g2w, g2b, c2A, c2B, 32, 4);

  // ---- conv3 (32->16) ----
  convk3_mfma_kernel<32, 16, true><<<dim3(64, 34, NB), 256, 0, stream>>>(
      bufB, w3B, b3, c2A, c2B, stats3, bufA);
  gn_coef_kernel<<<(NB * 16 + 63) / 64, 64, 0, stream>>>(stats3, g3w, g3b, c3A, c3B, 16, 4);

  // ---- conv4 (16->8) ----
  convs_kernel<16, 8, 2, true><<<dim3(64, 34, NB), 256, 0, stream>>>(
      bufA, w4T, b4, c3A, c3B, stats4, bufB);
  gn_coef_kernel<<<(NB * 8 + 63) / 64, 64, 0, stream>>>(stats4, g4w, g4b, c4A, c4B, 8, 2);

  // ---- conv5 (8->2) ----
  convs_kernel<8, 2, 1, false><<<dim3(64, 34, NB), 256, 0, stream>>>(
      bufB, w5T, b5, c4A, c4B, nullptr, c5);

  // ---- bilateral (guide fused) + rescale + composite ----
  bilateral_kernel<<<dim3(32, 17, NB), 256, 0, stream>>>(c5, gt, bilat);
  minmax_partial_kernel<<<256, 256, 0, stream>>>(bilat, mmpart);
  minmax_final_kernel<<<1, 256, 0, stream>>>(mmpart, mm);
  final_kernel<<<(NB * NPIX + 255) / 256, 256, 0, stream>>>(bilat, x, mm, out);

  (void)in_sizes; (void)n_in; (void)out_size; (void)ws_size;
}

// Round 4
// 1526.499 us; speedup vs baseline: 9.3738x; 1.0185x over previous
//
#include <hip/hip_runtime.h>

// ---------------- problem constants ----------------
constexpr int NB  = 4;
constexpr int IH  = 270;
constexpr int IW  = 512;
constexpr int NPIX = IH * IW;      // 138240
constexpr int PH  = 271;           // pooled height
constexpr int PW  = 513;           // pooled width
constexpr float TWO_PI_F = 6.28318530717958647692f;

typedef short  bf16x8 __attribute__((ext_vector_type(8)));
typedef float floatx4 __attribute__((ext_vector_type(4)));

__device__ inline short f2bf(float x) {
  union { float f; unsigned u; } un; un.f = x;
  unsigned r = un.u + 0x7fff + ((un.u >> 16) & 1);   // RNE
  return (short)(r >> 16);
}
// monotone float<->uint keys for atomic min/max
__device__ inline unsigned fkey(float f) {
  unsigned u = __float_as_uint(f);
  return (u & 0x80000000u) ? ~u : (u | 0x80000000u);
}
__device__ inline float funkey(unsigned k) {
  unsigned u = (k & 0x80000000u) ? (k ^ 0x80000000u) : ~k;
  return __uint_as_float(u);
}
// per-thread GN coef (thread c < C): A,B from fp32 stats
__device__ inline void gn_coef_thread(const float* __restrict__ stats,
                                      const float* __restrict__ gamma,
                                      const float* __restrict__ beta,
                                      float* cA, float* cB, int C, int chper, int b) {
  int c = threadIdx.x;
  if (c < C) {
    int g0 = (c / chper) * chper;
    float S = 0.f, S2 = 0.f;
    for (int k = 0; k < chper; k++) {
      S  += stats[(b * C + g0 + k) * 2];
      S2 += stats[(b * C + g0 + k) * 2 + 1];
    }
    double Nd = (double)chper * NPIX;
    double mu = (double)S / Nd;
    double var = (double)S2 / Nd - mu * mu;
    double rstd = 1.0 / sqrt(var + 1e-5);
    float A = (float)rstd * gamma[c];
    cA[c] = A;
    cB[c] = beta[c] - (float)mu * A;
  }
}

// ============================================================
// Combined weight prep: all MFMA B-packs + fp32 repacks, one kernel.
// ============================================================
__device__ inline void mfma_pack_one(const float* __restrict__ w, short* __restrict__ wB,
                                     int i, int CO, int CI, int KK, int CHUNKS) {
  int j = i & 7, l = (i >> 3) & 63, f = i >> 9;
  int t = f % KK; int fc = f / KK; int cc = fc % CHUNKS; int g = fc / CHUNKS;
  int ci = cc * 32 + ((l >> 4) << 3) + j;
  int co = g * 16 + (l & 15);
  float v = (ci < CI && co < CO) ? w[((size_t)co * CI + ci) * KK + t] : 0.f;
  wB[i] = f2bf(v);
}
__device__ inline void repack_one(const float* __restrict__ w, float* __restrict__ wT,
                                  int i, int CO, int CI, int KK) {
  int o = i / (CI * KK);
  int r = i % (CI * KK);
  int ci = r / KK, kk = r % KK;
  wT[(kk * CI + ci) * CO + o] = w[i];
}
__global__ __launch_bounds__(256) void prep_kernel(
    const float* __restrict__ w1, const float* __restrict__ w2,
    const float* __restrict__ w3, const float* __restrict__ w4,
    const float* __restrict__ w5,
    short* __restrict__ w1B, short* __restrict__ w2B, short* __restrict__ w3B,
    float* __restrict__ w4T, float* __restrict__ w5T) {
  constexpr int N1 = 4 * 4 * 25 * 512;   // 204800
  constexpr int N2 = 2 * 2 * 9 * 512;    // 18432
  constexpr int N3 = 1 * 1 * 9 * 512;    // 4608
  constexpr int N4 = 8 * 16 * 9;         // 1152
  constexpr int N5 = 2 * 8 * 9;          // 144
  int i = blockIdx.x * 256 + threadIdx.x;
  if (i < N1) { mfma_pack_one(w1, w1B, i, 64, 128, 25, 4); return; }
  i -= N1;
  if (i < N2) { mfma_pack_one(w2, w2B, i, 32, 64, 9, 2); return; }
  i -= N2;
  if (i < N3) { mfma_pack_one(w3, w3B, i, 16, 32, 9, 1); return; }
  i -= N3;
  if (i < N4) { repack_one(w4, w4T, i, 8, 16, 9); return; }
  i -= N4;
  if (i < N5) { repack_one(w5, w5T, i, 2, 8, 9); return; }
}

// ============================================================
// Stage 1: x -> pooled (8 ch, PH x PW).
// ============================================================
__global__ __launch_bounds__(256) void pooled_kernel(
    const float* __restrict__ x, float* __restrict__ pooled) {
  const int b = blockIdx.z;
  const int px0 = blockIdx.x * 16, py0 = blockIdx.y * 16;
  __shared__ float wo0s[19][19];
  __shared__ float wo1s[19][19];
  __shared__ int   bo0s[19][19];
  const float* xb = x + (size_t)b * NPIX;

  for (int t = threadIdx.x; t < 19 * 19; t += 256) {
    int r = t / 19, c = t % 19;
    int gy = py0 - 2 + r, gx = px0 - 2 + c;
    float w0 = 0.f, w1v = 0.f; int b0 = 0;
    if (gy >= 0 && gy < IH && gx >= 0 && gx < IW) {
      int xm = gx > 0 ? gx - 1 : 0, xp = gx < IW - 1 ? gx + 1 : IW - 1;
      int ym = gy > 0 ? gy - 1 : 0, yp = gy < IH - 1 ? gy + 1 : IH - 1;
      float gxv = (xb[gy * IW + xp] - xb[gy * IW + xm]) * 0.5f;
      float gyv = (xb[yp * IW + gx] - xb[ym * IW + gx]) * 0.5f;
      float mag = sqrtf(gxv * gxv + gyv * gyv + 1e-10f);
      float ori = atan2f(gyv, gxv + 1e-10f) + TWO_PI_F;
      float obig = ori * (8.0f / TWO_PI_F);
      float bf = floorf(obig);
      float w1_ = obig - bf;
      w0  = (1.0f - w1_) * mag;
      w1v = w1_ * mag;
      b0  = ((int)bf) & 7;
    }
    wo0s[r][c] = w0; wo1s[r][c] = w1v; bo0s[r][c] = b0;
  }
  __syncthreads();

  const int t = threadIdx.x;
  const int lx = t % 16, ly = t / 16;
  const int py = py0 + ly, px = px0 + lx;
  if (py >= PH || px >= PW) return;

  const float pwt[4] = {0.25f, 0.75f, 0.75f, 0.25f};
  float acc[8] = {0, 0, 0, 0, 0, 0, 0, 0};
  for (int i = 0; i < 4; i++) {
    for (int j = 0; j < 4; j++) {
      int r = ly + i, c = lx + j;
      float w0 = wo0s[r][c], w1v = wo1s[r][c];
      int b0 = bo0s[r][c];
      int b1i = (b0 + 1) & 7;
      float pw = pwt[i] * pwt[j];
      #pragma unroll
      for (int a = 0; a < 8; a++) {
        float add = (a == b0 ? w0 : 0.f) + (a == b1i ? w1v : 0.f);
        acc[a] = fmaf(pw, add, acc[a]);
      }
    }
  }
  float* pb = pooled + (size_t)b * 8 * PH * PW;
  #pragma unroll
  for (int a = 0; a < 8; a++) pb[((size_t)a * PH + py) * PW + px] = acc[a];
}

// ============================================================
// Stage 2: per-pixel SIFT normalization scalars s1, g
// ============================================================
__global__ __launch_bounds__(256) void sift_scalars_kernel(
    const float* __restrict__ pooled, float* __restrict__ s1g) {
  const int b = blockIdx.z;
  const int x0 = blockIdx.x * 16, y0 = blockIdx.y * 16;
  __shared__ float pt[8][19][19];
  const float* pb = pooled + (size_t)b * 8 * PH * PW;
  for (int t = threadIdx.x; t < 8 * 19 * 19; t += 256) {
    int a = t / 361, rc = t % 361, r = rc / 19, c = rc % 19;
    int gy = y0 - 1 + r, gx = x0 - 1 + c;
    float v = 0.f;
    if (gy >= 0 && gy < PH && gx >= 0 && gx < PW) v = pb[((size_t)a * PH + gy) * PW + gx];
    pt[a][r][c] = v;
  }
  __syncthreads();
  const int t = threadIdx.x;
  const int lx = t % 16, ly = t / 16;
  const int y = y0 + ly, x = x0 + lx;
  if (y >= IH) return;

  float sum2 = 0.f;
  for (int c = 0; c < 128; c++) {
    int a = c >> 4, i = (c >> 2) & 3, j = c & 3;
    float p = pt[a][ly + i][lx + j];
    sum2 = fmaf(p, p, sum2);
  }
  float s1 = 1.0f / fmaxf(sqrtf(sum2), 1e-12f);
  float st2 = 0.f, st = 0.f;
  for (int c = 0; c < 128; c++) {
    int a = c >> 4, i = (c >> 2) & 3, j = c & 3;
    float p = pt[a][ly + i][lx + j];
    float tv = fminf(p * s1, 0.2f);
    st2 = fmaf(tv, tv, st2);
    st += tv;
  }
  float s2 = 1.0f / fmaxf(sqrtf(st2), 1e-12f);
  float l1 = fmaxf(s2 * st, 1e-12f);
  float g = s2 / l1;
  float* o = s1g + (size_t)b * 2 * NPIX;
  o[y * IW + x] = s1;
  o[NPIX + y * IW + x] = g;
}

// ============================================================
// Conv1 via MFMA, 16x16 tile. Wave w: M-tiles 4w..4w+3, ALL 4 co-groups
// (each A ds_read feeds 4 MFMAs). Pooled planes staged 2-per-chunk,
// prefetched during MFMA. LDS ~39.4KB -> 4 blocks/CU.
// grid (32,17,NB), block 256.
// ============================================================
__global__ __launch_bounds__(256, 4) void conv1_mfma_kernel(
    const float* __restrict__ pooled, const float* __restrict__ s1g,
    const short* __restrict__ w1B, const float* __restrict__ bias,
    float* __restrict__ out, float* __restrict__ stats) {
  const int b = blockIdx.z;
  const int x0 = blockIdx.x * 16, y0 = blockIdx.y * 16;
  __shared__ __align__(16) char smem_raw[39440];
  short* desc = (short*)smem_raw;                 // [400 pos][40] bf16
  float* sc   = (float*)(smem_raw + 32000);       // [2][400]
  float* pt   = (float*)(smem_raw + 35208);       // [2][529] (2 planes)
  float* cout = (float*)smem_raw;                 // epilogue [32][261]

  const int tid = threadIdx.x;
  const int wave = tid >> 6, lane = tid & 63;
  const int quad = lane >> 4, lm = lane & 15;

  const float* pb = pooled + (size_t)b * 8 * PH * PW;
  const float* sb = s1g + (size_t)b * 2 * NPIX;
  for (int t = tid; t < 400; t += 256) {
    int r = t / 20, c = t % 20;
    int gy = y0 - 2 + r, gx = x0 - 2 + c;
    float a0 = 0.f, a1 = 0.f;
    if (gy >= 0 && gy < IH && gx >= 0 && gx < IW) {
      a0 = sb[gy * IW + gx];
      a1 = sb[NPIX + gy * IW + gx];
    }
    sc[t] = a0; sc[400 + t] = a1;
  }
  // stage planes 0,1 (chunk 0)
  for (int t = tid; t < 1058; t += 256) {
    int pl = t / 529, rc = t % 529, r = rc / 23, c = rc % 23;
    int gy = y0 - 3 + r, gx = x0 - 3 + c;
    float v = 0.f;
    if (gy >= 0 && gy < PH && gx >= 0 && gx < PW) v = pb[((size_t)pl * PH + gy) * PW + gx];
    pt[t] = v;
  }

  floatx4 acc[4][4];   // [n-group][m-tile]
  #pragma unroll
  for (int n = 0; n < 4; n++)
    #pragma unroll
    for (int i = 0; i < 4; i++) acc[n][i] = (floatx4){0.f, 0.f, 0.f, 0.f};

  for (int cc = 0; cc < 4; cc++) {
    __syncthreads();   // planes for cc staged; desc of cc-1 consumed
    // regen desc chunk cc from pt (planes 2cc, 2cc+1)
    for (int v = tid; v < 3200; v += 256) {
      int pos = v % 400, cg = v / 400;   // cg: group of 4 ci within chunk
      int r = pos / 20, c = pos % 20;
      int gy = y0 - 2 + r, gx = x0 - 2 + c;
      bool ok = (gy >= 0 && gy < IH && gx >= 0 && gx < IW);
      int al = cg >> 2;          // local plane
      int ii = cg & 3;           // i
      float s1v = sc[pos], gv = sc[400 + pos];
      const float* prow = pt + al * 529 + (r + ii) * 23 + c;
      unsigned short o4[4];
      #pragma unroll
      for (int q = 0; q < 4; q++) {
        float p = prow[q];
        float val = ok ? sqrtf(fminf(p * s1v, 0.2f) * gv + 1e-10f) : 0.f;
        o4[q] = (unsigned short)f2bf(val);
      }
      uint2 pk;
      pk.x = (unsigned)o4[0] | ((unsigned)o4[1] << 16);
      pk.y = (unsigned)o4[2] | ((unsigned)o4[3] << 16);
      *(uint2*)(desc + pos * 40 + cg * 4) = pk;
    }
    __syncthreads();   // desc ready; pt free

    // prefetch next chunk's planes into pt (overlaps MFMA below)
    if (cc < 3) {
      for (int t = tid; t < 1058; t += 256) {
        int pl = t / 529, rc = t % 529, r = rc / 23, c = rc % 23;
        int gy = y0 - 3 + r, gx = x0 - 3 + c;
        float v = 0.f;
        if (gy >= 0 && gy < PH && gx >= 0 && gx < PW)
          v = pb[((size_t)(2 * (cc + 1) + pl) * PH + gy) * PW + gx];
        pt[t] = v;
      }
    }

    #pragma unroll
    for (int ky = 0; ky < 5; ky++) {
      #pragma unroll
      for (int kx = 0; kx < 5; kx++) {
        bf16x8 bfr[4];
        #pragma unroll
        for (int n = 0; n < 4; n++) {
          int f = (n * 4 + cc) * 25 + ky * 5 + kx;
          bfr[n] = *(const bf16x8*)(w1B + ((size_t)f << 9) + (lane << 3));
        }
        bf16x8 av[4];
        #pragma unroll
        for (int i = 0; i < 4; i++) {
          int mt = wave * 4 + i;
          av[i] = *(const bf16x8*)(desc + ((mt + ky) * 20 + lm + kx) * 40 + quad * 8);
        }
        #pragma unroll
        for (int n = 0; n < 4; n++)
          #pragma unroll
          for (int i = 0; i < 4; i++)
            acc[n][i] = __builtin_amdgcn_mfma_f32_16x16x32_bf16(av[i], bfr[n], acc[n][i], 0, 0, 0);
      }
    }
  }

  // epilogue in two 32-co halves: transpose via LDS, store, fused GN stats
  float* ob = out + (size_t)b * 64 * NPIX;
  for (int h = 0; h < 2; h++) {
    __syncthreads();
    #pragma unroll
    for (int nn = 0; nn < 2; nn++)
      #pragma unroll
      for (int i = 0; i < 4; i++)
        #pragma unroll
        for (int r = 0; r < 4; r++)
          cout[(nn * 16 + lm) * 261 + (wave * 4 + i) * 16 + quad * 4 + r] = acc[h * 2 + nn][i][r];
    __syncthreads();
    for (int v = tid; v < 8192; v += 256) {
      int col = v >> 8, px = v & 255;
      int y = y0 + (px >> 4), x = x0 + (px & 15);
      if (y < IH)
        ob[(size_t)(h * 32 + col) * NPIX + y * IW + x] = cout[col * 261 + px] + bias[h * 32 + col];
    }
    // stats: 32 co x 8 segs (2 rows each)
    int col = tid >> 3, seg = tid & 7;
    int co = h * 32 + col;
    float bv = bias[co];
    float sum = 0.f, sq = 0.f;
    #pragma unroll
    for (int rr = 0; rr < 2; rr++) {
      int row = seg * 2 + rr;
      if (y0 + row < IH) {
        #pragma unroll
        for (int k = 0; k < 16; k++) {
          float vv = cout[col * 261 + row * 16 + k] + bv;
          sum += vv; sq += vv * vv;
        }
      }
    }
    sum += __shfl_down(sum, 4); sq += __shfl_down(sq, 4);
    sum += __shfl_down(sum, 2); sq += __shfl_down(sq, 2);
    sum += __shfl_down(sum, 1); sq += __shfl_down(sq, 1);
    if ((tid & 7) == 0) {
      atomicAdd(&stats[(b * 64 + co) * 2], sum);
      atomicAdd(&stats[(b * 64 + co) * 2 + 1], sq);
    }
  }
}

// ============================================================
// 3x3 conv via MFMA, 16x8 tile, fused input-GN (coefs computed in
// prologue from stats) + fused output stats. grid (32,34,NB).
// ============================================================
template <int CI, int CO, int CHPER, bool STATS>
__global__ __launch_bounds__(256) void convk3_mfma_kernel(
    const float* __restrict__ xin, const short* __restrict__ wB,
    const float* __restrict__ bias, const float* __restrict__ statsIn,
    const float* __restrict__ gamma, const float* __restrict__ beta,
    float* __restrict__ statsOut, float* __restrict__ out) {
  constexpr int CHUNKS = CI / 32;
  constexpr int G = CO / 16;           // co-groups (2 or 1)
  constexpr int MPW = 2 * G;           // m-tiles per wave (4 or 2)
  constexpr int CIS = CI + 8;          // LDS short-stride per position
  constexpr int TILE_B = 180 * CIS * 2;
  constexpr int COUT_B = CO * 133 * 4;
  constexpr int UNION_B = TILE_B > COUT_B ? TILE_B : COUT_B;
  __shared__ __align__(16) char sm[UNION_B + CI * 8];
  short* tile = (short*)sm;
  float* cout = (float*)sm;
  float* cA = (float*)(sm + UNION_B);
  float* cB = cA + CI;

  const int b = blockIdx.z;
  const int x0 = blockIdx.x * 16, y0 = blockIdx.y * 8;
  const int tid = threadIdx.x;
  const int wave = tid >> 6, lane = tid & 63;
  const int quad = lane >> 4, lm = lane & 15;
  const int n = wave % G, mh = wave / G;

  gn_coef_thread(statsIn, gamma, beta, cA, cB, CI, CHPER, b);
  __syncthreads();

  const float* xb = xin + (size_t)b * CI * NPIX;
  for (int v = tid; v < (CI / 2) * 180; v += 256) {
    int cp = v / 180, pos = v % 180;
    int r = pos / 18, c = pos % 18;
    int gy = y0 - 1 + r, gx = x0 - 1 + c;
    float v0 = 0.f, v1 = 0.f;
    if (gy >= 0 && gy < IH && gx >= 0 && gx < IW) {
      v0 = fmaxf(fmaf(xb[(size_t)(2 * cp) * NPIX + gy * IW + gx], cA[2 * cp], cB[2 * cp]), 0.f);
      v1 = fmaxf(fmaf(xb[(size_t)(2 * cp + 1) * NPIX + gy * IW + gx], cA[2 * cp + 1], cB[2 * cp + 1]), 0.f);
    }
    unsigned pk = (unsigned)(unsigned short)f2bf(v0) |
                  ((unsigned)(unsigned short)f2bf(v1) << 16);
    *(unsigned*)(tile + pos * CIS + 2 * cp) = pk;
  }
  __syncthreads();

  floatx4 acc[MPW];
  #pragma unroll
  for (int i = 0; i < MPW; i++) acc[i] = (floatx4){0.f, 0.f, 0.f, 0.f};

  #pragma unroll
  for (int cc = 0; cc < CHUNKS; cc++) {
    #pragma unroll
    for (int ky = 0; ky < 3; ky++) {
      #pragma unroll
      for (int kx = 0; kx < 3; kx++) {
        int f = (n * CHUNKS + cc) * 9 + ky * 3 + kx;
        bf16x8 bfr = *(const bf16x8*)(wB + ((size_t)f << 9) + (lane << 3));
        #pragma unroll
        for (int i = 0; i < MPW; i++) {
          int mt = mh * MPW + i;
          bf16x8 av = *(const bf16x8*)(tile + ((mt + ky) * 18 + lm + kx) * CIS + cc * 32 + quad * 8);
          acc[i] = __builtin_amdgcn_mfma_f32_16x16x32_bf16(av, bfr, acc[i], 0, 0, 0);
        }
      }
    }
  }
  __syncthreads();   // tile consumed; cout overlays
  #pragma unroll
  for (int i = 0; i < MPW; i++) {
    #pragma unroll
    for (int r = 0; r < 4; r++) {
      int pixel = (mh * MPW + i) * 16 + quad * 4 + r;
      cout[(n * 16 + lm) * 133 + pixel] = acc[i][r];
    }
  }
  __syncthreads();
  float* ob = out + (size_t)b * CO * NPIX;
  for (int v = tid; v < CO * 128; v += 256) {
    int co = v >> 7, px = v & 127;
    int y = y0 + (px >> 4), x = x0 + (px & 15);
    if (y < IH) ob[(size_t)co * NPIX + y * IW + x] = cout[co * 133 + px] + bias[co];
  }
  if (STATS) {
    constexpr int TPC = 256 / CO;     // threads per channel (8 or 16)
    constexpr int PXT = 128 / TPC;    // pixels per thread
    int col = tid / TPC, seg = tid % TPC;
    float bv = bias[col];
    float sum = 0.f, sq = 0.f;
    #pragma unroll
    for (int k = 0; k < PXT; k++) {
      int p = seg * PXT + k;
      if (y0 + (p >> 4) < IH) {
        float vv = cout[col * 133 + p] + bv;
        sum += vv; sq += vv * vv;
      }
    }
    #pragma unroll
    for (int off = TPC / 2; off > 0; off >>= 1) {
      sum += __shfl_down(sum, off);
      sq  += __shfl_down(sq, off);
    }
    if (seg == 0) {
      atomicAdd(&statsOut[(b * CO + col) * 2], sum);
      atomicAdd(&statsOut[(b * CO + col) * 2 + 1], sq);
    }
  }
}

// ============================================================
// Small direct fp32 3x3 conv, 16x8 tile, fused input GN+ReLU (coef
// prologue), optional output stats via LDS atomics.
// ============================================================
template <int CI, int CO, int CHPER, bool STATS>
__global__ __launch_bounds__(256) void convs_kernel(
    const float* __restrict__ xin, const float* __restrict__ wT,
    const float* __restrict__ bias, const float* __restrict__ statsIn,
    const float* __restrict__ gamma, const float* __restrict__ beta,
    float* __restrict__ statsOut, float* __restrict__ out) {
  constexpr int OPT = CO / 2;
  const int b = blockIdx.z;
  const int x0 = blockIdx.x * 16, y0 = blockIdx.y * 8;
  __shared__ float tile[CI * 180];
  __shared__ float cA[CI], cB[CI];
  __shared__ float ssum[CO], ssq[CO];
  gn_coef_thread(statsIn, gamma, beta, cA, cB, CI, CHPER, b);
  if (STATS && threadIdx.x < CO) { ssum[threadIdx.x] = 0.f; ssq[threadIdx.x] = 0.f; }
  __syncthreads();
  const float* xb = xin + (size_t)b * CI * NPIX;
  for (int t = threadIdx.x; t < CI * 180; t += 256) {
    int ci = t / 180, rc = t % 180, r = rc / 18, c = rc % 18;
    int gy = y0 - 1 + r, gx = x0 - 1 + c;
    float v = 0.f;
    if (gy >= 0 && gy < IH && gx >= 0 && gx < IW)
      v = fmaxf(fmaf(xb[(size_t)ci * NPIX + gy * IW + gx], cA[ci], cB[ci]), 0.f);
    tile[t] = v;
  }
  __syncthreads();
  const int t = threadIdx.x;
  const int px = t & 127, og = t >> 7;
  const int pyy = px >> 4, pxx = px & 15;
  const int oc0 = og * OPT;
  const int y = y0 + pyy, x = x0 + pxx;
  float acc[OPT] = {};
  for (int ky = 0; ky < 3; ky++) {
    for (int kx = 0; kx < 3; kx++) {
      const float* wrow = wT + (size_t)((ky * 3 + kx) * CI) * CO + oc0;
      for (int ci = 0; ci < CI; ci++) {
        float v = tile[ci * 180 + (pyy + ky) * 18 + pxx + kx];
        #pragma unroll
        for (int o = 0; o < OPT; o++) acc[o] = fmaf(v, wrow[ci * CO + o], acc[o]);
      }
    }
  }
  if (y < IH) {
    float* ob = out + (size_t)b * CO * NPIX;
    #pragma unroll
    for (int o = 0; o < OPT; o++) {
      float vv = acc[o] + bias[oc0 + o];
      ob[(size_t)(oc0 + o) * NPIX + y * IW + x] = vv;
      if (STATS) {
        atomicAdd(&ssum[oc0 + o], vv);
        atomicAdd(&ssq[oc0 + o], vv * vv);
      }
    }
  }
  if (STATS) {
    __syncthreads();
    if (threadIdx.x < CO) {
      atomicAdd(&statsOut[(b * CO + threadIdx.x) * 2], ssum[threadIdx.x]);
      atomicAdd(&statsOut[(b * CO + threadIdx.x) * 2 + 1], ssq[threadIdx.x]);
    }
  }
}

// ============================================================
// Joint bilateral 5x5 (reflect), guide fused, global min/max fused
// (order-independent atomic min/max on monotone keys).
// ============================================================
__global__ __launch_bounds__(256) void bilateral_kernel(
    const float* __restrict__ f, const float* __restrict__ gt,
    float* __restrict__ out, unsigned* __restrict__ mmbits) {
  const int b = blockIdx.z;
  const int x0 = blockIdx.x * 16, y0 = blockIdx.y * 16;
  __shared__ float gu[20][20], gv[20][20], f0s[20][20], f1s[20][20];
  __shared__ float red[4][4];
  const float* gtb = gt + (size_t)b * 3 * NPIX;
  const float* fb = f + (size_t)b * 2 * NPIX;
  for (int t = threadIdx.x; t < 400; t += 256) {
    int r = t / 20, c = t % 20;
    int gy = y0 - 2 + r, gx = x0 - 2 + c;
    if (gy < 0) gy = -gy;
    if (gy > IH - 1) gy = 2 * (IH - 1) - gy;
    if (gx < 0) gx = -gx;
    if (gx > IW - 1) gx = 2 * (IW - 1) - gx;
    int p = gy * IW + gx;
    float rr = gtb[p], gg = gtb[NPIX + p], bb = gtb[2 * NPIX + p];
    gu[r][c]  = -0.147f * rr - 0.289f * gg + 0.436f * bb;
    gv[r][c]  =  0.615f * rr - 0.515f * gg - 0.100f * bb;
    f0s[r][c] = fb[p];
    f1s[r][c] = fb[NPIX + p];
  }
  __syncthreads();
  const int t = threadIdx.x;
  const int lx = t % 16, ly = t / 16;
  const int y = y0 + ly, x = x0 + lx;
  const bool valid = (y < IH);

  float o0 = 0.f, o1 = 0.f;
  if (valid) {
    float g1v[5];
    float s = 0.f;
    #pragma unroll
    for (int k = 0; k < 5; k++) {
      float a = (float)(k - 2);
      g1v[k] = expf(-a * a / 4.5f);
      s += g1v[k];
    }
    #pragma unroll
    for (int k = 0; k < 5; k++) g1v[k] /= s;
    float cu = gu[ly + 2][lx + 2], cv = gv[ly + 2][lx + 2];
    float num0 = 0.f, num1 = 0.f, den = 0.f;
    #pragma unroll
    for (int dy = 0; dy < 5; dy++) {
      #pragma unroll
      for (int dx = 0; dx < 5; dx++) {
        float du = fabsf(gu[ly + dy][lx + dx] - cu) + fabsf(gv[ly + dy][lx + dx] - cv);
        float wgt = g1v[dy] * g1v[dx] * expf(-50.0f * du * du);
        num0 = fmaf(wgt, f0s[ly + dy][lx + dx], num0);
        num1 = fmaf(wgt, f1s[ly + dy][lx + dx], num1);
        den += wgt;
      }
    }
    o0 = num0 / den; o1 = num1 / den;
    float* ob = out + (size_t)b * 2 * NPIX;
    ob[y * IW + x] = o0;
    ob[NPIX + y * IW + x] = o1;
  }
  // block-level min/max reduce -> device atomics
  float mn0 = valid ? o0 : 1e30f,  mx0 = valid ? o0 : -1e30f;
  float mn1 = valid ? o1 : 1e30f,  mx1 = valid ? o1 : -1e30f;
  #pragma unroll
  for (int off = 32; off > 0; off >>= 1) {
    mn0 = fminf(mn0, __shfl_xor(mn0, off));
    mx0 = fmaxf(mx0, __shfl_xor(mx0, off));
    mn1 = fminf(mn1, __shfl_xor(mn1, off));
    mx1 = fmaxf(mx1, __shfl_xor(mx1, off));
  }
  if ((t & 63) == 0) {
    red[t >> 6][0] = mn0; red[t >> 6][1] = mx0;
    red[t >> 6][2] = mn1; red[t >> 6][3] = mx1;
  }
  __syncthreads();
  if (t == 0) {
    for (int w = 1; w < 4; w++) {
      red[0][0] = fminf(red[0][0], red[w][0]);
      red[0][1] = fmaxf(red[0][1], red[w][1]);
      red[0][2] = fminf(red[0][2], red[w][2]);
      red[0][3] = fmaxf(red[0][3], red[w][3]);
    }
    atomicMax(&mmbits[0], fkey(red[0][1]));   // max0
    atomicMax(&mmbits[1], fkey(red[0][3]));   // max1
    atomicMin(&mmbits[2], fkey(red[0][0]));   // min0
    atomicMin(&mmbits[3], fkey(red[0][2]));   // min1
  }
}

// ============================================================
// Final: rescale U/V from atomic min/max keys, YUV->RGB
// ============================================================
__global__ __launch_bounds__(256) void final_kernel(
    const float* __restrict__ bil, const float* __restrict__ x,
    const unsigned* __restrict__ mmbits, float* __restrict__ out) {
  int i = blockIdx.x * 256 + threadIdx.x;
  if (i >= NB * NPIX) return;
  float mx0 = funkey(mmbits[0]), mx1 = funkey(mmbits[1]);
  float mn0 = funkey(mmbits[2]), mn1 = funkey(mmbits[3]);
  int b = i / NPIX, p = i % NPIX;
  float f0 = bil[(size_t)b * 2 * NPIX + p];
  float f1 = bil[(size_t)b * 2 * NPIX + NPIX + p];
  float U = (f0 - mn0) / (mx0 - mn0 + 1e-6f);
  U = fminf(fmaxf(U, 0.f), 1.f) * 0.872f - 0.436f;
  float V = (f1 - mn1) / (mx1 - mn1 + 1e-6f);
  V = fminf(fmaxf(V, 0.f), 1.f) * 1.23f - 0.615f;
  float Y = x[(size_t)b * NPIX + p];
  float* ob = out + (size_t)b * 3 * NPIX;
  ob[p]            = Y + 1.14f * V;
  ob[NPIX + p]     = Y - 0.396f * U - 0.581f * V;
  ob[2 * NPIX + p] = Y + 2.029f * U;
}

// ============================================================
// launch
// ============================================================
extern "C" void kernel_launch(void* const* d_in, const int* in_sizes, int n_in,
                              void* d_out, int out_size, void* d_ws, size_t ws_size,
                              hipStream_t stream) {
  const float* x   = (const float*)d_in[0];
  const float* gt  = (const float*)d_in[1];
  const float* w1  = (const float*)d_in[2];
  const float* b1  = (const float*)d_in[3];
  const float* g1w = (const float*)d_in[4];
  const float* g1b = (const float*)d_in[5];
  const float* w2  = (const float*)d_in[6];
  const float* b2  = (const float*)d_in[7];
  const float* g2w = (const float*)d_in[8];
  const float* g2b = (const float*)d_in[9];
  const float* w3  = (const float*)d_in[10];
  const float* b3  = (const float*)d_in[11];
  const float* g3w = (const float*)d_in[12];
  const float* g3b = (const float*)d_in[13];
  const float* w4  = (const float*)d_in[14];
  const float* b4  = (const float*)d_in[15];
  const float* g4w = (const float*)d_in[16];
  const float* g4b = (const float*)d_in[17];
  const float* w5  = (const float*)d_in[18];
  const float* b5  = (const float*)d_in[19];
  float* out = (float*)d_out;

  // ---- workspace layout ----
  char* ws = (char*)d_ws;
  float* stats1 = (float*)ws;                  // 512
  float* stats2 = stats1 + 512;                // 256
  float* stats3 = stats2 + 256;                // 128
  float* stats4 = stats3 + 128;                // 64  (ends 960)
  unsigned* mmbits = (unsigned*)(ws + 12288);  // [max0,max1,min0,min1]
  float* fbase  = (float*)(ws + 16384);
  size_t off = 0;
  float* pooled = fbase + off; off += 4452864;   // NB*8*PH*PW
  float* s1g    = fbase + off; off += 1105920;   // NB*2*NPIX
  short* w1B    = (short*)(fbase + off); off += 102400;  // 204800 bf16
  short* w2B    = (short*)(fbase + off); off += 9216;
  short* w3B    = (short*)(fbase + off); off += 2304;
  float* w4T    = fbase + off; off += 1152;
  float* w5T    = fbase + off; off += 256;
  float* bufA   = fbase + off; off += 35389440;  // 64ch fp32 (also c3 out)
  float* bufB   = fbase + off; off += 17694720;  // 32ch fp32 (also c4 out)
  float* c5     = pooled;                        // alias: pooled dead by conv5
  float* bilat  = pooled + 1105920;              // alias

  hipMemsetAsync(ws, 0, 12304, stream);              // stats + max keys
  hipMemsetAsync(ws + 12296, 0xFF, 8, stream);       // min keys

  // ---- weight prep (single kernel) ----
  prep_kernel<<<896, 256, 0, stream>>>(w1, w2, w3, w4, w5, w1B, w2B, w3B, w4T, w5T);

  // ---- SIFT front-end ----
  pooled_kernel<<<dim3(33, 17, NB), 256, 0, stream>>>(x, pooled);
  sift_scalars_kernel<<<dim3(32, 17, NB), 256, 0, stream>>>(pooled, s1g);
  conv1_mfma_kernel<<<dim3(32, 17, NB), 256, 0, stream>>>(pooled, s1g, w1B, b1, bufA, stats1);

  // ---- conv2 (64->32, GN1 on input, stats2 fused) ----
  convk3_mfma_kernel<64, 32, 8, true><<<dim3(32, 34, NB), 256, 0, stream>>>(
      bufA, w2B, b2, stats1, g1w, g1b, stats2, bufB);

  // ---- conv3 (32->16, GN2 on input, stats3 fused) ----
  convk3_mfma_kernel<32, 16, 4, true><<<dim3(32, 34, NB), 256, 0, stream>>>(
      bufB, w3B, b3, stats2, g2w, g2b, stats3, bufA);

  // ---- conv4 (16->8, GN3 on input, stats4 fused) ----
  convs_kernel<16, 8, 4, true><<<dim3(32, 34, NB), 256, 0, stream>>>(
      bufA, w4T, b4, stats3, g3w, g3b, stats4, bufB);

  // ---- conv5 (8->2, GN4 on input) ----
  convs_kernel<8, 2, 2, false><<<dim3(32, 34, NB), 256, 0, stream>>>(
      bufB, w5T, b5, stats4, g4w, g4b, nullptr, c5);

  // ---- bilateral (guide + minmax fused) + composite ----
  bilateral_kernel<<<dim3(32, 17, NB), 256, 0, stream>>>(c5, gt, bilat, mmbits);
  final_kernel<<<(NB * NPIX + 255) / 256, 256, 0, stream>>>(bilat, x, mmbits, out);

  (void)in_sizes; (void)n_in; (void)out_size; (void)ws_size;
}

// Round 5
// 1415.028 us; speedup vs baseline: 10.1122x; 1.0788x over previous
//
#include <hip/hip_runtime.h>

// ---------------- problem constants ----------------
constexpr int NB  = 4;
constexpr int IH  = 270;
constexpr int IW  = 512;
constexpr int NPIX = IH * IW;      // 138240
constexpr int PH  = 271;           // pooled height
constexpr int PW  = 513;           // pooled width
constexpr float TWO_PI_F = 6.28318530717958647692f;

typedef short  bf16x8 __attribute__((ext_vector_type(8)));
typedef float floatx4 __attribute__((ext_vector_type(4)));

__device__ inline short f2bf(float x) {
  union { float f; unsigned u; } un; un.f = x;
  unsigned r = un.u + 0x7fff + ((un.u >> 16) & 1);   // RNE
  return (short)(r >> 16);
}
// monotone float<->uint keys for atomic min/max
__device__ inline unsigned fkey(float f) {
  unsigned u = __float_as_uint(f);
  return (u & 0x80000000u) ? ~u : (u | 0x80000000u);
}
__device__ inline float funkey(unsigned k) {
  unsigned u = (k & 0x80000000u) ? (k ^ 0x80000000u) : ~k;
  return __uint_as_float(u);
}
// per-thread GN coef (thread c < C): A,B from fp32 stats
__device__ inline void gn_coef_thread(const float* __restrict__ stats,
                                      const float* __restrict__ gamma,
                                      const float* __restrict__ beta,
                                      float* cA, float* cB, int C, int chper, int b) {
  int c = threadIdx.x;
  if (c < C) {
    int g0 = (c / chper) * chper;
    float S = 0.f, S2 = 0.f;
    for (int k = 0; k < chper; k++) {
      S  += stats[(b * C + g0 + k) * 2];
      S2 += stats[(b * C + g0 + k) * 2 + 1];
    }
    double Nd = (double)chper * NPIX;
    double mu = (double)S / Nd;
    double var = (double)S2 / Nd - mu * mu;
    double rstd = 1.0 / sqrt(var + 1e-5);
    float A = (float)rstd * gamma[c];
    cA[c] = A;
    cB[c] = beta[c] - (float)mu * A;
  }
}

// ============================================================
// Combined weight prep: all MFMA B-packs + fp32 repacks, one kernel.
// ============================================================
__device__ inline void mfma_pack_one(const float* __restrict__ w, short* __restrict__ wB,
                                     int i, int CO, int CI, int KK, int CHUNKS) {
  int j = i & 7, l = (i >> 3) & 63, f = i >> 9;
  int t = f % KK; int fc = f / KK; int cc = fc % CHUNKS; int g = fc / CHUNKS;
  int ci = cc * 32 + ((l >> 4) << 3) + j;
  int co = g * 16 + (l & 15);
  float v = (ci < CI && co < CO) ? w[((size_t)co * CI + ci) * KK + t] : 0.f;
  wB[i] = f2bf(v);
}
__device__ inline void repack_one(const float* __restrict__ w, float* __restrict__ wT,
                                  int i, int CO, int CI, int KK) {
  int o = i / (CI * KK);
  int r = i % (CI * KK);
  int ci = r / KK, kk = r % KK;
  wT[(kk * CI + ci) * CO + o] = w[i];
}
__global__ __launch_bounds__(256) void prep_kernel(
    const float* __restrict__ w1, const float* __restrict__ w2,
    const float* __restrict__ w3, const float* __restrict__ w4,
    const float* __restrict__ w5,
    short* __restrict__ w1B, short* __restrict__ w2B, short* __restrict__ w3B,
    float* __restrict__ w4T, float* __restrict__ w5T) {
  constexpr int N1 = 4 * 4 * 25 * 512;   // 204800
  constexpr int N2 = 2 * 2 * 9 * 512;    // 18432
  constexpr int N3 = 1 * 1 * 9 * 512;    // 4608
  constexpr int N4 = 8 * 16 * 9;         // 1152
  constexpr int N5 = 2 * 8 * 9;          // 144
  int i = blockIdx.x * 256 + threadIdx.x;
  if (i < N1) { mfma_pack_one(w1, w1B, i, 64, 128, 25, 4); return; }
  i -= N1;
  if (i < N2) { mfma_pack_one(w2, w2B, i, 32, 64, 9, 2); return; }
  i -= N2;
  if (i < N3) { mfma_pack_one(w3, w3B, i, 16, 32, 9, 1); return; }
  i -= N3;
  if (i < N4) { repack_one(w4, w4T, i, 8, 16, 9); return; }
  i -= N4;
  if (i < N5) { repack_one(w5, w5T, i, 2, 8, 9); return; }
}

// ============================================================
// Stage 1: x -> pooled (8 ch, PH x PW).
// ============================================================
__global__ __launch_bounds__(256) void pooled_kernel(
    const float* __restrict__ x, float* __restrict__ pooled) {
  const int b = blockIdx.z;
  const int px0 = blockIdx.x * 16, py0 = blockIdx.y * 16;
  __shared__ float wo0s[19][19];
  __shared__ float wo1s[19][19];
  __shared__ int   bo0s[19][19];
  const float* xb = x + (size_t)b * NPIX;

  for (int t = threadIdx.x; t < 19 * 19; t += 256) {
    int r = t / 19, c = t % 19;
    int gy = py0 - 2 + r, gx = px0 - 2 + c;
    float w0 = 0.f, w1v = 0.f; int b0 = 0;
    if (gy >= 0 && gy < IH && gx >= 0 && gx < IW) {
      int xm = gx > 0 ? gx - 1 : 0, xp = gx < IW - 1 ? gx + 1 : IW - 1;
      int ym = gy > 0 ? gy - 1 : 0, yp = gy < IH - 1 ? gy + 1 : IH - 1;
      float gxv = (xb[gy * IW + xp] - xb[gy * IW + xm]) * 0.5f;
      float gyv = (xb[yp * IW + gx] - xb[ym * IW + gx]) * 0.5f;
      float mag = sqrtf(gxv * gxv + gyv * gyv + 1e-10f);
      float ori = atan2f(gyv, gxv + 1e-10f) + TWO_PI_F;
      float obig = ori * (8.0f / TWO_PI_F);
      float bf = floorf(obig);
      float w1_ = obig - bf;
      w0  = (1.0f - w1_) * mag;
      w1v = w1_ * mag;
      b0  = ((int)bf) & 7;
    }
    wo0s[r][c] = w0; wo1s[r][c] = w1v; bo0s[r][c] = b0;
  }
  __syncthreads();

  const int t = threadIdx.x;
  const int lx = t % 16, ly = t / 16;
  const int py = py0 + ly, px = px0 + lx;
  if (py >= PH || px >= PW) return;

  const float pwt[4] = {0.25f, 0.75f, 0.75f, 0.25f};
  float acc[8] = {0, 0, 0, 0, 0, 0, 0, 0};
  for (int i = 0; i < 4; i++) {
    for (int j = 0; j < 4; j++) {
      int r = ly + i, c = lx + j;
      float w0 = wo0s[r][c], w1v = wo1s[r][c];
      int b0 = bo0s[r][c];
      int b1i = (b0 + 1) & 7;
      float pw = pwt[i] * pwt[j];
      #pragma unroll
      for (int a = 0; a < 8; a++) {
        float add = (a == b0 ? w0 : 0.f) + (a == b1i ? w1v : 0.f);
        acc[a] = fmaf(pw, add, acc[a]);
      }
    }
  }
  float* pb = pooled + (size_t)b * 8 * PH * PW;
  #pragma unroll
  for (int a = 0; a < 8; a++) pb[((size_t)a * PH + py) * PW + px] = acc[a];
}

// ============================================================
// Stage 2: per-pixel SIFT normalization scalars s1, g
// ============================================================
__global__ __launch_bounds__(256) void sift_scalars_kernel(
    const float* __restrict__ pooled, float* __restrict__ s1g) {
  const int b = blockIdx.z;
  const int x0 = blockIdx.x * 16, y0 = blockIdx.y * 16;
  __shared__ float pt[8][19][19];
  const float* pb = pooled + (size_t)b * 8 * PH * PW;
  for (int t = threadIdx.x; t < 8 * 19 * 19; t += 256) {
    int a = t / 361, rc = t % 361, r = rc / 19, c = rc % 19;
    int gy = y0 - 1 + r, gx = x0 - 1 + c;
    float v = 0.f;
    if (gy >= 0 && gy < PH && gx >= 0 && gx < PW) v = pb[((size_t)a * PH + gy) * PW + gx];
    pt[a][r][c] = v;
  }
  __syncthreads();
  const int t = threadIdx.x;
  const int lx = t % 16, ly = t / 16;
  const int y = y0 + ly, x = x0 + lx;
  if (y >= IH) return;

  float sum2 = 0.f;
  for (int c = 0; c < 128; c++) {
    int a = c >> 4, i = (c >> 2) & 3, j = c & 3;
    float p = pt[a][ly + i][lx + j];
    sum2 = fmaf(p, p, sum2);
  }
  float s1 = 1.0f / fmaxf(sqrtf(sum2), 1e-12f);
  float st2 = 0.f, st = 0.f;
  for (int c = 0; c < 128; c++) {
    int a = c >> 4, i = (c >> 2) & 3, j = c & 3;
    float p = pt[a][ly + i][lx + j];
    float tv = fminf(p * s1, 0.2f);
    st2 = fmaf(tv, tv, st2);
    st += tv;
  }
  float s2 = 1.0f / fmaxf(sqrtf(st2), 1e-12f);
  float l1 = fmaxf(s2 * st, 1e-12f);
  float g = s2 / l1;
  float* o = s1g + (size_t)b * 2 * NPIX;
  o[y * IW + x] = s1;
  o[NPIX + y * IW + x] = g;
}

// ============================================================
// Conv1 via MFMA, 16x16 tile. Wave w: M-tiles 4w..4w+3, ALL 4 co-groups
// (each A ds_read feeds 4 MFMAs). Pooled planes staged 2-per-chunk,
// prefetched during MFMA. LDS ~39.4KB.
// NOTE: min-waves arg must stay <=2 — (256,4) caps VGPR at 64 and spills
// the 64-reg accumulator to scratch (R4: 1.33 GB HBM traffic, 655 us).
// grid (32,17,NB), block 256.
// ============================================================
__global__ __launch_bounds__(256, 2) void conv1_mfma_kernel(
    const float* __restrict__ pooled, const float* __restrict__ s1g,
    const short* __restrict__ w1B, const float* __restrict__ bias,
    float* __restrict__ out, float* __restrict__ stats) {
  const int b = blockIdx.z;
  const int x0 = blockIdx.x * 16, y0 = blockIdx.y * 16;
  __shared__ __align__(16) char smem_raw[39440];
  short* desc = (short*)smem_raw;                 // [400 pos][40] bf16
  float* sc   = (float*)(smem_raw + 32000);       // [2][400]
  float* pt   = (float*)(smem_raw + 35208);       // [2][529] (2 planes)
  float* cout = (float*)smem_raw;                 // epilogue [32][261]

  const int tid = threadIdx.x;
  const int wave = tid >> 6, lane = tid & 63;
  const int quad = lane >> 4, lm = lane & 15;

  const float* pb = pooled + (size_t)b * 8 * PH * PW;
  const float* sb = s1g + (size_t)b * 2 * NPIX;
  for (int t = tid; t < 400; t += 256) {
    int r = t / 20, c = t % 20;
    int gy = y0 - 2 + r, gx = x0 - 2 + c;
    float a0 = 0.f, a1 = 0.f;
    if (gy >= 0 && gy < IH && gx >= 0 && gx < IW) {
      a0 = sb[gy * IW + gx];
      a1 = sb[NPIX + gy * IW + gx];
    }
    sc[t] = a0; sc[400 + t] = a1;
  }
  // stage planes 0,1 (chunk 0)
  for (int t = tid; t < 1058; t += 256) {
    int pl = t / 529, rc = t % 529, r = rc / 23, c = rc % 23;
    int gy = y0 - 3 + r, gx = x0 - 3 + c;
    float v = 0.f;
    if (gy >= 0 && gy < PH && gx >= 0 && gx < PW) v = pb[((size_t)pl * PH + gy) * PW + gx];
    pt[t] = v;
  }

  floatx4 acc[4][4];   // [n-group][m-tile]
  #pragma unroll
  for (int n = 0; n < 4; n++)
    #pragma unroll
    for (int i = 0; i < 4; i++) acc[n][i] = (floatx4){0.f, 0.f, 0.f, 0.f};

  for (int cc = 0; cc < 4; cc++) {
    __syncthreads();   // planes for cc staged; desc of cc-1 consumed
    // regen desc chunk cc from pt (planes 2cc, 2cc+1)
    for (int v = tid; v < 3200; v += 256) {
      int pos = v % 400, cg = v / 400;   // cg: group of 4 ci within chunk
      int r = pos / 20, c = pos % 20;
      int gy = y0 - 2 + r, gx = x0 - 2 + c;
      bool ok = (gy >= 0 && gy < IH && gx >= 0 && gx < IW);
      int al = cg >> 2;          // local plane
      int ii = cg & 3;           // i
      float s1v = sc[pos], gv = sc[400 + pos];
      const float* prow = pt + al * 529 + (r + ii) * 23 + c;
      unsigned short o4[4];
      #pragma unroll
      for (int q = 0; q < 4; q++) {
        float p = prow[q];
        float val = ok ? sqrtf(fminf(p * s1v, 0.2f) * gv + 1e-10f) : 0.f;
        o4[q] = (unsigned short)f2bf(val);
      }
      uint2 pk;
      pk.x = (unsigned)o4[0] | ((unsigned)o4[1] << 16);
      pk.y = (unsigned)o4[2] | ((unsigned)o4[3] << 16);
      *(uint2*)(desc + pos * 40 + cg * 4) = pk;
    }
    __syncthreads();   // desc ready; pt free

    // prefetch next chunk's planes into pt (overlaps MFMA below)
    if (cc < 3) {
      for (int t = tid; t < 1058; t += 256) {
        int pl = t / 529, rc = t % 529, r = rc / 23, c = rc % 23;
        int gy = y0 - 3 + r, gx = x0 - 3 + c;
        float v = 0.f;
        if (gy >= 0 && gy < PH && gx >= 0 && gx < PW)
          v = pb[((size_t)(2 * (cc + 1) + pl) * PH + gy) * PW + gx];
        pt[t] = v;
      }
    }

    #pragma unroll
    for (int ky = 0; ky < 5; ky++) {
      #pragma unroll
      for (int kx = 0; kx < 5; kx++) {
        bf16x8 bfr[4];
        #pragma unroll
        for (int n = 0; n < 4; n++) {
          int f = (n * 4 + cc) * 25 + ky * 5 + kx;
          bfr[n] = *(const bf16x8*)(w1B + ((size_t)f << 9) + (lane << 3));
        }
        bf16x8 av[4];
        #pragma unroll
        for (int i = 0; i < 4; i++) {
          int mt = wave * 4 + i;
          av[i] = *(const bf16x8*)(desc + ((mt + ky) * 20 + lm + kx) * 40 + quad * 8);
        }
        #pragma unroll
        for (int n = 0; n < 4; n++)
          #pragma unroll
          for (int i = 0; i < 4; i++)
            acc[n][i] = __builtin_amdgcn_mfma_f32_16x16x32_bf16(av[i], bfr[n], acc[n][i], 0, 0, 0);
      }
    }
  }

  // epilogue in two 32-co halves: transpose via LDS, store, fused GN stats
  float* ob = out + (size_t)b * 64 * NPIX;
  for (int h = 0; h < 2; h++) {
    __syncthreads();
    #pragma unroll
    for (int nn = 0; nn < 2; nn++)
      #pragma unroll
      for (int i = 0; i < 4; i++)
        #pragma unroll
        for (int r = 0; r < 4; r++)
          cout[(nn * 16 + lm) * 261 + (wave * 4 + i) * 16 + quad * 4 + r] = acc[h * 2 + nn][i][r];
    __syncthreads();
    for (int v = tid; v < 8192; v += 256) {
      int col = v >> 8, px = v & 255;
      int y = y0 + (px >> 4), x = x0 + (px & 15);
      if (y < IH)
        ob[(size_t)(h * 32 + col) * NPIX + y * IW + x] = cout[col * 261 + px] + bias[h * 32 + col];
    }
    // stats: 32 co x 8 segs (2 rows each)
    int col = tid >> 3, seg = tid & 7;
    int co = h * 32 + col;
    float bv = bias[co];
    float sum = 0.f, sq = 0.f;
    #pragma unroll
    for (int rr = 0; rr < 2; rr++) {
      int row = seg * 2 + rr;
      if (y0 + row < IH) {
        #pragma unroll
        for (int k = 0; k < 16; k++) {
          float vv = cout[col * 261 + row * 16 + k] + bv;
          sum += vv; sq += vv * vv;
        }
      }
    }
    sum += __shfl_down(sum, 4); sq += __shfl_down(sq, 4);
    sum += __shfl_down(sum, 2); sq += __shfl_down(sq, 2);
    sum += __shfl_down(sum, 1); sq += __shfl_down(sq, 1);
    if ((tid & 7) == 0) {
      atomicAdd(&stats[(b * 64 + co) * 2], sum);
      atomicAdd(&stats[(b * 64 + co) * 2 + 1], sq);
    }
  }
}

// ============================================================
// 3x3 conv via MFMA, 16x8 tile, fused input-GN (coefs computed in
// prologue from stats) + fused output stats. grid (32,34,NB).
// ============================================================
template <int CI, int CO, int CHPER, bool STATS>
__global__ __launch_bounds__(256) void convk3_mfma_kernel(
    const float* __restrict__ xin, const short* __restrict__ wB,
    const float* __restrict__ bias, const float* __restrict__ statsIn,
    const float* __restrict__ gamma, const float* __restrict__ beta,
    float* __restrict__ statsOut, float* __restrict__ out) {
  constexpr int CHUNKS = CI / 32;
  constexpr int G = CO / 16;           // co-groups (2 or 1)
  constexpr int MPW = 2 * G;           // m-tiles per wave (4 or 2)
  constexpr int CIS = CI + 8;          // LDS short-stride per position
  constexpr int TILE_B = 180 * CIS * 2;
  constexpr int COUT_B = CO * 133 * 4;
  constexpr int UNION_B = TILE_B > COUT_B ? TILE_B : COUT_B;
  __shared__ __align__(16) char sm[UNION_B + CI * 8];
  short* tile = (short*)sm;
  float* cout = (float*)sm;
  float* cA = (float*)(sm + UNION_B);
  float* cB = cA + CI;

  const int b = blockIdx.z;
  const int x0 = blockIdx.x * 16, y0 = blockIdx.y * 8;
  const int tid = threadIdx.x;
  const int wave = tid >> 6, lane = tid & 63;
  const int quad = lane >> 4, lm = lane & 15;
  const int n = wave % G, mh = wave / G;

  gn_coef_thread(statsIn, gamma, beta, cA, cB, CI, CHPER, b);
  __syncthreads();

  const float* xb = xin + (size_t)b * CI * NPIX;
  for (int v = tid; v < (CI / 2) * 180; v += 256) {
    int cp = v / 180, pos = v % 180;
    int r = pos / 18, c = pos % 18;
    int gy = y0 - 1 + r, gx = x0 - 1 + c;
    float v0 = 0.f, v1 = 0.f;
    if (gy >= 0 && gy < IH && gx >= 0 && gx < IW) {
      v0 = fmaxf(fmaf(xb[(size_t)(2 * cp) * NPIX + gy * IW + gx], cA[2 * cp], cB[2 * cp]), 0.f);
      v1 = fmaxf(fmaf(xb[(size_t)(2 * cp + 1) * NPIX + gy * IW + gx], cA[2 * cp + 1], cB[2 * cp + 1]), 0.f);
    }
    unsigned pk = (unsigned)(unsigned short)f2bf(v0) |
                  ((unsigned)(unsigned short)f2bf(v1) << 16);
    *(unsigned*)(tile + pos * CIS + 2 * cp) = pk;
  }
  __syncthreads();

  floatx4 acc[MPW];
  #pragma unroll
  for (int i = 0; i < MPW; i++) acc[i] = (floatx4){0.f, 0.f, 0.f, 0.f};

  #pragma unroll
  for (int cc = 0; cc < CHUNKS; cc++) {
    #pragma unroll
    for (int ky = 0; ky < 3; ky++) {
      #pragma unroll
      for (int kx = 0; kx < 3; kx++) {
        int f = (n * CHUNKS + cc) * 9 + ky * 3 + kx;
        bf16x8 bfr = *(const bf16x8*)(wB + ((size_t)f << 9) + (lane << 3));
        #pragma unroll
        for (int i = 0; i < MPW; i++) {
          int mt = mh * MPW + i;
          bf16x8 av = *(const bf16x8*)(tile + ((mt + ky) * 18 + lm + kx) * CIS + cc * 32 + quad * 8);
          acc[i] = __builtin_amdgcn_mfma_f32_16x16x32_bf16(av, bfr, acc[i], 0, 0, 0);
        }
      }
    }
  }
  __syncthreads();   // tile consumed; cout overlays
  #pragma unroll
  for (int i = 0; i < MPW; i++) {
    #pragma unroll
    for (int r = 0; r < 4; r++) {
      int pixel = (mh * MPW + i) * 16 + quad * 4 + r;
      cout[(n * 16 + lm) * 133 + pixel] = acc[i][r];
    }
  }
  __syncthreads();
  float* ob = out + (size_t)b * CO * NPIX;
  for (int v = tid; v < CO * 128; v += 256) {
    int co = v >> 7, px = v & 127;
    int y = y0 + (px >> 4), x = x0 + (px & 15);
    if (y < IH) ob[(size_t)co * NPIX + y * IW + x] = cout[co * 133 + px] + bias[co];
  }
  if (STATS) {
    constexpr int TPC = 256 / CO;     // threads per channel (8 or 16)
    constexpr int PXT = 128 / TPC;    // pixels per thread
    int col = tid / TPC, seg = tid % TPC;
    float bv = bias[col];
    float sum = 0.f, sq = 0.f;
    #pragma unroll
    for (int k = 0; k < PXT; k++) {
      int p = seg * PXT + k;
      if (y0 + (p >> 4) < IH) {
        float vv = cout[col * 133 + p] + bv;
        sum += vv; sq += vv * vv;
      }
    }
    #pragma unroll
    for (int off = TPC / 2; off > 0; off >>= 1) {
      sum += __shfl_down(sum, off);
      sq  += __shfl_down(sq, off);
    }
    if (seg == 0) {
      atomicAdd(&statsOut[(b * CO + col) * 2], sum);
      atomicAdd(&statsOut[(b * CO + col) * 2 + 1], sq);
    }
  }
}

// ============================================================
// Small direct fp32 3x3 conv, 16x8 tile, fused input GN+ReLU (coef
// prologue), optional output stats via LDS atomics.
// ============================================================
template <int CI, int CO, int CHPER, bool STATS>
__global__ __launch_bounds__(256) void convs_kernel(
    const float* __restrict__ xin, const float* __restrict__ wT,
    const float* __restrict__ bias, const float* __restrict__ statsIn,
    const float* __restrict__ gamma, const float* __restrict__ beta,
    float* __restrict__ statsOut, float* __restrict__ out) {
  constexpr int OPT = CO / 2;
  const int b = blockIdx.z;
  const int x0 = blockIdx.x * 16, y0 = blockIdx.y * 8;
  __shared__ float tile[CI * 180];
  __shared__ float cA[CI], cB[CI];
  __shared__ float ssum[CO], ssq[CO];
  gn_coef_thread(statsIn, gamma, beta, cA, cB, CI, CHPER, b);
  if (STATS && threadIdx.x < CO) { ssum[threadIdx.x] = 0.f; ssq[threadIdx.x] = 0.f; }
  __syncthreads();
  const float* xb = xin + (size_t)b * CI * NPIX;
  for (int t = threadIdx.x; t < CI * 180; t += 256) {
    int ci = t / 180, rc = t % 180, r = rc / 18, c = rc % 18;
    int gy = y0 - 1 + r, gx = x0 - 1 + c;
    float v = 0.f;
    if (gy >= 0 && gy < IH && gx >= 0 && gx < IW)
      v = fmaxf(fmaf(xb[(size_t)ci * NPIX + gy * IW + gx], cA[ci], cB[ci]), 0.f);
    tile[t] = v;
  }
  __syncthreads();
  const int t = threadIdx.x;
  const int px = t & 127, og = t >> 7;
  const int pyy = px >> 4, pxx = px & 15;
  const int oc0 = og * OPT;
  const int y = y0 + pyy, x = x0 + pxx;
  float acc[OPT] = {};
  for (int ky = 0; ky < 3; ky++) {
    for (int kx = 0; kx < 3; kx++) {
      const float* wrow = wT + (size_t)((ky * 3 + kx) * CI) * CO + oc0;
      for (int ci = 0; ci < CI; ci++) {
        float v = tile[ci * 180 + (pyy + ky) * 18 + pxx + kx];
        #pragma unroll
        for (int o = 0; o < OPT; o++) acc[o] = fmaf(v, wrow[ci * CO + o], acc[o]);
      }
    }
  }
  if (y < IH) {
    float* ob = out + (size_t)b * CO * NPIX;
    #pragma unroll
    for (int o = 0; o < OPT; o++) {
      float vv = acc[o] + bias[oc0 + o];
      ob[(size_t)(oc0 + o) * NPIX + y * IW + x] = vv;
      if (STATS) {
        atomicAdd(&ssum[oc0 + o], vv);
        atomicAdd(&ssq[oc0 + o], vv * vv);
      }
    }
  }
  if (STATS) {
    __syncthreads();
    if (threadIdx.x < CO) {
      atomicAdd(&statsOut[(b * CO + threadIdx.x) * 2], ssum[threadIdx.x]);
      atomicAdd(&statsOut[(b * CO + threadIdx.x) * 2 + 1], ssq[threadIdx.x]);
    }
  }
}

// ============================================================
// Joint bilateral 5x5 (reflect), guide fused, global min/max fused
// (order-independent atomic min/max on monotone keys).
// ============================================================
__global__ __launch_bounds__(256) void bilateral_kernel(
    const float* __restrict__ f, const float* __restrict__ gt,
    float* __restrict__ out, unsigned* __restrict__ mmbits) {
  const int b = blockIdx.z;
  const int x0 = blockIdx.x * 16, y0 = blockIdx.y * 16;
  __shared__ float gu[20][20], gv[20][20], f0s[20][20], f1s[20][20];
  __shared__ float red[4][4];
  const float* gtb = gt + (size_t)b * 3 * NPIX;
  const float* fb = f + (size_t)b * 2 * NPIX;
  for (int t = threadIdx.x; t < 400; t += 256) {
    int r = t / 20, c = t % 20;
    int gy = y0 - 2 + r, gx = x0 - 2 + c;
    if (gy < 0) gy = -gy;
    if (gy > IH - 1) gy = 2 * (IH - 1) - gy;
    if (gx < 0) gx = -gx;
    if (gx > IW - 1) gx = 2 * (IW - 1) - gx;
    int p = gy * IW + gx;
    float rr = gtb[p], gg = gtb[NPIX + p], bb = gtb[2 * NPIX + p];
    gu[r][c]  = -0.147f * rr - 0.289f * gg + 0.436f * bb;
    gv[r][c]  =  0.615f * rr - 0.515f * gg - 0.100f * bb;
    f0s[r][c] = fb[p];
    f1s[r][c] = fb[NPIX + p];
  }
  __syncthreads();
  const int t = threadIdx.x;
  const int lx = t % 16, ly = t / 16;
  const int y = y0 + ly, x = x0 + lx;
  const bool valid = (y < IH);

  float o0 = 0.f, o1 = 0.f;
  if (valid) {
    float g1v[5];
    float s = 0.f;
    #pragma unroll
    for (int k = 0; k < 5; k++) {
      float a = (float)(k - 2);
      g1v[k] = expf(-a * a / 4.5f);
      s += g1v[k];
    }
    #pragma unroll
    for (int k = 0; k < 5; k++) g1v[k] /= s;
    float cu = gu[ly + 2][lx + 2], cv = gv[ly + 2][lx + 2];
    float num0 = 0.f, num1 = 0.f, den = 0.f;
    #pragma unroll
    for (int dy = 0; dy < 5; dy++) {
      #pragma unroll
      for (int dx = 0; dx < 5; dx++) {
        float du = fabsf(gu[ly + dy][lx + dx] - cu) + fabsf(gv[ly + dy][lx + dx] - cv);
        float wgt = g1v[dy] * g1v[dx] * expf(-50.0f * du * du);
        num0 = fmaf(wgt, f0s[ly + dy][lx + dx], num0);
        num1 = fmaf(wgt, f1s[ly + dy][lx + dx], num1);
        den += wgt;
      }
    }
    o0 = num0 / den; o1 = num1 / den;
    float* ob = out + (size_t)b * 2 * NPIX;
    ob[y * IW + x] = o0;
    ob[NPIX + y * IW + x] = o1;
  }
  // block-level min/max reduce -> device atomics
  float mn0 = valid ? o0 : 1e30f,  mx0 = valid ? o0 : -1e30f;
  float mn1 = valid ? o1 : 1e30f,  mx1 = valid ? o1 : -1e30f;
  #pragma unroll
  for (int off = 32; off > 0; off >>= 1) {
    mn0 = fminf(mn0, __shfl_xor(mn0, off));
    mx0 = fmaxf(mx0, __shfl_xor(mx0, off));
    mn1 = fminf(mn1, __shfl_xor(mn1, off));
    mx1 = fmaxf(mx1, __shfl_xor(mx1, off));
  }
  if ((t & 63) == 0) {
    red[t >> 6][0] = mn0; red[t >> 6][1] = mx0;
    red[t >> 6][2] = mn1; red[t >> 6][3] = mx1;
  }
  __syncthreads();
  if (t == 0) {
    for (int w = 1; w < 4; w++) {
      red[0][0] = fminf(red[0][0], red[w][0]);
      red[0][1] = fmaxf(red[0][1], red[w][1]);
      red[0][2] = fminf(red[0][2], red[w][2]);
      red[0][3] = fmaxf(red[0][3], red[w][3]);
    }
    atomicMax(&mmbits[0], fkey(red[0][1]));   // max0
    atomicMax(&mmbits[1], fkey(red[0][3]));   // max1
    atomicMin(&mmbits[2], fkey(red[0][0]));   // min0
    atomicMin(&mmbits[3], fkey(red[0][2]));   // min1
  }
}

// ============================================================
// Final: rescale U/V from atomic min/max keys, YUV->RGB
// ============================================================
__global__ __launch_bounds__(256) void final_kernel(
    const float* __restrict__ bil, const float* __restrict__ x,
    const unsigned* __restrict__ mmbits, float* __restrict__ out) {
  int i = blockIdx.x * 256 + threadIdx.x;
  if (i >= NB * NPIX) return;
  float mx0 = funkey(mmbits[0]), mx1 = funkey(mmbits[1]);
  float mn0 = funkey(mmbits[2]), mn1 = funkey(mmbits[3]);
  int b = i / NPIX, p = i % NPIX;
  float f0 = bil[(size_t)b * 2 * NPIX + p];
  float f1 = bil[(size_t)b * 2 * NPIX + NPIX + p];
  float U = (f0 - mn0) / (mx0 - mn0 + 1e-6f);
  U = fminf(fmaxf(U, 0.f), 1.f) * 0.872f - 0.436f;
  float V = (f1 - mn1) / (mx1 - mn1 + 1e-6f);
  V = fminf(fmaxf(V, 0.f), 1.f) * 1.23f - 0.615f;
  float Y = x[(size_t)b * NPIX + p];
  float* ob = out + (size_t)b * 3 * NPIX;
  ob[p]            = Y + 1.14f * V;
  ob[NPIX + p]     = Y - 0.396f * U - 0.581f * V;
  ob[2 * NPIX + p] = Y + 2.029f * U;
}

// ============================================================
// launch
// ============================================================
extern "C" void kernel_launch(void* const* d_in, const int* in_sizes, int n_in,
                              void* d_out, int out_size, void* d_ws, size_t ws_size,
                              hipStream_t stream) {
  const float* x   = (const float*)d_in[0];
  const float* gt  = (const float*)d_in[1];
  const float* w1  = (const float*)d_in[2];
  const float* b1  = (const float*)d_in[3];
  const float* g1w = (const float*)d_in[4];
  const float* g1b = (const float*)d_in[5];
  const float* w2  = (const float*)d_in[6];
  const float* b2  = (const float*)d_in[7];
  const float* g2w = (const float*)d_in[8];
  const float* g2b = (const float*)d_in[9];
  const float* w3  = (const float*)d_in[10];
  const float* b3  = (const float*)d_in[11];
  const float* g3w = (const float*)d_in[12];
  const float* g3b = (const float*)d_in[13];
  const float* w4  = (const float*)d_in[14];
  const float* b4  = (const float*)d_in[15];
  const float* g4w = (const float*)d_in[16];
  const float* g4b = (const float*)d_in[17];
  const float* w5  = (const float*)d_in[18];
  const float* b5  = (const float*)d_in[19];
  float* out = (float*)d_out;

  // ---- workspace layout ----
  char* ws = (char*)d_ws;
  float* stats1 = (float*)ws;                  // 512
  float* stats2 = stats1 + 512;                // 256
  float* stats3 = stats2 + 256;                // 128
  float* stats4 = stats3 + 128;                // 64  (ends 960)
  unsigned* mmbits = (unsigned*)(ws + 12288);  // [max0,max1,min0,min1]
  float* fbase  = (float*)(ws + 16384);
  size_t off = 0;
  float* pooled = fbase + off; off += 4452864;   // NB*8*PH*PW
  float* s1g    = fbase + off; off += 1105920;   // NB*2*NPIX
  short* w1B    = (short*)(fbase + off); off += 102400;  // 204800 bf16
  short* w2B    = (short*)(fbase + off); off += 9216;
  short* w3B    = (short*)(fbase + off); off += 2304;
  float* w4T    = fbase + off; off += 1152;
  float* w5T    = fbase + off; off += 256;
  float* bufA   = fbase + off; off += 35389440;  // 64ch fp32 (also c3 out)
  float* bufB   = fbase + off; off += 17694720;  // 32ch fp32 (also c4 out)
  float* c5     = pooled;                        // alias: pooled dead by conv5
  float* bilat  = pooled + 1105920;              // alias

  hipMemsetAsync(ws, 0, 12304, stream);              // stats + max keys
  hipMemsetAsync(ws + 12296, 0xFF, 8, stream);       // min keys

  // ---- weight prep (single kernel) ----
  prep_kernel<<<896, 256, 0, stream>>>(w1, w2, w3, w4, w5, w1B, w2B, w3B, w4T, w5T);

  // ---- SIFT front-end ----
  pooled_kernel<<<dim3(33, 17, NB), 256, 0, stream>>>(x, pooled);
  sift_scalars_kernel<<<dim3(32, 17, NB), 256, 0, stream>>>(pooled, s1g);
  conv1_mfma_kernel<<<dim3(32, 17, NB), 256, 0, stream>>>(pooled, s1g, w1B, b1, bufA, stats1);

  // ---- conv2 (64->32, GN1 on input, stats2 fused) ----
  convk3_mfma_kernel<64, 32, 8, true><<<dim3(32, 34, NB), 256, 0, stream>>>(
      bufA, w2B, b2, stats1, g1w, g1b, stats2, bufB);

  // ---- conv3 (32->16, GN2 on input, stats3 fused) ----
  convk3_mfma_kernel<32, 16, 4, true><<<dim3(32, 34, NB), 256, 0, stream>>>(
      bufB, w3B, b3, stats2, g2w, g2b, stats3, bufA);

  // ---- conv4 (16->8, GN3 on input, stats4 fused) ----
  convs_kernel<16, 8, 4, true><<<dim3(32, 34, NB), 256, 0, stream>>>(
      bufA, w4T, b4, stats3, g3w, g3b, stats4, bufB);

  // ---- conv5 (8->2, GN4 on input) ----
  convs_kernel<8, 2, 2, false><<<dim3(32, 34, NB), 256, 0, stream>>>(
      bufB, w5T, b5, stats4, g4w, g4b, nullptr, c5);

  // ---- bilateral (guide + minmax fused) + composite ----
  bilateral_kernel<<<dim3(32, 17, NB), 256, 0, stream>>>(c5, gt, bilat, mmbits);
  final_kernel<<<(NB * NPIX + 255) / 256, 256, 0, stream>>>(bilat, x, mmbits, out);

  (void)in_sizes; (void)n_in; (void)out_size; (void)ws_size;
}

// Round 6
// 1309.632 us; speedup vs baseline: 10.9261x; 1.0805x over previous
//
#include <hip/hip_runtime.h>

// ---------------- problem constants ----------------
constexpr int NB  = 4;
constexpr int IH  = 270;
constexpr int IW  = 512;
constexpr int NPIX = IH * IW;      // 138240
constexpr int PH  = 271;           // pooled height
constexpr int PW  = 513;           // pooled width
constexpr float TWO_PI_F = 6.28318530717958647692f;

typedef short  bf16x8 __attribute__((ext_vector_type(8)));
typedef float floatx4 __attribute__((ext_vector_type(4)));

__device__ inline unsigned short f2bf(float x) {
  union { float f; unsigned u; } un; un.f = x;
  unsigned r = un.u + 0x7fff + ((un.u >> 16) & 1);   // RNE
  return (unsigned short)(r >> 16);
}
__device__ inline float bf2f(unsigned short u) {
  union { unsigned u; float f; } x; x.u = ((unsigned)u) << 16; return x.f;
}
// monotone float<->uint keys for atomic min/max
__device__ inline unsigned fkey(float f) {
  unsigned u = __float_as_uint(f);
  return (u & 0x80000000u) ? ~u : (u | 0x80000000u);
}
__device__ inline float funkey(unsigned k) {
  unsigned u = (k & 0x80000000u) ? (k ^ 0x80000000u) : ~k;
  return __uint_as_float(u);
}
// per-thread GN coef (thread c < C): A,B from fp32 stats
__device__ inline void gn_coef_thread(const float* __restrict__ stats,
                                      const float* __restrict__ gamma,
                                      const float* __restrict__ beta,
                                      float* cA, float* cB, int C, int chper, int b) {
  int c = threadIdx.x;
  if (c < C) {
    int g0 = (c / chper) * chper;
    float S = 0.f, S2 = 0.f;
    for (int k = 0; k < chper; k++) {
      S  += stats[(b * C + g0 + k) * 2];
      S2 += stats[(b * C + g0 + k) * 2 + 1];
    }
    double Nd = (double)chper * NPIX;
    double mu = (double)S / Nd;
    double var = (double)S2 / Nd - mu * mu;
    double rstd = 1.0 / sqrt(var + 1e-5);
    float A = (float)rstd * gamma[c];
    cA[c] = A;
    cB[c] = beta[c] - (float)mu * A;
  }
}

// ============================================================
// Combined weight prep: all MFMA B-packs + fp32 repacks, one kernel.
// ============================================================
__device__ inline void mfma_pack_one(const float* __restrict__ w, short* __restrict__ wB,
                                     int i, int CO, int CI, int KK, int CHUNKS) {
  int j = i & 7, l = (i >> 3) & 63, f = i >> 9;
  int t = f % KK; int fc = f / KK; int cc = fc % CHUNKS; int g = fc / CHUNKS;
  int ci = cc * 32 + ((l >> 4) << 3) + j;
  int co = g * 16 + (l & 15);
  float v = (ci < CI && co < CO) ? w[((size_t)co * CI + ci) * KK + t] : 0.f;
  wB[i] = (short)f2bf(v);
}
__device__ inline void repack_one(const float* __restrict__ w, float* __restrict__ wT,
                                  int i, int CO, int CI, int KK) {
  int o = i / (CI * KK);
  int r = i % (CI * KK);
  int ci = r / KK, kk = r % KK;
  wT[(kk * CI + ci) * CO + o] = w[i];
}
__global__ __launch_bounds__(256) void prep_kernel(
    const float* __restrict__ w1, const float* __restrict__ w2,
    const float* __restrict__ w3, const float* __restrict__ w4,
    const float* __restrict__ w5,
    short* __restrict__ w1B, short* __restrict__ w2B, short* __restrict__ w3B,
    float* __restrict__ w4T, float* __restrict__ w5T) {
  constexpr int N1 = 4 * 4 * 25 * 512;   // 204800
  constexpr int N2 = 2 * 2 * 9 * 512;    // 18432
  constexpr int N3 = 1 * 1 * 9 * 512;    // 4608
  constexpr int N4 = 8 * 16 * 9;         // 1152
  constexpr int N5 = 2 * 8 * 9;          // 144
  int i = blockIdx.x * 256 + threadIdx.x;
  if (i < N1) { mfma_pack_one(w1, w1B, i, 64, 128, 25, 4); return; }
  i -= N1;
  if (i < N2) { mfma_pack_one(w2, w2B, i, 32, 64, 9, 2); return; }
  i -= N2;
  if (i < N3) { mfma_pack_one(w3, w3B, i, 16, 32, 9, 1); return; }
  i -= N3;
  if (i < N4) { repack_one(w4, w4T, i, 8, 16, 9); return; }
  i -= N4;
  if (i < N5) { repack_one(w5, w5T, i, 2, 8, 9); return; }
}

// ============================================================
// Fused SIFT front-end: x -> (grad, ang, pooled, norms) -> full 128-ch
// bf16 descriptor written chunk-major: descg[b][cc][pixel][32ch].
// 16x16 pixel tile; grid (32,17,NB), block 256.
// ============================================================
__global__ __launch_bounds__(256) void sift_desc_kernel(
    const float* __restrict__ x, short* __restrict__ descg) {
  const int b = blockIdx.z;
  const int x0 = blockIdx.x * 16, y0 = blockIdx.y * 16;
  __shared__ float xs[24][25];
  __shared__ float wo0[22][23], wo1[22][23];
  __shared__ int   bo0[22][23];
  __shared__ float pooled[8][19][20];
  __shared__ float s1s[256], gs[256];
  const int tid = threadIdx.x;
  const float* xb = x + (size_t)b * NPIX;

  // A: x tile (edge-clamped), rows y0-4..y0+19, cols x0-4..x0+19
  for (int t = tid; t < 576; t += 256) {
    int r = t / 24, c = t % 24;
    int gy = min(max(y0 - 4 + r, 0), IH - 1);
    int gx = min(max(x0 - 4 + c, 0), IW - 1);
    xs[r][c] = xb[gy * IW + gx];
  }
  __syncthreads();

  // B: orientation bins (ang), rows y0-3..y0+18
  for (int t = tid; t < 484; t += 256) {
    int r = t / 22, c = t % 22;
    int gy = y0 - 3 + r, gx = x0 - 3 + c;
    float w0 = 0.f, w1v = 0.f; int b0 = 0;
    if (gy >= 0 && gy < IH && gx >= 0 && gx < IW) {
      float gxv = (xs[r + 1][c + 2] - xs[r + 1][c]) * 0.5f;
      float gyv = (xs[r + 2][c + 1] - xs[r][c + 1]) * 0.5f;
      float mag = sqrtf(gxv * gxv + gyv * gyv + 1e-10f);
      float ori = atan2f(gyv, gxv + 1e-10f) + TWO_PI_F;
      float obig = ori * (8.0f / TWO_PI_F);
      float bf = floorf(obig);
      float w1_ = obig - bf;
      w0  = (1.0f - w1_) * mag;
      w1v = w1_ * mag;
      b0  = ((int)bf) & 7;
    }
    wo0[r][c] = w0; wo1[r][c] = w1v; bo0[r][c] = b0;
  }
  __syncthreads();

  // C: pooled 19x19 x 8ch (rows y0-1..y0+17 of the PHxPW pooled map)
  const float pwt[4] = {0.25f, 0.75f, 0.75f, 0.25f};
  for (int t = tid; t < 361; t += 256) {
    int pr = t / 19, pc = t % 19;
    int py = y0 - 1 + pr, px = x0 - 1 + pc;
    float acc[8] = {0, 0, 0, 0, 0, 0, 0, 0};
    if (py >= 0 && py < PH && px >= 0 && px < PW) {
      #pragma unroll
      for (int i = 0; i < 4; i++) {
        #pragma unroll
        for (int j = 0; j < 4; j++) {
          float w0 = wo0[pr + i][pc + j], w1v = wo1[pr + i][pc + j];
          int b0 = bo0[pr + i][pc + j];
          int b1i = (b0 + 1) & 7;
          float pw = pwt[i] * pwt[j];
          #pragma unroll
          for (int a = 0; a < 8; a++) {
            float add = (a == b0 ? w0 : 0.f) + (a == b1i ? w1v : 0.f);
            acc[a] = fmaf(pw, add, acc[a]);
          }
        }
      }
    }
    #pragma unroll
    for (int a = 0; a < 8; a++) pooled[a][pr][pc] = acc[a];
  }
  __syncthreads();

  // D: per-pixel normalization scalars
  {
    int py = tid >> 4, px = tid & 15;
    int y = y0 + py;
    float s1 = 0.f, g = 0.f;
    if (y < IH) {
      float sum2 = 0.f;
      for (int c = 0; c < 128; c++) {
        int a = c >> 4, i = (c >> 2) & 3, j = c & 3;
        float p = pooled[a][py + i][px + j];
        sum2 = fmaf(p, p, sum2);
      }
      s1 = 1.0f / fmaxf(sqrtf(sum2), 1e-12f);
      float st2 = 0.f, st = 0.f;
      for (int c = 0; c < 128; c++) {
        int a = c >> 4, i = (c >> 2) & 3, j = c & 3;
        float p = pooled[a][py + i][px + j];
        float tv = fminf(p * s1, 0.2f);
        st2 = fmaf(tv, tv, st2);
        st += tv;
      }
      float s2 = 1.0f / fmaxf(sqrtf(st2), 1e-12f);
      float l1 = fmaxf(s2 * st, 1e-12f);
      g = s2 / l1;
    }
    s1s[tid] = s1; gs[tid] = g;
  }
  __syncthreads();

  // E: write descriptor, 4096 16B-units: unit = [cc][pix][sub]
  for (int k = 0; k < 16; k++) {
    int gidx = k * 256 + tid;
    int cc = gidx >> 10, pix = (gidx >> 2) & 255, sub = gidx & 3;
    int py = pix >> 4, px = pix & 15;
    int y = y0 + py;
    if (y >= IH) continue;
    float s1v = s1s[pix], gv = gs[pix];
    int a = cc * 2 + (sub >> 1);
    unsigned short v8[8];
    #pragma unroll
    for (int jj = 0; jj < 8; jj++) {
      int i = (sub * 2 + (jj >> 2)) & 3;
      int j = jj & 3;
      float p = pooled[a][py + i][px + j];
      v8[jj] = f2bf(sqrtf(fminf(p * s1v, 0.2f) * gv + 1e-10f));
    }
    uint4 pk;
    pk.x = (unsigned)v8[0] | ((unsigned)v8[1] << 16);
    pk.y = (unsigned)v8[2] | ((unsigned)v8[3] << 16);
    pk.z = (unsigned)v8[4] | ((unsigned)v8[5] << 16);
    pk.w = (unsigned)v8[6] | ((unsigned)v8[7] << 16);
    size_t base = ((size_t)(b * 4 + cc) * NPIX + (size_t)y * IW + (x0 + px)) * 32 + sub * 8;
    *(uint4*)(descg + base) = pk;
  }
}

// ============================================================
// Conv1 via MFMA, 16x16 tile, pure-GEMM staging from precomputed descg.
// Wave w: M-tiles (rows) 4w..4w+3, all 4 co-groups (A ds_read feeds 4 MFMAs).
// LDS 33.4KB -> 4 blocks/CU. Output bf16 + fused GN1 stats.
// grid (32,17,NB), block 256.
// ============================================================
__global__ __launch_bounds__(256, 2) void conv1_mfma_kernel(
    const short* __restrict__ descg, const short* __restrict__ w1B,
    const float* __restrict__ bias, unsigned short* __restrict__ out,
    float* __restrict__ stats) {
  const int b = blockIdx.z;
  const int x0 = blockIdx.x * 16, y0 = blockIdx.y * 16;
  __shared__ __align__(16) char smem_raw[33408];
  short* desc = (short*)smem_raw;                 // [400 pos][40] bf16
  float* cout = (float*)smem_raw;                 // epilogue [32][261]

  const int tid = threadIdx.x;
  const int wave = tid >> 6, lane = tid & 63;
  const int quad = lane >> 4, lm = lane & 15;

  floatx4 acc[4][4];   // [n-group][m-tile]
  #pragma unroll
  for (int n = 0; n < 4; n++)
    #pragma unroll
    for (int i = 0; i < 4; i++) acc[n][i] = (floatx4){0.f, 0.f, 0.f, 0.f};

  for (int cc = 0; cc < 4; cc++) {
    __syncthreads();   // previous chunk consumed
    const short* dg = descg + (size_t)(b * 4 + cc) * NPIX * 32;
    for (int u = tid; u < 1600; u += 256) {        // 400 pos x 4 16B-subs
      int pos = u >> 2, sub = u & 3;
      int r = pos / 20, c = pos % 20;
      int gy = y0 - 2 + r, gx = x0 - 2 + c;
      uint4 val = {0u, 0u, 0u, 0u};
      if (gy >= 0 && gy < IH && gx >= 0 && gx < IW)
        val = *(const uint4*)(dg + ((size_t)gy * IW + gx) * 32 + sub * 8);
      *(uint4*)(desc + pos * 40 + sub * 8) = val;
    }
    __syncthreads();   // desc ready

    #pragma unroll
    for (int ky = 0; ky < 5; ky++) {
      #pragma unroll
      for (int kx = 0; kx < 5; kx++) {
        bf16x8 bfr[4];
        #pragma unroll
        for (int n = 0; n < 4; n++) {
          int f = (n * 4 + cc) * 25 + ky * 5 + kx;
          bfr[n] = *(const bf16x8*)(w1B + ((size_t)f << 9) + (lane << 3));
        }
        bf16x8 av[4];
        #pragma unroll
        for (int i = 0; i < 4; i++) {
          int mt = wave * 4 + i;
          av[i] = *(const bf16x8*)(desc + ((mt + ky) * 20 + lm + kx) * 40 + quad * 8);
        }
        #pragma unroll
        for (int n = 0; n < 4; n++)
          #pragma unroll
          for (int i = 0; i < 4; i++)
            acc[n][i] = __builtin_amdgcn_mfma_f32_16x16x32_bf16(av[i], bfr[n], acc[n][i], 0, 0, 0);
      }
    }
  }

  // epilogue in two 32-co halves: transpose via LDS, bf16 store, GN stats
  unsigned short* ob = out + (size_t)b * 64 * NPIX;
  for (int h = 0; h < 2; h++) {
    __syncthreads();
    #pragma unroll
    for (int nn = 0; nn < 2; nn++)
      #pragma unroll
      for (int i = 0; i < 4; i++)
        #pragma unroll
        for (int r = 0; r < 4; r++)
          cout[(nn * 16 + lm) * 261 + (wave * 4 + i) * 16 + quad * 4 + r] = acc[h * 2 + nn][i][r];
    __syncthreads();
    for (int v = tid; v < 8192; v += 256) {
      int col = v >> 8, px = v & 255;
      int y = y0 + (px >> 4), x = x0 + (px & 15);
      if (y < IH)
        ob[(size_t)(h * 32 + col) * NPIX + y * IW + x] = f2bf(cout[col * 261 + px] + bias[h * 32 + col]);
    }
    // stats: 32 co x 8 segs (2 rows each)
    int col = tid >> 3, seg = tid & 7;
    int co = h * 32 + col;
    float bv = bias[co];
    float sum = 0.f, sq = 0.f;
    #pragma unroll
    for (int rr = 0; rr < 2; rr++) {
      int row = seg * 2 + rr;
      if (y0 + row < IH) {
        #pragma unroll
        for (int k = 0; k < 16; k++) {
          float vv = cout[col * 261 + row * 16 + k] + bv;
          sum += vv; sq += vv * vv;
        }
      }
    }
    sum += __shfl_down(sum, 4); sq += __shfl_down(sq, 4);
    sum += __shfl_down(sum, 2); sq += __shfl_down(sq, 2);
    sum += __shfl_down(sum, 1); sq += __shfl_down(sq, 1);
    if ((tid & 7) == 0) {
      atomicAdd(&stats[(b * 64 + co) * 2], sum);
      atomicAdd(&stats[(b * 64 + co) * 2 + 1], sq);
    }
  }
}

// ============================================================
// 3x3 conv via MFMA, 16x8 tile, bf16 in/out, fused input-GN + output stats.
// grid (32,34,NB).
// ============================================================
template <int CI, int CO, int CHPER, bool STATS>
__global__ __launch_bounds__(256) void convk3_mfma_kernel(
    const unsigned short* __restrict__ xin, const short* __restrict__ wB,
    const float* __restrict__ bias, const float* __restrict__ statsIn,
    const float* __restrict__ gamma, const float* __restrict__ beta,
    float* __restrict__ statsOut, unsigned short* __restrict__ out) {
  constexpr int CHUNKS = CI / 32;
  constexpr int G = CO / 16;           // co-groups (2 or 1)
  constexpr int MPW = 2 * G;           // m-tiles per wave (4 or 2)
  constexpr int CIS = CI + 8;          // LDS short-stride per position
  constexpr int TILE_B = 180 * CIS * 2;
  constexpr int COUT_B = CO * 133 * 4;
  constexpr int UNION_B = TILE_B > COUT_B ? TILE_B : COUT_B;
  __shared__ __align__(16) char sm[UNION_B + CI * 8];
  short* tile = (short*)sm;
  float* cout = (float*)sm;
  float* cA = (float*)(sm + UNION_B);
  float* cB = cA + CI;

  const int b = blockIdx.z;
  const int x0 = blockIdx.x * 16, y0 = blockIdx.y * 8;
  const int tid = threadIdx.x;
  const int wave = tid >> 6, lane = tid & 63;
  const int quad = lane >> 4, lm = lane & 15;
  const int n = wave % G, mh = wave / G;

  gn_coef_thread(statsIn, gamma, beta, cA, cB, CI, CHPER, b);
  __syncthreads();

  const unsigned short* xb = xin + (size_t)b * CI * NPIX;
  for (int v = tid; v < (CI / 2) * 180; v += 256) {
    int cp = v / 180, pos = v % 180;
    int r = pos / 18, c = pos % 18;
    int gy = y0 - 1 + r, gx = x0 - 1 + c;
    float v0 = 0.f, v1 = 0.f;
    if (gy >= 0 && gy < IH && gx >= 0 && gx < IW) {
      v0 = fmaxf(fmaf(bf2f(xb[(size_t)(2 * cp) * NPIX + gy * IW + gx]), cA[2 * cp], cB[2 * cp]), 0.f);
      v1 = fmaxf(fmaf(bf2f(xb[(size_t)(2 * cp + 1) * NPIX + gy * IW + gx]), cA[2 * cp + 1], cB[2 * cp + 1]), 0.f);
    }
    unsigned pk = (unsigned)f2bf(v0) | ((unsigned)f2bf(v1) << 16);
    *(unsigned*)(tile + pos * CIS + 2 * cp) = pk;
  }
  __syncthreads();

  floatx4 acc[MPW];
  #pragma unroll
  for (int i = 0; i < MPW; i++) acc[i] = (floatx4){0.f, 0.f, 0.f, 0.f};

  #pragma unroll
  for (int cc = 0; cc < CHUNKS; cc++) {
    #pragma unroll
    for (int ky = 0; ky < 3; ky++) {
      #pragma unroll
      for (int kx = 0; kx < 3; kx++) {
        int f = (n * CHUNKS + cc) * 9 + ky * 3 + kx;
        bf16x8 bfr = *(const bf16x8*)(wB + ((size_t)f << 9) + (lane << 3));
        #pragma unroll
        for (int i = 0; i < MPW; i++) {
          int mt = mh * MPW + i;
          bf16x8 av = *(const bf16x8*)(tile + ((mt + ky) * 18 + lm + kx) * CIS + cc * 32 + quad * 8);
          acc[i] = __builtin_amdgcn_mfma_f32_16x16x32_bf16(av, bfr, acc[i], 0, 0, 0);
        }
      }
    }
  }
  __syncthreads();   // tile consumed; cout overlays
  #pragma unroll
  for (int i = 0; i < MPW; i++) {
    #pragma unroll
    for (int r = 0; r < 4; r++) {
      int pixel = (mh * MPW + i) * 16 + quad * 4 + r;
      cout[(n * 16 + lm) * 133 + pixel] = acc[i][r];
    }
  }
  __syncthreads();
  unsigned short* ob = out + (size_t)b * CO * NPIX;
  for (int v = tid; v < CO * 128; v += 256) {
    int co = v >> 7, px = v & 127;
    int y = y0 + (px >> 4), x = x0 + (px & 15);
    if (y < IH) ob[(size_t)co * NPIX + y * IW + x] = f2bf(cout[co * 133 + px] + bias[co]);
  }
  if (STATS) {
    constexpr int TPC = 256 / CO;     // threads per channel (8 or 16)
    constexpr int PXT = 128 / TPC;    // pixels per thread
    int col = tid / TPC, seg = tid % TPC;
    float bv = bias[col];
    float sum = 0.f, sq = 0.f;
    #pragma unroll
    for (int k = 0; k < PXT; k++) {
      int p = seg * PXT + k;
      if (y0 + (p >> 4) < IH) {
        float vv = cout[col * 133 + p] + bv;
        sum += vv; sq += vv * vv;
      }
    }
    #pragma unroll
    for (int off = TPC / 2; off > 0; off >>= 1) {
      sum += __shfl_down(sum, off);
      sq  += __shfl_down(sq, off);
    }
    if (seg == 0) {
      atomicAdd(&statsOut[(b * CO + col) * 2], sum);
      atomicAdd(&statsOut[(b * CO + col) * 2 + 1], sq);
    }
  }
}

// ============================================================
// Small direct fp32 3x3 conv, 16x8 tile, bf16 input + fused GN, output
// bf16 (OUT_BF16) or fp32, optional output stats via LDS atomics.
// ============================================================
template <int CI, int CO, int CHPER, bool STATS, bool OUT_BF16>
__global__ __launch_bounds__(256) void convs_kernel(
    const unsigned short* __restrict__ xin, const float* __restrict__ wT,
    const float* __restrict__ bias, const float* __restrict__ statsIn,
    const float* __restrict__ gamma, const float* __restrict__ beta,
    float* __restrict__ statsOut, void* __restrict__ outv) {
  constexpr int OPT = CO / 2;
  const int b = blockIdx.z;
  const int x0 = blockIdx.x * 16, y0 = blockIdx.y * 8;
  __shared__ float tile[CI * 180];
  __shared__ float cA[CI], cB[CI];
  __shared__ float ssum[CO], ssq[CO];
  gn_coef_thread(statsIn, gamma, beta, cA, cB, CI, CHPER, b);
  if (STATS && threadIdx.x < CO) { ssum[threadIdx.x] = 0.f; ssq[threadIdx.x] = 0.f; }
  __syncthreads();
  const unsigned short* xb = xin + (size_t)b * CI * NPIX;
  for (int t = threadIdx.x; t < CI * 180; t += 256) {
    int ci = t / 180, rc = t % 180, r = rc / 18, c = rc % 18;
    int gy = y0 - 1 + r, gx = x0 - 1 + c;
    float v = 0.f;
    if (gy >= 0 && gy < IH && gx >= 0 && gx < IW)
      v = fmaxf(fmaf(bf2f(xb[(size_t)ci * NPIX + gy * IW + gx]), cA[ci], cB[ci]), 0.f);
    tile[t] = v;
  }
  __syncthreads();
  const int t = threadIdx.x;
  const int px = t & 127, og = t >> 7;
  const int pyy = px >> 4, pxx = px & 15;
  const int oc0 = og * OPT;
  const int y = y0 + pyy, x = x0 + pxx;
  float acc[OPT] = {};
  for (int ky = 0; ky < 3; ky++) {
    for (int kx = 0; kx < 3; kx++) {
      const float* wrow = wT + (size_t)((ky * 3 + kx) * CI) * CO + oc0;
      for (int ci = 0; ci < CI; ci++) {
        float v = tile[ci * 180 + (pyy + ky) * 18 + pxx + kx];
        #pragma unroll
        for (int o = 0; o < OPT; o++) acc[o] = fmaf(v, wrow[ci * CO + o], acc[o]);
      }
    }
  }
  if (y < IH) {
    #pragma unroll
    for (int o = 0; o < OPT; o++) {
      float vv = acc[o] + bias[oc0 + o];
      if (OUT_BF16) {
        unsigned short* ob = (unsigned short*)outv + (size_t)b * CO * NPIX;
        ob[(size_t)(oc0 + o) * NPIX + y * IW + x] = f2bf(vv);
      } else {
        float* ob = (float*)outv + (size_t)b * CO * NPIX;
        ob[(size_t)(oc0 + o) * NPIX + y * IW + x] = vv;
      }
      if (STATS) {
        atomicAdd(&ssum[oc0 + o], vv);
        atomicAdd(&ssq[oc0 + o], vv * vv);
      }
    }
  }
  if (STATS) {
    __syncthreads();
    if (threadIdx.x < CO) {
      atomicAdd(&statsOut[(b * CO + threadIdx.x) * 2], ssum[threadIdx.x]);
      atomicAdd(&statsOut[(b * CO + threadIdx.x) * 2 + 1], ssq[threadIdx.x]);
    }
  }
}

// ============================================================
// Joint bilateral 5x5 (reflect), guide fused, global min/max fused.
// ============================================================
__global__ __launch_bounds__(256) void bilateral_kernel(
    const float* __restrict__ f, const float* __restrict__ gt,
    float* __restrict__ out, unsigned* __restrict__ mmbits) {
  const int b = blockIdx.z;
  const int x0 = blockIdx.x * 16, y0 = blockIdx.y * 16;
  __shared__ float gu[20][20], gv[20][20], f0s[20][20], f1s[20][20];
  __shared__ float red[4][4];
  const float* gtb = gt + (size_t)b * 3 * NPIX;
  const float* fb = f + (size_t)b * 2 * NPIX;
  for (int t = threadIdx.x; t < 400; t += 256) {
    int r = t / 20, c = t % 20;
    int gy = y0 - 2 + r, gx = x0 - 2 + c;
    if (gy < 0) gy = -gy;
    if (gy > IH - 1) gy = 2 * (IH - 1) - gy;
    if (gx < 0) gx = -gx;
    if (gx > IW - 1) gx = 2 * (IW - 1) - gx;
    int p = gy * IW + gx;
    float rr = gtb[p], gg = gtb[NPIX + p], bb = gtb[2 * NPIX + p];
    gu[r][c]  = -0.147f * rr - 0.289f * gg + 0.436f * bb;
    gv[r][c]  =  0.615f * rr - 0.515f * gg - 0.100f * bb;
    f0s[r][c] = fb[p];
    f1s[r][c] = fb[NPIX + p];
  }
  __syncthreads();
  const int t = threadIdx.x;
  const int lx = t % 16, ly = t / 16;
  const int y = y0 + ly, x = x0 + lx;
  const bool valid = (y < IH);

  float o0 = 0.f, o1 = 0.f;
  if (valid) {
    float g1v[5];
    float s = 0.f;
    #pragma unroll
    for (int k = 0; k < 5; k++) {
      float a = (float)(k - 2);
      g1v[k] = expf(-a * a / 4.5f);
      s += g1v[k];
    }
    #pragma unroll
    for (int k = 0; k < 5; k++) g1v[k] /= s;
    float cu = gu[ly + 2][lx + 2], cv = gv[ly + 2][lx + 2];
    float num0 = 0.f, num1 = 0.f, den = 0.f;
    #pragma unroll
    for (int dy = 0; dy < 5; dy++) {
      #pragma unroll
      for (int dx = 0; dx < 5; dx++) {
        float du = fabsf(gu[ly + dy][lx + dx] - cu) + fabsf(gv[ly + dy][lx + dx] - cv);
        float wgt = g1v[dy] * g1v[dx] * expf(-50.0f * du * du);
        num0 = fmaf(wgt, f0s[ly + dy][lx + dx], num0);
        num1 = fmaf(wgt, f1s[ly + dy][lx + dx], num1);
        den += wgt;
      }
    }
    o0 = num0 / den; o1 = num1 / den;
    float* ob = out + (size_t)b * 2 * NPIX;
    ob[y * IW + x] = o0;
    ob[NPIX + y * IW + x] = o1;
  }
  float mn0 = valid ? o0 : 1e30f,  mx0 = valid ? o0 : -1e30f;
  float mn1 = valid ? o1 : 1e30f,  mx1 = valid ? o1 : -1e30f;
  #pragma unroll
  for (int off = 32; off > 0; off >>= 1) {
    mn0 = fminf(mn0, __shfl_xor(mn0, off));
    mx0 = fmaxf(mx0, __shfl_xor(mx0, off));
    mn1 = fminf(mn1, __shfl_xor(mn1, off));
    mx1 = fmaxf(mx1, __shfl_xor(mx1, off));
  }
  if ((t & 63) == 0) {
    red[t >> 6][0] = mn0; red[t >> 6][1] = mx0;
    red[t >> 6][2] = mn1; red[t >> 6][3] = mx1;
  }
  __syncthreads();
  if (t == 0) {
    for (int w = 1; w < 4; w++) {
      red[0][0] = fminf(red[0][0], red[w][0]);
      red[0][1] = fmaxf(red[0][1], red[w][1]);
      red[0][2] = fminf(red[0][2], red[w][2]);
      red[0][3] = fmaxf(red[0][3], red[w][3]);
    }
    atomicMax(&mmbits[0], fkey(red[0][1]));   // max0
    atomicMax(&mmbits[1], fkey(red[0][3]));   // max1
    atomicMin(&mmbits[2], fkey(red[0][0]));   // min0
    atomicMin(&mmbits[3], fkey(red[0][2]));   // min1
  }
}

// ============================================================
// Final: rescale U/V from atomic min/max keys, YUV->RGB
// ============================================================
__global__ __launch_bounds__(256) void final_kernel(
    const float* __restrict__ bil, const float* __restrict__ x,
    const unsigned* __restrict__ mmbits, float* __restrict__ out) {
  int i = blockIdx.x * 256 + threadIdx.x;
  if (i >= NB * NPIX) return;
  float mx0 = funkey(mmbits[0]), mx1 = funkey(mmbits[1]);
  float mn0 = funkey(mmbits[2]), mn1 = funkey(mmbits[3]);
  int b = i / NPIX, p = i % NPIX;
  float f0 = bil[(size_t)b * 2 * NPIX + p];
  float f1 = bil[(size_t)b * 2 * NPIX + NPIX + p];
  float U = (f0 - mn0) / (mx0 - mn0 + 1e-6f);
  U = fminf(fmaxf(U, 0.f), 1.f) * 0.872f - 0.436f;
  float V = (f1 - mn1) / (mx1 - mn1 + 1e-6f);
  V = fminf(fmaxf(V, 0.f), 1.f) * 1.23f - 0.615f;
  float Y = x[(size_t)b * NPIX + p];
  float* ob = out + (size_t)b * 3 * NPIX;
  ob[p]            = Y + 1.14f * V;
  ob[NPIX + p]     = Y - 0.396f * U - 0.581f * V;
  ob[2 * NPIX + p] = Y + 2.029f * U;
}

// ============================================================
// launch
// ============================================================
extern "C" void kernel_launch(void* const* d_in, const int* in_sizes, int n_in,
                              void* d_out, int out_size, void* d_ws, size_t ws_size,
                              hipStream_t stream) {
  const float* x   = (const float*)d_in[0];
  const float* gt  = (const float*)d_in[1];
  const float* w1  = (const float*)d_in[2];
  const float* b1  = (const float*)d_in[3];
  const float* g1w = (const float*)d_in[4];
  const float* g1b = (const float*)d_in[5];
  const float* w2  = (const float*)d_in[6];
  const float* b2  = (const float*)d_in[7];
  const float* g2w = (const float*)d_in[8];
  const float* g2b = (const float*)d_in[9];
  const float* w3  = (const float*)d_in[10];
  const float* b3  = (const float*)d_in[11];
  const float* g3w = (const float*)d_in[12];
  const float* g3b = (const float*)d_in[13];
  const float* w4  = (const float*)d_in[14];
  const float* b4  = (const float*)d_in[15];
  const float* g4w = (const float*)d_in[16];
  const float* g4b = (const float*)d_in[17];
  const float* w5  = (const float*)d_in[18];
  const float* b5  = (const float*)d_in[19];
  float* out = (float*)d_out;

  // ---- workspace layout ----
  char* ws = (char*)d_ws;
  float* stats1 = (float*)ws;                  // 512
  float* stats2 = stats1 + 512;                // 256
  float* stats3 = stats2 + 256;                // 128
  float* stats4 = stats3 + 128;                // 64  (ends 960)
  unsigned* mmbits = (unsigned*)(ws + 12288);  // [max0,max1,min0,min1]
  char* base = ws + 16384;
  // descg region: NB*4*NPIX*32 shorts = 141.6 MB
  short* descg = (short*)base;
  size_t descg_shorts = (size_t)NB * 4 * NPIX * 32;       // 70,778,880
  // aliases inside descg region (descg dead after conv1):
  unsigned short* bufB_h = (unsigned short*)base;         // conv2 out 32ch / conv4 out 8ch
  float* c5    = (float*)(base + 36000000);               // conv5 out (2ch fp32)
  float* bilat = (float*)(base + 41000000);               // bilateral out
  short* w1B = descg + descg_shorts;                      // 204800 shorts
  short* w2B = w1B + 204800;                              // 18432
  short* w3B = w2B + 18432;                               // 4608
  float* w4T = (float*)(w3B + 4608);                      // 1152 floats
  float* w5T = w4T + 1152;                                // 144 floats
  unsigned short* bufA_h = (unsigned short*)(w5T + 144);  // conv1 out 64ch / conv3 out 16ch

  hipMemsetAsync(ws, 0, 12304, stream);              // stats + max keys
  hipMemsetAsync(ws + 12296, 0xFF, 8, stream);       // min keys

  // ---- weight prep (single kernel) ----
  prep_kernel<<<896, 256, 0, stream>>>(w1, w2, w3, w4, w5, w1B, w2B, w3B, w4T, w5T);

  // ---- fused SIFT front-end -> bf16 descriptor ----
  sift_desc_kernel<<<dim3(32, 17, NB), 256, 0, stream>>>(x, descg);

  // ---- conv1 (128->64 MFMA GEMM over descg, bf16 out, stats1 fused) ----
  conv1_mfma_kernel<<<dim3(32, 17, NB), 256, 0, stream>>>(descg, w1B, b1, bufA_h, stats1);

  // ---- conv2 (64->32, GN1 on input, stats2 fused) ----
  convk3_mfma_kernel<64, 32, 8, true><<<dim3(32, 34, NB), 256, 0, stream>>>(
      bufA_h, w2B, b2, stats1, g1w, g1b, stats2, bufB_h);

  // ---- conv3 (32->16, GN2 on input, stats3 fused) ----
  convk3_mfma_kernel<32, 16, 4, true><<<dim3(32, 34, NB), 256, 0, stream>>>(
      bufB_h, w3B, b3, stats2, g2w, g2b, stats3, bufA_h);

  // ---- conv4 (16->8, GN3 on input, stats4 fused, bf16 out) ----
  convs_kernel<16, 8, 4, true, true><<<dim3(32, 34, NB), 256, 0, stream>>>(
      bufA_h, w4T, b4, stats3, g3w, g3b, stats4, bufB_h);

  // ---- conv5 (8->2, GN4 on input, fp32 out) ----
  convs_kernel<8, 2, 2, false, false><<<dim3(32, 34, NB), 256, 0, stream>>>(
      bufB_h, w5T, b5, stats4, g4w, g4b, nullptr, c5);

  // ---- bilateral (guide + minmax fused) + composite ----
  bilateral_kernel<<<dim3(32, 17, NB), 256, 0, stream>>>(c5, gt, bilat, mmbits);
  final_kernel<<<(NB * NPIX + 255) / 256, 256, 0, stream>>>(bilat, x, mmbits, out);

  (void)in_sizes; (void)n_in; (void)out_size; (void)ws_size;
}

// Round 7
// 1264.687 us; speedup vs baseline: 11.3143x; 1.0355x over previous
//
#include <hip/hip_runtime.h>

// ---------------- problem constants ----------------
constexpr int NB  = 4;
constexpr int IH  = 270;
constexpr int IW  = 512;
constexpr int NPIX = IH * IW;      // 138240
constexpr int PH  = 271;           // pooled height
constexpr int PW  = 513;           // pooled width
constexpr float TWO_PI_F = 6.28318530717958647692f;

typedef short  bf16x8 __attribute__((ext_vector_type(8)));
typedef float floatx4 __attribute__((ext_vector_type(4)));

__device__ inline unsigned short f2bf(float x) {
  union { float f; unsigned u; } un; un.f = x;
  unsigned r = un.u + 0x7fff + ((un.u >> 16) & 1);   // RNE
  return (unsigned short)(r >> 16);
}
__device__ inline float bf2f(unsigned short u) {
  union { unsigned u; float f; } x; x.u = ((unsigned)u) << 16; return x.f;
}
// monotone float<->uint keys for atomic min/max
__device__ inline unsigned fkey(float f) {
  unsigned u = __float_as_uint(f);
  return (u & 0x80000000u) ? ~u : (u | 0x80000000u);
}
__device__ inline float funkey(unsigned k) {
  unsigned u = (k & 0x80000000u) ? (k ^ 0x80000000u) : ~k;
  return __uint_as_float(u);
}
// per-thread GN coef (thread c < C): A,B from fp32 stats
__device__ inline void gn_coef_thread(const float* __restrict__ stats,
                                      const float* __restrict__ gamma,
                                      const float* __restrict__ beta,
                                      float* cA, float* cB, int C, int chper, int b) {
  int c = threadIdx.x;
  if (c < C) {
    int g0 = (c / chper) * chper;
    float S = 0.f, S2 = 0.f;
    for (int k = 0; k < chper; k++) {
      S  += stats[(b * C + g0 + k) * 2];
      S2 += stats[(b * C + g0 + k) * 2 + 1];
    }
    double Nd = (double)chper * NPIX;
    double mu = (double)S / Nd;
    double var = (double)S2 / Nd - mu * mu;
    double rstd = 1.0 / sqrt(var + 1e-5);
    float A = (float)rstd * gamma[c];
    cA[c] = A;
    cB[c] = beta[c] - (float)mu * A;
  }
}

// ============================================================
// Combined weight prep: all MFMA B-packs + fp32 repacks, one kernel.
// ============================================================
__device__ inline void mfma_pack_one(const float* __restrict__ w, short* __restrict__ wB,
                                     int i, int CO, int CI, int KK, int CHUNKS) {
  int j = i & 7, l = (i >> 3) & 63, f = i >> 9;
  int t = f % KK; int fc = f / KK; int cc = fc % CHUNKS; int g = fc / CHUNKS;
  int ci = cc * 32 + ((l >> 4) << 3) + j;
  int co = g * 16 + (l & 15);
  float v = (ci < CI && co < CO) ? w[((size_t)co * CI + ci) * KK + t] : 0.f;
  wB[i] = (short)f2bf(v);
}
__device__ inline void repack_one(const float* __restrict__ w, float* __restrict__ wT,
                                  int i, int CO, int CI, int KK) {
  int o = i / (CI * KK);
  int r = i % (CI * KK);
  int ci = r / KK, kk = r % KK;
  wT[(kk * CI + ci) * CO + o] = w[i];
}
__global__ __launch_bounds__(256) void prep_kernel(
    const float* __restrict__ w1, const float* __restrict__ w2,
    const float* __restrict__ w3, const float* __restrict__ w4,
    const float* __restrict__ w5,
    short* __restrict__ w1B, short* __restrict__ w2B, short* __restrict__ w3B,
    float* __restrict__ w4T, float* __restrict__ w5T) {
  constexpr int N1 = 4 * 4 * 25 * 512;   // 204800
  constexpr int N2 = 2 * 2 * 9 * 512;    // 18432
  constexpr int N3 = 1 * 1 * 9 * 512;    // 4608
  constexpr int N4 = 8 * 16 * 9;         // 1152
  constexpr int N5 = 2 * 8 * 9;          // 144
  int i = blockIdx.x * 256 + threadIdx.x;
  if (i < N1) { mfma_pack_one(w1, w1B, i, 64, 128, 25, 4); return; }
  i -= N1;
  if (i < N2) { mfma_pack_one(w2, w2B, i, 32, 64, 9, 2); return; }
  i -= N2;
  if (i < N3) { mfma_pack_one(w3, w3B, i, 16, 32, 9, 1); return; }
  i -= N3;
  if (i < N4) { repack_one(w4, w4T, i, 8, 16, 9); return; }
  i -= N4;
  if (i < N5) { repack_one(w5, w5T, i, 2, 8, 9); return; }
}

// ============================================================
// Fused SIFT front-end: x -> full 128-ch bf16 descriptor, chunk-major
// descg[b][cc][pixel][32ch]. 16x16 tile; grid (32,17,NB), block 256.
// ============================================================
__global__ __launch_bounds__(256) void sift_desc_kernel(
    const float* __restrict__ x, short* __restrict__ descg) {
  const int b = blockIdx.z;
  const int x0 = blockIdx.x * 16, y0 = blockIdx.y * 16;
  __shared__ float xs[24][25];
  __shared__ float wo0[22][23], wo1[22][23];
  __shared__ int   bo0[22][23];
  __shared__ float pooled[8][19][20];
  __shared__ float s1s[256], gs[256];
  const int tid = threadIdx.x;
  const float* xb = x + (size_t)b * NPIX;

  for (int t = tid; t < 576; t += 256) {
    int r = t / 24, c = t % 24;
    int gy = min(max(y0 - 4 + r, 0), IH - 1);
    int gx = min(max(x0 - 4 + c, 0), IW - 1);
    xs[r][c] = xb[gy * IW + gx];
  }
  __syncthreads();

  for (int t = tid; t < 484; t += 256) {
    int r = t / 22, c = t % 22;
    int gy = y0 - 3 + r, gx = x0 - 3 + c;
    float w0 = 0.f, w1v = 0.f; int b0 = 0;
    if (gy >= 0 && gy < IH && gx >= 0 && gx < IW) {
      float gxv = (xs[r + 1][c + 2] - xs[r + 1][c]) * 0.5f;
      float gyv = (xs[r + 2][c + 1] - xs[r][c + 1]) * 0.5f;
      float mag = sqrtf(gxv * gxv + gyv * gyv + 1e-10f);
      float ori = atan2f(gyv, gxv + 1e-10f) + TWO_PI_F;
      float obig = ori * (8.0f / TWO_PI_F);
      float bf = floorf(obig);
      float w1_ = obig - bf;
      w0  = (1.0f - w1_) * mag;
      w1v = w1_ * mag;
      b0  = ((int)bf) & 7;
    }
    wo0[r][c] = w0; wo1[r][c] = w1v; bo0[r][c] = b0;
  }
  __syncthreads();

  const float pwt[4] = {0.25f, 0.75f, 0.75f, 0.25f};
  for (int t = tid; t < 361; t += 256) {
    int pr = t / 19, pc = t % 19;
    int py = y0 - 1 + pr, px = x0 - 1 + pc;
    float acc[8] = {0, 0, 0, 0, 0, 0, 0, 0};
    if (py >= 0 && py < PH && px >= 0 && px < PW) {
      #pragma unroll
      for (int i = 0; i < 4; i++) {
        #pragma unroll
        for (int j = 0; j < 4; j++) {
          float w0 = wo0[pr + i][pc + j], w1v = wo1[pr + i][pc + j];
          int b0 = bo0[pr + i][pc + j];
          int b1i = (b0 + 1) & 7;
          float pw = pwt[i] * pwt[j];
          #pragma unroll
          for (int a = 0; a < 8; a++) {
            float add = (a == b0 ? w0 : 0.f) + (a == b1i ? w1v : 0.f);
            acc[a] = fmaf(pw, add, acc[a]);
          }
        }
      }
    }
    #pragma unroll
    for (int a = 0; a < 8; a++) pooled[a][pr][pc] = acc[a];
  }
  __syncthreads();

  {
    int py = tid >> 4, px = tid & 15;
    int y = y0 + py;
    float s1 = 0.f, g = 0.f;
    if (y < IH) {
      float sum2 = 0.f;
      for (int c = 0; c < 128; c++) {
        int a = c >> 4, i = (c >> 2) & 3, j = c & 3;
        float p = pooled[a][py + i][px + j];
        sum2 = fmaf(p, p, sum2);
      }
      s1 = 1.0f / fmaxf(sqrtf(sum2), 1e-12f);
      float st2 = 0.f, st = 0.f;
      for (int c = 0; c < 128; c++) {
        int a = c >> 4, i = (c >> 2) & 3, j = c & 3;
        float p = pooled[a][py + i][px + j];
        float tv = fminf(p * s1, 0.2f);
        st2 = fmaf(tv, tv, st2);
        st += tv;
      }
      float s2 = 1.0f / fmaxf(sqrtf(st2), 1e-12f);
      float l1 = fmaxf(s2 * st, 1e-12f);
      g = s2 / l1;
    }
    s1s[tid] = s1; gs[tid] = g;
  }
  __syncthreads();

  for (int k = 0; k < 16; k++) {
    int gidx = k * 256 + tid;
    int cc = gidx >> 10, pix = (gidx >> 2) & 255, sub = gidx & 3;
    int py = pix >> 4, px = pix & 15;
    int y = y0 + py;
    if (y >= IH) continue;
    float s1v = s1s[pix], gv = gs[pix];
    int a = cc * 2 + (sub >> 1);
    unsigned short v8[8];
    #pragma unroll
    for (int jj = 0; jj < 8; jj++) {
      int i = (sub * 2 + (jj >> 2)) & 3;
      int j = jj & 3;
      float p = pooled[a][py + i][px + j];
      v8[jj] = f2bf(sqrtf(fminf(p * s1v, 0.2f) * gv + 1e-10f));
    }
    uint4 pk;
    pk.x = (unsigned)v8[0] | ((unsigned)v8[1] << 16);
    pk.y = (unsigned)v8[2] | ((unsigned)v8[3] << 16);
    pk.z = (unsigned)v8[4] | ((unsigned)v8[5] << 16);
    pk.w = (unsigned)v8[6] | ((unsigned)v8[7] << 16);
    size_t base = ((size_t)(b * 4 + cc) * NPIX + (size_t)y * IW + (x0 + px)) * 32 + sub * 8;
    *(uint4*)(descg + base) = pk;
  }
}

// ============================================================
// Conv1 via MFMA, 16x16 tile, GEMM over descg with EXPLICIT one-tap-ahead
// software pipelining of B (global/L2) and A (LDS) fragments: the 16 MFMAs
// of tap t cover the load latency of tap t+1. grid (32,17,NB), block 256.
// ============================================================
__global__ __launch_bounds__(256, 2) void conv1_mfma_kernel(
    const short* __restrict__ descg, const short* __restrict__ w1B,
    const float* __restrict__ bias, unsigned short* __restrict__ out,
    float* __restrict__ stats) {
  const int b = blockIdx.z;
  const int x0 = blockIdx.x * 16, y0 = blockIdx.y * 16;
  __shared__ __align__(16) char smem_raw[33408];
  short* desc = (short*)smem_raw;                 // [400 pos][40] bf16
  float* cout = (float*)smem_raw;                 // epilogue [32][261]

  const int tid = threadIdx.x;
  const int wave = tid >> 6, lane = tid & 63;
  const int quad = lane >> 4, lm = lane & 15;

  floatx4 acc[4][4];   // [n-group][m-tile]
  #pragma unroll
  for (int n = 0; n < 4; n++)
    #pragma unroll
    for (int i = 0; i < 4; i++) acc[n][i] = (floatx4){0.f, 0.f, 0.f, 0.f};

  for (int cc = 0; cc < 4; cc++) {
    __syncthreads();   // previous chunk consumed
    const short* dg = descg + (size_t)(b * 4 + cc) * NPIX * 32;
    for (int u = tid; u < 1600; u += 256) {        // 400 pos x 4 16B-subs
      int pos = u >> 2, sub = u & 3;
      int r = pos / 20, c = pos % 20;
      int gy = y0 - 2 + r, gx = x0 - 2 + c;
      uint4 val = {0u, 0u, 0u, 0u};
      if (gy >= 0 && gy < IH && gx >= 0 && gx < IW)
        val = *(const uint4*)(dg + ((size_t)gy * IW + gx) * 32 + sub * 8);
      *(uint4*)(desc + pos * 40 + sub * 8) = val;
    }
    __syncthreads();   // desc ready

    const short* wb = w1B + (size_t)cc * 25 * 512 + (lane << 3);
    bf16x8 bfrC[4], avC[4], bfrN[4], avN[4];
    #pragma unroll
    for (int n = 0; n < 4; n++)
      bfrN[n] = *(const bf16x8*)(wb + (size_t)n * 4 * 25 * 512);
    #pragma unroll
    for (int i = 0; i < 4; i++)
      avN[i] = *(const bf16x8*)(desc + ((wave * 4 + i) * 20 + lm) * 40 + quad * 8);
    #pragma unroll
    for (int t = 0; t < 25; t++) {
      #pragma unroll
      for (int n = 0; n < 4; n++) bfrC[n] = bfrN[n];
      #pragma unroll
      for (int i = 0; i < 4; i++) avC[i] = avN[i];
      if (t < 24) {
        int t1 = t + 1, ky1 = t1 / 5, kx1 = t1 % 5;
        #pragma unroll
        for (int n = 0; n < 4; n++)
          bfrN[n] = *(const bf16x8*)(wb + ((size_t)n * 4 * 25 + t1) * 512);
        #pragma unroll
        for (int i = 0; i < 4; i++)
          avN[i] = *(const bf16x8*)(desc + ((wave * 4 + i + ky1) * 20 + lm + kx1) * 40 + quad * 8);
      }
      #pragma unroll
      for (int n = 0; n < 4; n++)
        #pragma unroll
        for (int i = 0; i < 4; i++)
          acc[n][i] = __builtin_amdgcn_mfma_f32_16x16x32_bf16(avC[i], bfrC[n], acc[n][i], 0, 0, 0);
    }
  }

  // epilogue in two 32-co halves: transpose via LDS, bf16 store, GN stats
  unsigned short* ob = out + (size_t)b * 64 * NPIX;
  for (int h = 0; h < 2; h++) {
    __syncthreads();
    #pragma unroll
    for (int nn = 0; nn < 2; nn++)
      #pragma unroll
      for (int i = 0; i < 4; i++)
        #pragma unroll
        for (int r = 0; r < 4; r++)
          cout[(nn * 16 + lm) * 261 + (wave * 4 + i) * 16 + quad * 4 + r] = acc[h * 2 + nn][i][r];
    __syncthreads();
    for (int v = tid; v < 8192; v += 256) {
      int col = v >> 8, px = v & 255;
      int y = y0 + (px >> 4), x = x0 + (px & 15);
      if (y < IH)
        ob[(size_t)(h * 32 + col) * NPIX + y * IW + x] = f2bf(cout[col * 261 + px] + bias[h * 32 + col]);
    }
    int col = tid >> 3, seg = tid & 7;
    int co = h * 32 + col;
    float bv = bias[co];
    float sum = 0.f, sq = 0.f;
    #pragma unroll
    for (int rr = 0; rr < 2; rr++) {
      int row = seg * 2 + rr;
      if (y0 + row < IH) {
        #pragma unroll
        for (int k = 0; k < 16; k++) {
          float vv = cout[col * 261 + row * 16 + k] + bv;
          sum += vv; sq += vv * vv;
        }
      }
    }
    sum += __shfl_down(sum, 4); sq += __shfl_down(sq, 4);
    sum += __shfl_down(sum, 2); sq += __shfl_down(sq, 2);
    sum += __shfl_down(sum, 1); sq += __shfl_down(sq, 1);
    if ((tid & 7) == 0) {
      atomicAdd(&stats[(b * 64 + co) * 2], sum);
      atomicAdd(&stats[(b * 64 + co) * 2 + 1], sq);
    }
  }
}

// ============================================================
// 3x3 conv via MFMA, 16x8 tile, bf16 in/out, fused input-GN + output
// stats, one-tap-ahead software pipelining. grid (32,34,NB).
// ============================================================
template <int CI, int CO, int CHPER, bool STATS>
__global__ __launch_bounds__(256) void convk3_mfma_kernel(
    const unsigned short* __restrict__ xin, const short* __restrict__ wB,
    const float* __restrict__ bias, const float* __restrict__ statsIn,
    const float* __restrict__ gamma, const float* __restrict__ beta,
    float* __restrict__ statsOut, unsigned short* __restrict__ out) {
  constexpr int CHUNKS = CI / 32;
  constexpr int G = CO / 16;           // co-groups (2 or 1)
  constexpr int MPW = 2 * G;           // m-tiles per wave (4 or 2)
  constexpr int CIS = CI + 8;          // LDS short-stride per position
  constexpr int TILE_B = 180 * CIS * 2;
  constexpr int COUT_B = CO * 133 * 4;
  constexpr int UNION_B = TILE_B > COUT_B ? TILE_B : COUT_B;
  __shared__ __align__(16) char sm[UNION_B + CI * 8];
  short* tile = (short*)sm;
  float* cout = (float*)sm;
  float* cA = (float*)(sm + UNION_B);
  float* cB = cA + CI;

  const int b = blockIdx.z;
  const int x0 = blockIdx.x * 16, y0 = blockIdx.y * 8;
  const int tid = threadIdx.x;
  const int wave = tid >> 6, lane = tid & 63;
  const int quad = lane >> 4, lm = lane & 15;
  const int n = wave % G, mh = wave / G;

  gn_coef_thread(statsIn, gamma, beta, cA, cB, CI, CHPER, b);
  __syncthreads();

  const unsigned short* xb = xin + (size_t)b * CI * NPIX;
  for (int v = tid; v < (CI / 2) * 180; v += 256) {
    int cp = v / 180, pos = v % 180;
    int r = pos / 18, c = pos % 18;
    int gy = y0 - 1 + r, gx = x0 - 1 + c;
    float v0 = 0.f, v1 = 0.f;
    if (gy >= 0 && gy < IH && gx >= 0 && gx < IW) {
      v0 = fmaxf(fmaf(bf2f(xb[(size_t)(2 * cp) * NPIX + gy * IW + gx]), cA[2 * cp], cB[2 * cp]), 0.f);
      v1 = fmaxf(fmaf(bf2f(xb[(size_t)(2 * cp + 1) * NPIX + gy * IW + gx]), cA[2 * cp + 1], cB[2 * cp + 1]), 0.f);
    }
    unsigned pk = (unsigned)f2bf(v0) | ((unsigned)f2bf(v1) << 16);
    *(unsigned*)(tile + pos * CIS + 2 * cp) = pk;
  }
  __syncthreads();

  floatx4 acc[MPW];
  #pragma unroll
  for (int i = 0; i < MPW; i++) acc[i] = (floatx4){0.f, 0.f, 0.f, 0.f};

  constexpr int NT = CHUNKS * 9;
  const short* wbase = wB + ((size_t)n * NT) * 512 + (lane << 3);
  bf16x8 bfrC, avC[MPW], bfrN, avN[MPW];
  bfrN = *(const bf16x8*)(wbase);
  #pragma unroll
  for (int i = 0; i < MPW; i++)
    avN[i] = *(const bf16x8*)(tile + ((mh * MPW + i) * 18 + lm) * CIS + quad * 8);
  #pragma unroll
  for (int t = 0; t < NT; t++) {
    bfrC = bfrN;
    #pragma unroll
    for (int i = 0; i < MPW; i++) avC[i] = avN[i];
    if (t < NT - 1) {
      int t1 = t + 1;
      int cc1 = t1 / 9, r1 = t1 % 9, ky1 = r1 / 3, kx1 = r1 % 3;
      bfrN = *(const bf16x8*)(wbase + (size_t)t1 * 512);
      #pragma unroll
      for (int i = 0; i < MPW; i++)
        avN[i] = *(const bf16x8*)(tile + ((mh * MPW + i + ky1) * 18 + lm + kx1) * CIS + cc1 * 32 + quad * 8);
    }
    #pragma unroll
    for (int i = 0; i < MPW; i++)
      acc[i] = __builtin_amdgcn_mfma_f32_16x16x32_bf16(avC[i], bfrC, acc[i], 0, 0, 0);
  }
  __syncthreads();   // tile consumed; cout overlays
  #pragma unroll
  for (int i = 0; i < MPW; i++) {
    #pragma unroll
    for (int r = 0; r < 4; r++) {
      int pixel = (mh * MPW + i) * 16 + quad * 4 + r;
      cout[(n * 16 + lm) * 133 + pixel] = acc[i][r];
    }
  }
  __syncthreads();
  unsigned short* ob = out + (size_t)b * CO * NPIX;
  for (int v = tid; v < CO * 128; v += 256) {
    int co = v >> 7, px = v & 127;
    int y = y0 + (px >> 4), x = x0 + (px & 15);
    if (y < IH) ob[(size_t)co * NPIX + y * IW + x] = f2bf(cout[co * 133 + px] + bias[co]);
  }
  if (STATS) {
    constexpr int TPC = 256 / CO;     // threads per channel (8 or 16)
    constexpr int PXT = 128 / TPC;    // pixels per thread
    int col = tid / TPC, seg = tid % TPC;
    float bv = bias[col];
    float sum = 0.f, sq = 0.f;
    #pragma unroll
    for (int k = 0; k < PXT; k++) {
      int p = seg * PXT + k;
      if (y0 + (p >> 4) < IH) {
        float vv = cout[col * 133 + p] + bv;
        sum += vv; sq += vv * vv;
      }
    }
    #pragma unroll
    for (int off = TPC / 2; off > 0; off >>= 1) {
      sum += __shfl_down(sum, off);
      sq  += __shfl_down(sq, off);
    }
    if (seg == 0) {
      atomicAdd(&statsOut[(b * CO + col) * 2], sum);
      atomicAdd(&statsOut[(b * CO + col) * 2 + 1], sq);
    }
  }
}

// ============================================================
// Small direct fp32 3x3 conv, 16x8 tile, bf16 input + fused GN, output
// bf16 (OUT_BF16) or fp32, optional output stats via LDS atomics.
// ============================================================
template <int CI, int CO, int CHPER, bool STATS, bool OUT_BF16>
__global__ __launch_bounds__(256) void convs_kernel(
    const unsigned short* __restrict__ xin, const float* __restrict__ wT,
    const float* __restrict__ bias, const float* __restrict__ statsIn,
    const float* __restrict__ gamma, const float* __restrict__ beta,
    float* __restrict__ statsOut, void* __restrict__ outv) {
  constexpr int OPT = CO / 2;
  const int b = blockIdx.z;
  const int x0 = blockIdx.x * 16, y0 = blockIdx.y * 8;
  __shared__ float tile[CI * 180];
  __shared__ float cA[CI], cB[CI];
  __shared__ float ssum[CO], ssq[CO];
  gn_coef_thread(statsIn, gamma, beta, cA, cB, CI, CHPER, b);
  if (STATS && threadIdx.x < CO) { ssum[threadIdx.x] = 0.f; ssq[threadIdx.x] = 0.f; }
  __syncthreads();
  const unsigned short* xb = xin + (size_t)b * CI * NPIX;
  for (int t = threadIdx.x; t < CI * 180; t += 256) {
    int ci = t / 180, rc = t % 180, r = rc / 18, c = rc % 18;
    int gy = y0 - 1 + r, gx = x0 - 1 + c;
    float v = 0.f;
    if (gy >= 0 && gy < IH && gx >= 0 && gx < IW)
      v = fmaxf(fmaf(bf2f(xb[(size_t)ci * NPIX + gy * IW + gx]), cA[ci], cB[ci]), 0.f);
    tile[t] = v;
  }
  __syncthreads();
  const int t = threadIdx.x;
  const int px = t & 127, og = t >> 7;
  const int pyy = px >> 4, pxx = px & 15;
  const int oc0 = og * OPT;
  const int y = y0 + pyy, x = x0 + pxx;
  float acc[OPT] = {};
  for (int ky = 0; ky < 3; ky++) {
    for (int kx = 0; kx < 3; kx++) {
      const float* wrow = wT + (size_t)((ky * 3 + kx) * CI) * CO + oc0;
      for (int ci = 0; ci < CI; ci++) {
        float v = tile[ci * 180 + (pyy + ky) * 18 + pxx + kx];
        #pragma unroll
        for (int o = 0; o < OPT; o++) acc[o] = fmaf(v, wrow[ci * CO + o], acc[o]);
      }
    }
  }
  if (y < IH) {
    #pragma unroll
    for (int o = 0; o < OPT; o++) {
      float vv = acc[o] + bias[oc0 + o];
      if (OUT_BF16) {
        unsigned short* ob = (unsigned short*)outv + (size_t)b * CO * NPIX;
        ob[(size_t)(oc0 + o) * NPIX + y * IW + x] = f2bf(vv);
      } else {
        float* ob = (float*)outv + (size_t)b * CO * NPIX;
        ob[(size_t)(oc0 + o) * NPIX + y * IW + x] = vv;
      }
      if (STATS) {
        atomicAdd(&ssum[oc0 + o], vv);
        atomicAdd(&ssq[oc0 + o], vv * vv);
      }
    }
  }
  if (STATS) {
    __syncthreads();
    if (threadIdx.x < CO) {
      atomicAdd(&statsOut[(b * CO + threadIdx.x) * 2], ssum[threadIdx.x]);
      atomicAdd(&statsOut[(b * CO + threadIdx.x) * 2 + 1], ssq[threadIdx.x]);
    }
  }
}

// ============================================================
// Joint bilateral 5x5 (reflect), guide fused, global min/max fused.
// ============================================================
__global__ __launch_bounds__(256) void bilateral_kernel(
    const float* __restrict__ f, const float* __restrict__ gt,
    float* __restrict__ out, unsigned* __restrict__ mmbits) {
  const int b = blockIdx.z;
  const int x0 = blockIdx.x * 16, y0 = blockIdx.y * 16;
  __shared__ float gu[20][20], gv[20][20], f0s[20][20], f1s[20][20];
  __shared__ float red[4][4];
  const float* gtb = gt + (size_t)b * 3 * NPIX;
  const float* fb = f + (size_t)b * 2 * NPIX;
  for (int t = threadIdx.x; t < 400; t += 256) {
    int r = t / 20, c = t % 20;
    int gy = y0 - 2 + r, gx = x0 - 2 + c;
    if (gy < 0) gy = -gy;
    if (gy > IH - 1) gy = 2 * (IH - 1) - gy;
    if (gx < 0) gx = -gx;
    if (gx > IW - 1) gx = 2 * (IW - 1) - gx;
    int p = gy * IW + gx;
    float rr = gtb[p], gg = gtb[NPIX + p], bb = gtb[2 * NPIX + p];
    gu[r][c]  = -0.147f * rr - 0.289f * gg + 0.436f * bb;
    gv[r][c]  =  0.615f * rr - 0.515f * gg - 0.100f * bb;
    f0s[r][c] = fb[p];
    f1s[r][c] = fb[NPIX + p];
  }
  __syncthreads();
  const int t = threadIdx.x;
  const int lx = t % 16, ly = t / 16;
  const int y = y0 + ly, x = x0 + lx;
  const bool valid = (y < IH);

  float o0 = 0.f, o1 = 0.f;
  if (valid) {
    float g1v[5];
    float s = 0.f;
    #pragma unroll
    for (int k = 0; k < 5; k++) {
      float a = (float)(k - 2);
      g1v[k] = expf(-a * a / 4.5f);
      s += g1v[k];
    }
    #pragma unroll
    for (int k = 0; k < 5; k++) g1v[k] /= s;
    float cu = gu[ly + 2][lx + 2], cv = gv[ly + 2][lx + 2];
    float num0 = 0.f, num1 = 0.f, den = 0.f;
    #pragma unroll
    for (int dy = 0; dy < 5; dy++) {
      #pragma unroll
      for (int dx = 0; dx < 5; dx++) {
        float du = fabsf(gu[ly + dy][lx + dx] - cu) + fabsf(gv[ly + dy][lx + dx] - cv);
        float wgt = g1v[dy] * g1v[dx] * expf(-50.0f * du * du);
        num0 = fmaf(wgt, f0s[ly + dy][lx + dx], num0);
        num1 = fmaf(wgt, f1s[ly + dy][lx + dx], num1);
        den += wgt;
      }
    }
    o0 = num0 / den; o1 = num1 / den;
    float* ob = out + (size_t)b * 2 * NPIX;
    ob[y * IW + x] = o0;
    ob[NPIX + y * IW + x] = o1;
  }
  float mn0 = valid ? o0 : 1e30f,  mx0 = valid ? o0 : -1e30f;
  float mn1 = valid ? o1 : 1e30f,  mx1 = valid ? o1 : -1e30f;
  #pragma unroll
  for (int off = 32; off > 0; off >>= 1) {
    mn0 = fminf(mn0, __shfl_xor(mn0, off));
    mx0 = fmaxf(mx0, __shfl_xor(mx0, off));
    mn1 = fminf(mn1, __shfl_xor(mn1, off));
    mx1 = fmaxf(mx1, __shfl_xor(mx1, off));
  }
  if ((t & 63) == 0) {
    red[t >> 6][0] = mn0; red[t >> 6][1] = mx0;
    red[t >> 6][2] = mn1; red[t >> 6][3] = mx1;
  }
  __syncthreads();
  if (t == 0) {
    for (int w = 1; w < 4; w++) {
      red[0][0] = fminf(red[0][0], red[w][0]);
      red[0][1] = fmaxf(red[0][1], red[w][1]);
      red[0][2] = fminf(red[0][2], red[w][2]);
      red[0][3] = fmaxf(red[0][3], red[w][3]);
    }
    atomicMax(&mmbits[0], fkey(red[0][1]));   // max0
    atomicMax(&mmbits[1], fkey(red[0][3]));   // max1
    atomicMin(&mmbits[2], fkey(red[0][0]));   // min0
    atomicMin(&mmbits[3], fkey(red[0][2]));   // min1
  }
}

// ============================================================
// Final: rescale U/V from atomic min/max keys, YUV->RGB
// ============================================================
__global__ __launch_bounds__(256) void final_kernel(
    const float* __restrict__ bil, const float* __restrict__ x,
    const unsigned* __restrict__ mmbits, float* __restrict__ out) {
  int i = blockIdx.x * 256 + threadIdx.x;
  if (i >= NB * NPIX) return;
  float mx0 = funkey(mmbits[0]), mx1 = funkey(mmbits[1]);
  float mn0 = funkey(mmbits[2]), mn1 = funkey(mmbits[3]);
  int b = i / NPIX, p = i % NPIX;
  float f0 = bil[(size_t)b * 2 * NPIX + p];
  float f1 = bil[(size_t)b * 2 * NPIX + NPIX + p];
  float U = (f0 - mn0) / (mx0 - mn0 + 1e-6f);
  U = fminf(fmaxf(U, 0.f), 1.f) * 0.872f - 0.436f;
  float V = (f1 - mn1) / (mx1 - mn1 + 1e-6f);
  V = fminf(fmaxf(V, 0.f), 1.f) * 1.23f - 0.615f;
  float Y = x[(size_t)b * NPIX + p];
  float* ob = out + (size_t)b * 3 * NPIX;
  ob[p]            = Y + 1.14f * V;
  ob[NPIX + p]     = Y - 0.396f * U - 0.581f * V;
  ob[2 * NPIX + p] = Y + 2.029f * U;
}

// ============================================================
// launch
// ============================================================
extern "C" void kernel_launch(void* const* d_in, const int* in_sizes, int n_in,
                              void* d_out, int out_size, void* d_ws, size_t ws_size,
                              hipStream_t stream) {
  const float* x   = (const float*)d_in[0];
  const float* gt  = (const float*)d_in[1];
  const float* w1  = (const float*)d_in[2];
  const float* b1  = (const float*)d_in[3];
  const float* g1w = (const float*)d_in[4];
  const float* g1b = (const float*)d_in[5];
  const float* w2  = (const float*)d_in[6];
  const float* b2  = (const float*)d_in[7];
  const float* g2w = (const float*)d_in[8];
  const float* g2b = (const float*)d_in[9];
  const float* w3  = (const float*)d_in[10];
  const float* b3  = (const float*)d_in[11];
  const float* g3w = (const float*)d_in[12];
  const float* g3b = (const float*)d_in[13];
  const float* w4  = (const float*)d_in[14];
  const float* b4  = (const float*)d_in[15];
  const float* g4w = (const float*)d_in[16];
  const float* g4b = (const float*)d_in[17];
  const float* w5  = (const float*)d_in[18];
  const float* b5  = (const float*)d_in[19];
  float* out = (float*)d_out;

  // ---- workspace layout ----
  char* ws = (char*)d_ws;
  float* stats1 = (float*)ws;                  // 512
  float* stats2 = stats1 + 512;                // 256
  float* stats3 = stats2 + 256;                // 128
  float* stats4 = stats3 + 128;                // 64  (ends 960)
  unsigned* mmbits = (unsigned*)(ws + 12288);  // [max0,max1,min0,min1]
  char* base = ws + 16384;
  short* descg = (short*)base;
  size_t descg_shorts = (size_t)NB * 4 * NPIX * 32;       // 70,778,880
  unsigned short* bufB_h = (unsigned short*)base;         // conv2 out 32ch / conv4 out 8ch
  float* c5    = (float*)(base + 36000000);               // conv5 out (2ch fp32)
  float* bilat = (float*)(base + 41000000);               // bilateral out
  short* w1B = descg + descg_shorts;                      // 204800 shorts
  short* w2B = w1B + 204800;                              // 18432
  short* w3B = w2B + 18432;                               // 4608
  float* w4T = (float*)(w3B + 4608);                      // 1152 floats
  float* w5T = w4T + 1152;                                // 144 floats
  unsigned short* bufA_h = (unsigned short*)(w5T + 144);  // conv1 out 64ch / conv3 out 16ch

  hipMemsetAsync(ws, 0, 12304, stream);              // stats + max keys
  hipMemsetAsync(ws + 12296, 0xFF, 8, stream);       // min keys

  prep_kernel<<<896, 256, 0, stream>>>(w1, w2, w3, w4, w5, w1B, w2B, w3B, w4T, w5T);

  sift_desc_kernel<<<dim3(32, 17, NB), 256, 0, stream>>>(x, descg);

  conv1_mfma_kernel<<<dim3(32, 17, NB), 256, 0, stream>>>(descg, w1B, b1, bufA_h, stats1);

  convk3_mfma_kernel<64, 32, 8, true><<<dim3(32, 34, NB), 256, 0, stream>>>(
      bufA_h, w2B, b2, stats1, g1w, g1b, stats2, bufB_h);

  convk3_mfma_kernel<32, 16, 4, true><<<dim3(32, 34, NB), 256, 0, stream>>>(
      bufB_h, w3B, b3, stats2, g2w, g2b, stats3, bufA_h);

  convs_kernel<16, 8, 4, true, true><<<dim3(32, 34, NB), 256, 0, stream>>>(
      bufA_h, w4T, b4, stats3, g3w, g3b, stats4, bufB_h);

  convs_kernel<8, 2, 2, false, false><<<dim3(32, 34, NB), 256, 0, stream>>>(
      bufB_h, w5T, b5, stats4, g4w, g4b, nullptr, c5);

  bilateral_kernel<<<dim3(32, 17, NB), 256, 0, stream>>>(c5, gt, bilat, mmbits);
  final_kernel<<<(NB * NPIX + 255) / 256, 256, 0, stream>>>(bilat, x, mmbits, out);

  (void)in_sizes; (void)n_in; (void)out_size; (void)ws_size;
}